// Round 1
// baseline (520.918 us; speedup 1.0000x reference)
//
#include <hip/hip_runtime.h>
#include <hip/hip_bf16.h>

// Problem constants
#define BB 8
#define SS 1024
#define HH 512
#define DD 64

typedef unsigned short u16;
typedef short v8s __attribute__((ext_vector_type(8)));   // 8 x bf16 (bit pattern)
typedef float v4f __attribute__((ext_vector_type(4)));

__device__ __forceinline__ float bf2f(u16 u) {
    union { unsigned int i; float f; } v; v.i = ((unsigned int)u) << 16; return v.f;
}
__device__ __forceinline__ u16 f2bf(float f) {
    union { float f; unsigned int i; } v; v.f = f;
    unsigned int u = v.i;
    unsigned int r = u + 0x7fffu + ((u >> 16) & 1u);   // RNE
    return (u16)(r >> 16);
}

// ---------------------------------------------------------------------------
// K1: x(8192x512) @ [Wq;Wk;Wv;gate_W]^T -> Qraw,Kraw,V (fp32, [8192][64]), glog [8192][2]
// ---------------------------------------------------------------------------
__global__ __launch_bounds__(256) void k_qkv(const float* __restrict__ x,
    const float* __restrict__ Wq, const float* __restrict__ Wk,
    const float* __restrict__ Wv, const float* __restrict__ gW,
    float* __restrict__ Q, float* __restrict__ K, float* __restrict__ V,
    float* __restrict__ glog)
{
    __shared__ float xs[16 * 516];
    int t = threadIdx.x;
    long row0 = (long)blockIdx.x * 16;
    #pragma unroll
    for (int i = 0; i < 8; i++) {
        int c = t + (i << 8);          // 0..2047 chunks of float4
        int r = c >> 7, kq = (c & 127) << 2;
        float4 v = *(const float4*)(x + (row0 + r) * 512 + kq);
        *(float4*)(&xs[r * 516 + kq]) = v;
    }
    __syncthreads();
    for (int it = 0; it < 2; it++) {
        int idx = t + (it << 8);
        if (idx < 388) {
            int col = idx >> 1, rh = (idx & 1) * 8;
            const float* Wrow;
            if (col < 64)       Wrow = Wq + col * 512;
            else if (col < 128) Wrow = Wk + (col - 64) * 512;
            else if (col < 192) Wrow = Wv + (col - 128) * 512;
            else                Wrow = gW + (col - 192) * 512;
            float acc[8] = {0.f,0.f,0.f,0.f,0.f,0.f,0.f,0.f};
            for (int kq = 0; kq < 512; kq += 4) {
                float4 wv = *(const float4*)(Wrow + kq);
                #pragma unroll
                for (int rr = 0; rr < 8; rr++) {
                    float4 xv = *(const float4*)(&xs[(rh + rr) * 516 + kq]);
                    acc[rr] += xv.x * wv.x + xv.y * wv.y + xv.z * wv.z + xv.w * wv.w;
                }
            }
            #pragma unroll
            for (int rr = 0; rr < 8; rr++) {
                long grow = row0 + rh + rr;
                if (col < 64)       Q[grow * 64 + col] = acc[rr];
                else if (col < 128) K[grow * 64 + (col - 64)] = acc[rr];
                else if (col < 192) V[grow * 64 + (col - 128)] = acc[rr];
                else                glog[grow * 2 + (col - 192)] = acc[rr];
            }
        }
    }
}

// ---------------------------------------------------------------------------
// K2: RoPE (fp32 -> bf16 Qb/Kb), gate softmax, hopVT (bf16 [hop][b][e][s])
// one wave per row, 4 rows per block
// ---------------------------------------------------------------------------
__global__ __launch_bounds__(256) void k_rope(
    const float* __restrict__ Qraw, const float* __restrict__ Kraw,
    const float* __restrict__ V, const float* __restrict__ glog,
    const float* __restrict__ hopW, const float* __restrict__ gateb,
    u16* __restrict__ Qb, u16* __restrict__ Kb,
    u16* __restrict__ hopVT, float* __restrict__ gate)
{
    __shared__ float vs[4][64];
    int t = threadIdx.x, l = t & 63, w = t >> 6;
    long row = (long)blockIdx.x * 4 + w;       // 0..8191
    int spos = (int)(row & (SS - 1));
    int b = (int)(row >> 10);
    float q = Qraw[row * 64 + l], k = Kraw[row * 64 + l];
    float qp = __shfl_xor(q, 32), kp = __shfl_xor(k, 32);
    float sgn = (l < 32) ? -1.f : 1.f;
    int f = l & 31;
    float ang = (float)spos * exp2f(-(float)f * (13.287712379549449f / 32.0f));
    float cs = cosf(ang), sn = sinf(ang);
    Qb[row * 64 + l] = f2bf(q * cs + sgn * qp * sn);
    Kb[row * 64 + l] = f2bf(k * cs + sgn * kp * sn);
    if (l < 2) {
        float g0 = glog[row * 2] + gateb[0], g1 = glog[row * 2 + 1] + gateb[1];
        float m = fmaxf(g0, g1);
        float e0 = __expf(g0 - m), e1 = __expf(g1 - m);
        gate[row * 2 + l] = ((l == 0) ? e0 : e1) / (e0 + e1);
    }
    vs[w][l] = V[row * 64 + l];
    __syncthreads();
    #pragma unroll
    for (int hop = 0; hop < 2; hop++) {
        float a = 0.f;
        const float* wr = hopW + (hop * 64 + l) * 64;
        #pragma unroll 8
        for (int d = 0; d < 64; d++) a += vs[w][d] * wr[d];
        hopVT[(((long)hop * BB + b) * 64 + l) * SS + spos] = f2bf(a);
    }
}

// ---------------------------------------------------------------------------
// Batched NT GEMM:  C[b] = X[b] (MxK) * Y[b]^T (NxK), bf16 in, fp32 acc
// 128x128 tile, 4 waves of 64x64, mfma_f32_16x16x32_bf16.
// C written bf16 (cf32=0) or fp32 (cf32=1). M,N,K multiples of 16; grid covers
// ceil; staging rows clamped, stores guarded.
// ---------------------------------------------------------------------------
__global__ __launch_bounds__(256) void gemm_nt(
    const u16* __restrict__ X, long sx,
    const u16* __restrict__ Y, long sy,
    void* __restrict__ Cv, long sc,
    int M, int N, int K, int cf32)
{
    __shared__ u16 Xs[128 * 40];   // rows padded 32->40 shorts (80B)
    __shared__ u16 Ys[128 * 40];
    const u16* Xb = X + (long)blockIdx.z * sx;
    const u16* Yb = Y + (long)blockIdx.z * sy;
    int tm = blockIdx.x * 128, tn = blockIdx.y * 128;
    int t = threadIdx.x, lane = t & 63, w = t >> 6;
    int wm = (w & 1) << 6, wn = (w >> 1) << 6;
    int fr = lane & 15, q = lane >> 4;
    v4f acc[4][4];
    #pragma unroll
    for (int i = 0; i < 4; i++)
        #pragma unroll
        for (int j = 0; j < 4; j++) {
            acc[i][j][0] = 0.f; acc[i][j][1] = 0.f; acc[i][j][2] = 0.f; acc[i][j][3] = 0.f;
        }
    for (int k0 = 0; k0 < K; k0 += 32) {
        __syncthreads();
        #pragma unroll
        for (int i = 0; i < 2; i++) {
            int c = t + (i << 8);
            int r = c >> 2, kc = (c & 3) << 3;
            int xr = tm + r; if (xr >= M) xr = M - 1;
            uint4 xv = *(const uint4*)(Xb + (long)xr * K + k0 + kc);
            *(uint4*)(&Xs[r * 40 + kc]) = xv;
            int yr = tn + r; if (yr >= N) yr = N - 1;
            uint4 yv = *(const uint4*)(Yb + (long)yr * K + k0 + kc);
            *(uint4*)(&Ys[r * 40 + kc]) = yv;
        }
        __syncthreads();
        v8s af[4], bfr[4];
        #pragma unroll
        for (int s = 0; s < 4; s++) {
            af[s]  = *(const v8s*)(&Xs[(wm + s * 16 + fr) * 40 + q * 8]);
            bfr[s] = *(const v8s*)(&Ys[(wn + s * 16 + fr) * 40 + q * 8]);
        }
        #pragma unroll
        for (int i = 0; i < 4; i++)
            #pragma unroll
            for (int j = 0; j < 4; j++)
                acc[i][j] = __builtin_amdgcn_mfma_f32_16x16x32_bf16(af[i], bfr[j], acc[i][j], 0, 0, 0);
    }
    long cb = (long)blockIdx.z * sc;
    #pragma unroll
    for (int i = 0; i < 4; i++) {
        int rowb = tm + wm + i * 16 + q * 4;
        #pragma unroll
        for (int j = 0; j < 4; j++) {
            int col = tn + wn + j * 16 + fr;
            if (col < N) {
                #pragma unroll
                for (int r = 0; r < 4; r++) {
                    int row = rowb + r;
                    if (row < M) {
                        if (cf32) ((float*)Cv)[cb + (long)row * N + col] = acc[i][j][r];
                        else      ((u16*)Cv)[cb + (long)row * N + col] = f2bf(acc[i][j][r]);
                    }
                }
            }
        }
    }
}

// ---------------------------------------------------------------------------
// K4: softmax over scores rows (+ bias from table, /sqrt(d), /temp) -> A bf16
// one wave per row
// ---------------------------------------------------------------------------
__global__ __launch_bounds__(256) void k_softmax(
    const float* __restrict__ scores, const float* __restrict__ btab,
    const float* __restrict__ temp, u16* __restrict__ A)
{
    __shared__ float bt[63 * 63];
    int t = threadIdx.x;
    for (int i = t; i < 3969; i += 256) bt[i] = btab[i];
    __syncthreads();
    int lane = t & 63, w = t >> 6;
    long row = (long)blockIdx.x * 4 + w;
    int i = (int)(row & 1023);
    int ih = i >> 5, iw = i & 31;
    float inv_t = 1.0f / fmaxf(temp[0], 0.1f);
    const float* srow = scores + row * 1024;
    float sc[16];
    float m = -1e30f;
    #pragma unroll
    for (int c = 0; c < 16; c++) {
        int j = c * 64 + lane;
        int jh = j >> 5, jw = j & 31;
        float pb = bt[(ih - jh + 31) * 63 + (iw - jw + 31)];
        float s = (srow[j] * 0.125f + pb) * inv_t;
        sc[c] = s; m = fmaxf(m, s);
    }
    #pragma unroll
    for (int o = 1; o < 64; o <<= 1) m = fmaxf(m, __shfl_xor(m, o));
    float sum = 0.f;
    #pragma unroll
    for (int c = 0; c < 16; c++) { sc[c] = __expf(sc[c] - m); sum += sc[c]; }
    #pragma unroll
    for (int o = 1; o < 64; o <<= 1) sum += __shfl_xor(sum, o);
    float inv = 1.0f / sum;
    #pragma unroll
    for (int c = 0; c < 16; c++) A[row * 1024 + c * 64 + lane] = f2bf(sc[c] * inv);
}

// ---------------------------------------------------------------------------
// K5: per-batch 1024x1024 bf16 transpose (A -> AT)
// ---------------------------------------------------------------------------
__global__ __launch_bounds__(256) void k_transpose(const u16* __restrict__ src, u16* __restrict__ dst)
{
    __shared__ u16 tile[64 * 72];
    long base = (long)blockIdx.z * (1024L * 1024L);
    int i0 = blockIdx.x * 64, j0 = blockIdx.y * 64;
    int t = threadIdx.x;
    int r = t >> 2, c0 = (t & 3) << 4;
    #pragma unroll
    for (int p = 0; p < 2; p++) {
        int c = c0 + p * 8;
        uint4 v = *(const uint4*)(src + base + (long)(i0 + r) * 1024 + j0 + c);
        *(uint4*)(&tile[r * 72 + c]) = v;
    }
    __syncthreads();
    #pragma unroll
    for (int p = 0; p < 2; p++) {
        uint4 ov;
        u16* po = (u16*)&ov;
        #pragma unroll
        for (int e = 0; e < 8; e++) po[e] = tile[(c0 + p * 8 + e) * 72 + r];
        *(uint4*)(dst + base + (long)(j0 + r) * 1024 + i0 + c0 + p * 8) = ov;
    }
}

// ---------------------------------------------------------------------------
// K6: fused prob_log/sigmoid/row-norm -> F bf16 (row-stochastic-ish weights)
// one wave per row; M1/M2/M3 are [8192][1024] bf16
// ---------------------------------------------------------------------------
__global__ __launch_bounds__(256) void k_fused(
    const u16* __restrict__ M1, const u16* __restrict__ M2,
    const u16* __restrict__ M3, const float* __restrict__ fw,
    const float* __restrict__ fbv, int hop, u16* __restrict__ F)
{
    int t = threadIdx.x, lane = t & 63, w = t >> 6;
    long row = (long)blockIdx.x * 4 + w;
    const u16* r1 = M1 + row * 1024;
    const u16* r2 = M2 + row * 1024;
    const u16* r3 = M3 + row * 1024;
    float m1[16], m2[16], m3[16];
    float s1 = 0.f, s2 = 0.f, s3 = 0.f;
    #pragma unroll
    for (int c = 0; c < 16; c++) {
        int j = c * 64 + lane;
        m1[c] = bf2f(r1[j]); m2[c] = bf2f(r2[j]); m3[c] = bf2f(r3[j]);
        s1 += m1[c]; s2 += m2[c]; s3 += m3[c];
    }
    #pragma unroll
    for (int o = 1; o < 64; o <<= 1) {
        s1 += __shfl_xor(s1, o); s2 += __shfl_xor(s2, o); s3 += __shfl_xor(s3, o);
    }
    float i1 = 1.f / (s1 + 1e-6f), i2 = 1.f / (s2 + 1e-6f), i3 = 1.f / (s3 + 1e-6f);
    float w0 = fw[hop * 3], w1 = fw[hop * 3 + 1], w2 = fw[hop * 3 + 2], b0 = fbv[hop];
    float sig[16];
    float ssum = 0.f;
    #pragma unroll
    for (int c = 0; c < 16; c++) {
        float p1 = fminf(fmaxf(m1[c] * i1, 1e-6f), 1.0f - 1e-6f);
        float p2 = fminf(fmaxf(m2[c] * i2, 1e-6f), 1.0f - 1e-6f);
        float p3 = fminf(fmaxf(m3[c] * i3, 1e-6f), 1.0f - 1e-6f);
        float l1 = __logf(p1 / (1.0f - p1 + 1e-6f));
        float l2 = __logf(p2 / (1.0f - p2 + 1e-6f));
        float l3 = __logf(p3 / (1.0f - p3 + 1e-6f));
        float lg = b0 + w0 * l1 + w1 * l2 + w2 * l3;
        float sg = 1.0f / (1.0f + __expf(-lg));
        sig[c] = sg; ssum += sg;
    }
    #pragma unroll
    for (int o = 1; o < 64; o <<= 1) ssum += __shfl_xor(ssum, o);
    float inv = 1.0f / (ssum + 1e-6f);
    #pragma unroll
    for (int c = 0; c < 16; c++) F[row * 1024 + c * 64 + lane] = f2bf(sig[c] * inv);
}

// ---------------------------------------------------------------------------
// K7: gate-combine hop outputs -> combined bf16 [8192][64]
// ---------------------------------------------------------------------------
__global__ __launch_bounds__(256) void k_combine(
    const float* __restrict__ h0, const float* __restrict__ h1,
    const float* __restrict__ gate, u16* __restrict__ comb)
{
    long idx = (long)blockIdx.x * 256 + threadIdx.x;   // 8192*64
    long row = idx >> 6;
    float g0 = gate[row * 2], g1 = gate[row * 2 + 1];
    comb[idx] = f2bf(h0[idx] * g0 + h1[idx] * g1);
}

__global__ __launch_bounds__(256) void k_convw(const float* __restrict__ wsrc, u16* __restrict__ wb)
{
    int idx = blockIdx.x * 256 + threadIdx.x;  // 512*64
    wb[idx] = f2bf(wsrc[idx]);
}

// ---------------------------------------------------------------------------
extern "C" void kernel_launch(void* const* d_in, const int* in_sizes, int n_in,
                              void* d_out, int out_size, void* d_ws, size_t ws_size,
                              hipStream_t stream) {
    const float* x    = (const float*)d_in[0];
    const float* Wq   = (const float*)d_in[1];
    const float* Wk   = (const float*)d_in[2];
    const float* Wv   = (const float*)d_in[3];
    const float* btab = (const float*)d_in[4];
    const float* fw   = (const float*)d_in[5];
    const float* fbv  = (const float*)d_in[6];
    const float* hopW = (const float*)d_in[7];
    const float* gW   = (const float*)d_in[8];
    const float* gb   = (const float*)d_in[9];
    const float* outW = (const float*)d_in[10];
    const float* temp = (const float*)d_in[11];
    float* out = (float*)d_out;

    // workspace carve-up (~167 MB total)
    char* wsb = (char*)d_ws;
    size_t off = 0;
    auto take = [&](size_t n) { char* p = wsb + off; off += (n + 255) & ~(size_t)255; return p; };
    float* Qraw  = (float*)take(8192L * 64 * 4);
    float* Kraw  = (float*)take(8192L * 64 * 4);
    float* V     = (float*)take(8192L * 64 * 4);
    float* glog  = (float*)take(8192L * 2 * 4);
    float* gate  = (float*)take(8192L * 2 * 4);
    u16* Qb      = (u16*)take(8192L * 64 * 2);
    u16* Kb      = (u16*)take(8192L * 64 * 2);
    u16* hopVT   = (u16*)take(2L * 8 * 64 * 1024 * 2);
    float* houts = (float*)take(2L * 8 * 1024 * 64 * 4);
    u16* comb    = (u16*)take(8192L * 64 * 2);
    u16* outWb   = (u16*)take(512L * 64 * 2);
    float* scoresF = (float*)take(8L * 1024 * 1024 * 4);  // aliased: F reuses this region
    u16* F       = (u16*)scoresF;                          // scores dead before F is written
    u16* A       = (u16*)take(8L * 1024 * 1024 * 2);
    u16* AT      = (u16*)take(8L * 1024 * 1024 * 2);
    u16* AAt     = (u16*)take(8L * 1024 * 1024 * 2);
    u16* AtA     = (u16*)take(8L * 1024 * 1024 * 2);
    u16* A2      = (u16*)take(8L * 1024 * 1024 * 2);
    u16* AAt2    = (u16*)take(8L * 1024 * 1024 * 2);
    u16* AtA2    = (u16*)take(8L * 1024 * 1024 * 2);
    (void)ws_size; (void)in_sizes; (void)n_in; (void)out_size;

    const long SD = (long)SS * DD;        // 65536
    const long SSq = (long)SS * SS;       // 1048576

    // 1. projections
    k_qkv<<<512, 256, 0, stream>>>(x, Wq, Wk, Wv, gW, Qraw, Kraw, V, glog);
    // 2. rope + gate + hopVT
    k_rope<<<2048, 256, 0, stream>>>(Qraw, Kraw, V, glog, hopW, gb, Qb, Kb, hopVT, gate);
    // 3. scores = Q K^T  (fp32 out)
    gemm_nt<<<dim3(8, 8, 8), 256, 0, stream>>>(Qb, SD, Kb, SD, scoresF, SSq, 1024, 1024, 64, 1);
    // 4. softmax -> A (bf16)
    k_softmax<<<2048, 256, 0, stream>>>(scoresF, btab, temp, A);
    // 5. AT
    k_transpose<<<dim3(16, 16, 8), 256, 0, stream>>>(A, AT);
    // 6. AAt = A A^T ; AtA = (AT)(AT)^T
    gemm_nt<<<dim3(8, 8, 8), 256, 0, stream>>>(A, SSq, A, SSq, AAt, SSq, 1024, 1024, 1024, 0);
    gemm_nt<<<dim3(8, 8, 8), 256, 0, stream>>>(AT, SSq, AT, SSq, AtA, SSq, 1024, 1024, 1024, 0);
    // 7. hop 0 fused -> F ; hop_out0 = F @ hopV0
    k_fused<<<2048, 256, 0, stream>>>(A, AAt, AtA, fw, fbv, 0, F);
    gemm_nt<<<dim3(8, 1, 8), 256, 0, stream>>>(F, SSq, hopVT, SD, houts, SD, 1024, 64, 1024, 1);
    // 8. squares for hop 1
    gemm_nt<<<dim3(8, 8, 8), 256, 0, stream>>>(A, SSq, AT, SSq, A2, SSq, 1024, 1024, 1024, 0);
    gemm_nt<<<dim3(8, 8, 8), 256, 0, stream>>>(AAt, SSq, AAt, SSq, AAt2, SSq, 1024, 1024, 1024, 0);
    gemm_nt<<<dim3(8, 8, 8), 256, 0, stream>>>(AtA, SSq, AtA, SSq, AtA2, SSq, 1024, 1024, 1024, 0);
    // 9. hop 1 fused -> F ; hop_out1
    k_fused<<<2048, 256, 0, stream>>>(A2, AAt2, AtA2, fw, fbv, 1, F);
    gemm_nt<<<dim3(8, 1, 8), 256, 0, stream>>>(F, SSq, hopVT + (long)BB * 64 * SS, SD,
                                               houts + (long)BB * SS * DD, SD, 1024, 64, 1024, 1);
    // 10. combine + output projection
    k_convw<<<128, 256, 0, stream>>>(outW, outWb);
    k_combine<<<2048, 256, 0, stream>>>(houts, houts + (long)BB * SS * DD, gate, comb);
    gemm_nt<<<dim3(64, 4, 1), 256, 0, stream>>>(comb, 0, outWb, 0, out, 0, 8192, 512, 64, 1);
}

// Round 2
// 476.840 us; speedup vs baseline: 1.0924x; 1.0924x over previous
//
#include <hip/hip_runtime.h>
#include <hip/hip_bf16.h>

// Problem constants
#define BB 8
#define SS 1024
#define HH 512
#define DD 64

typedef unsigned short u16;
typedef short v8s __attribute__((ext_vector_type(8)));   // 8 x bf16 (bit pattern)
typedef float v4f __attribute__((ext_vector_type(4)));

__device__ __forceinline__ float bf2f(u16 u) {
    union { unsigned int i; float f; } v; v.i = ((unsigned int)u) << 16; return v.f;
}
__device__ __forceinline__ u16 f2bf(float f) {
    union { float f; unsigned int i; } v; v.f = f;
    unsigned int u = v.i;
    unsigned int r = u + 0x7fffu + ((u >> 16) & 1u);   // RNE
    return (u16)(r >> 16);
}

// ---------------------------------------------------------------------------
// K0a: x (fp32, 8192x512) -> bf16, vectorized
// ---------------------------------------------------------------------------
__global__ __launch_bounds__(256) void k_packx(const float* __restrict__ src,
                                               u16* __restrict__ dst)
{
    long i = (long)blockIdx.x * 256 + threadIdx.x;  // over float4 units (1M total)
    float4 v = ((const float4*)src)[i];
    ushort4 o;
    o.x = f2bf(v.x); o.y = f2bf(v.y); o.z = f2bf(v.z); o.w = f2bf(v.w);
    ((ushort4*)dst)[i] = o;
}

// ---------------------------------------------------------------------------
// K0b: pack weights to bf16.
//  wpack [256][512]: rows 0-63 Wq, 64-127 Wk, 128-191 Wv, 192-193 gate_W, rest 0
//  hopWb [2*64][64] (= hopW layout), outWb [512][64]
// ---------------------------------------------------------------------------
__global__ __launch_bounds__(256) void k_packw(
    const float* __restrict__ Wq, const float* __restrict__ Wk,
    const float* __restrict__ Wv, const float* __restrict__ gW,
    const float* __restrict__ hopW, const float* __restrict__ outW,
    u16* __restrict__ wpack, u16* __restrict__ hopWb, u16* __restrict__ outWb)
{
    int idx = blockIdx.x * 256 + threadIdx.x;
    if (idx < 131072) {
        int r = idx >> 9, c = idx & 511;
        float v = 0.f;
        if (r < 64)       v = Wq[r * 512 + c];
        else if (r < 128) v = Wk[(r - 64) * 512 + c];
        else if (r < 192) v = Wv[(r - 128) * 512 + c];
        else if (r < 194) v = gW[(r - 192) * 512 + c];
        wpack[idx] = f2bf(v);
    } else if (idx < 131072 + 8192) {
        int i = idx - 131072;
        hopWb[i] = f2bf(hopW[i]);
    } else if (idx < 131072 + 8192 + 32768) {
        int i = idx - 131072 - 8192;
        outWb[i] = f2bf(outW[i]);
    }
}

// ---------------------------------------------------------------------------
// K2: RoPE (QKVG fp32 -> bf16 Qb/Kb), Vb bf16, gate softmax
// one wave per row, 4 rows per block
// ---------------------------------------------------------------------------
__global__ __launch_bounds__(256) void k_rope(
    const float* __restrict__ QKVG, const float* __restrict__ gateb,
    u16* __restrict__ Qb, u16* __restrict__ Kb, u16* __restrict__ Vb,
    float* __restrict__ gate)
{
    int t = threadIdx.x, l = t & 63, w = t >> 6;
    long row = (long)blockIdx.x * 4 + w;       // 0..8191
    int spos = (int)(row & (SS - 1));
    const float* base = QKVG + row * 256;
    float q = base[l], k = base[64 + l], v = base[128 + l];
    float qp = __shfl_xor(q, 32), kp = __shfl_xor(k, 32);
    float sgn = (l < 32) ? -1.f : 1.f;
    int f = l & 31;
    float ang = (float)spos * exp2f(-(float)f * (13.287712379549449f / 32.0f));
    float cs = cosf(ang), sn = sinf(ang);
    Qb[row * 64 + l] = f2bf(q * cs + sgn * qp * sn);
    Kb[row * 64 + l] = f2bf(k * cs + sgn * kp * sn);
    Vb[row * 64 + l] = f2bf(v);
    if (l < 2) {
        float g0 = base[192] + gateb[0], g1 = base[193] + gateb[1];
        float m = fmaxf(g0, g1);
        float e0 = __expf(g0 - m), e1 = __expf(g1 - m);
        gate[row * 2 + l] = ((l == 0) ? e0 : e1) / (e0 + e1);
    }
}

// ---------------------------------------------------------------------------
// Batched NT GEMM:  C[b] = X[b] (MxK) * Y[b]^T (NxK), bf16 in, fp32 acc
// 128x128 tile, 4 waves of 64x64, mfma_f32_16x16x32_bf16.
// C written bf16 (cf32=0) or fp32 (cf32=1). K multiple of 32; staging rows
// clamped, stores guarded.
// ---------------------------------------------------------------------------
__global__ __launch_bounds__(256) void gemm_nt(
    const u16* __restrict__ X, long sx,
    const u16* __restrict__ Y, long sy,
    void* __restrict__ Cv, long sc,
    int M, int N, int K, int cf32)
{
    __shared__ u16 Xs[128 * 40];   // rows padded 32->40 shorts (80B)
    __shared__ u16 Ys[128 * 40];
    const u16* Xb = X + (long)blockIdx.z * sx;
    const u16* Yb = Y + (long)blockIdx.z * sy;
    int tm = blockIdx.x * 128, tn = blockIdx.y * 128;
    int t = threadIdx.x, lane = t & 63, w = t >> 6;
    int wm = (w & 1) << 6, wn = (w >> 1) << 6;
    int fr = lane & 15, q = lane >> 4;
    v4f acc[4][4];
    #pragma unroll
    for (int i = 0; i < 4; i++)
        #pragma unroll
        for (int j = 0; j < 4; j++) {
            acc[i][j][0] = 0.f; acc[i][j][1] = 0.f; acc[i][j][2] = 0.f; acc[i][j][3] = 0.f;
        }
    for (int k0 = 0; k0 < K; k0 += 32) {
        __syncthreads();
        #pragma unroll
        for (int i = 0; i < 2; i++) {
            int c = t + (i << 8);
            int r = c >> 2, kc = (c & 3) << 3;
            int xr = tm + r; if (xr >= M) xr = M - 1;
            uint4 xv = *(const uint4*)(Xb + (long)xr * K + k0 + kc);
            *(uint4*)(&Xs[r * 40 + kc]) = xv;
            int yr = tn + r; if (yr >= N) yr = N - 1;
            uint4 yv = *(const uint4*)(Yb + (long)yr * K + k0 + kc);
            *(uint4*)(&Ys[r * 40 + kc]) = yv;
        }
        __syncthreads();
        v8s af[4], bfr[4];
        #pragma unroll
        for (int s = 0; s < 4; s++) {
            af[s]  = *(const v8s*)(&Xs[(wm + s * 16 + fr) * 40 + q * 8]);
            bfr[s] = *(const v8s*)(&Ys[(wn + s * 16 + fr) * 40 + q * 8]);
        }
        #pragma unroll
        for (int i = 0; i < 4; i++)
            #pragma unroll
            for (int j = 0; j < 4; j++)
                acc[i][j] = __builtin_amdgcn_mfma_f32_16x16x32_bf16(af[i], bfr[j], acc[i][j], 0, 0, 0);
    }
    long cb = (long)blockIdx.z * sc;
    #pragma unroll
    for (int i = 0; i < 4; i++) {
        int rowb = tm + wm + i * 16 + q * 4;
        #pragma unroll
        for (int j = 0; j < 4; j++) {
            int col = tn + wn + j * 16 + fr;
            if (col < N) {
                #pragma unroll
                for (int r = 0; r < 4; r++) {
                    int row = rowb + r;
                    if (row < M) {
                        if (cf32) ((float*)Cv)[cb + (long)row * N + col] = acc[i][j][r];
                        else      ((u16*)Cv)[cb + (long)row * N + col] = f2bf(acc[i][j][r]);
                    }
                }
            }
        }
    }
}

// ---------------------------------------------------------------------------
// K4: softmax over scores rows (+ bias from table, /sqrt(d), /temp) -> A bf16
// one wave per row
// ---------------------------------------------------------------------------
__global__ __launch_bounds__(256) void k_softmax(
    const float* __restrict__ scores, const float* __restrict__ btab,
    const float* __restrict__ temp, u16* __restrict__ A)
{
    __shared__ float bt[63 * 63];
    int t = threadIdx.x;
    for (int i = t; i < 3969; i += 256) bt[i] = btab[i];
    __syncthreads();
    int lane = t & 63, w = t >> 6;
    long row = (long)blockIdx.x * 4 + w;
    int i = (int)(row & 1023);
    int ih = i >> 5, iw = i & 31;
    float inv_t = 1.0f / fmaxf(temp[0], 0.1f);
    const float* srow = scores + row * 1024;
    float sc[16];
    float m = -1e30f;
    #pragma unroll
    for (int c = 0; c < 16; c++) {
        int j = c * 64 + lane;
        int jh = j >> 5, jw = j & 31;
        float pb = bt[(ih - jh + 31) * 63 + (iw - jw + 31)];
        float s = (srow[j] * 0.125f + pb) * inv_t;
        sc[c] = s; m = fmaxf(m, s);
    }
    #pragma unroll
    for (int o = 1; o < 64; o <<= 1) m = fmaxf(m, __shfl_xor(m, o));
    float sum = 0.f;
    #pragma unroll
    for (int c = 0; c < 16; c++) { sc[c] = __expf(sc[c] - m); sum += sc[c]; }
    #pragma unroll
    for (int o = 1; o < 64; o <<= 1) sum += __shfl_xor(sum, o);
    float inv = 1.0f / sum;
    #pragma unroll
    for (int c = 0; c < 16; c++) A[row * 1024 + c * 64 + lane] = f2bf(sc[c] * inv);
}

// ---------------------------------------------------------------------------
// K5: bf16 transpose, 64x64 tiles. src row stride srs, dst row stride drs,
// per-batch strides sbs/dbs. dst[j][i] = src[i][j].
// grid: (rows/64, cols/64, nbatch)
// ---------------------------------------------------------------------------
__global__ __launch_bounds__(256) void k_transpose(
    const u16* __restrict__ src, u16* __restrict__ dst,
    int srs, int drs, long sbs, long dbs)
{
    __shared__ u16 tile[64 * 72];
    const u16* s = src + (long)blockIdx.z * sbs;
    u16* d = dst + (long)blockIdx.z * dbs;
    int i0 = blockIdx.x * 64, j0 = blockIdx.y * 64;
    int t = threadIdx.x;
    int r = t >> 2, c0 = (t & 3) << 4;
    #pragma unroll
    for (int p = 0; p < 2; p++) {
        int c = c0 + p * 8;
        uint4 v = *(const uint4*)(s + (long)(i0 + r) * srs + j0 + c);
        *(uint4*)(&tile[r * 72 + c]) = v;
    }
    __syncthreads();
    #pragma unroll
    for (int p = 0; p < 2; p++) {
        uint4 ov;
        u16* po = (u16*)&ov;
        #pragma unroll
        for (int e = 0; e < 8; e++) po[e] = tile[(c0 + p * 8 + e) * 72 + r];
        *(uint4*)(d + (long)(j0 + r) * drs + i0 + c0 + p * 8) = ov;
    }
}

// ---------------------------------------------------------------------------
// K6: fused prob_log/sigmoid/row-norm -> F bf16
// one wave per row; M1/M2/M3 are [8192][1024] bf16
// ---------------------------------------------------------------------------
__global__ __launch_bounds__(256) void k_fused(
    const u16* __restrict__ M1, const u16* __restrict__ M2,
    const u16* __restrict__ M3, const float* __restrict__ fw,
    const float* __restrict__ fbv, int hop, u16* __restrict__ F)
{
    int t = threadIdx.x, lane = t & 63, w = t >> 6;
    long row = (long)blockIdx.x * 4 + w;
    const u16* r1 = M1 + row * 1024;
    const u16* r2 = M2 + row * 1024;
    const u16* r3 = M3 + row * 1024;
    float m1[16], m2[16], m3[16];
    float s1 = 0.f, s2 = 0.f, s3 = 0.f;
    #pragma unroll
    for (int c = 0; c < 16; c++) {
        int j = c * 64 + lane;
        m1[c] = bf2f(r1[j]); m2[c] = bf2f(r2[j]); m3[c] = bf2f(r3[j]);
        s1 += m1[c]; s2 += m2[c]; s3 += m3[c];
    }
    #pragma unroll
    for (int o = 1; o < 64; o <<= 1) {
        s1 += __shfl_xor(s1, o); s2 += __shfl_xor(s2, o); s3 += __shfl_xor(s3, o);
    }
    float i1 = 1.f / (s1 + 1e-6f), i2 = 1.f / (s2 + 1e-6f), i3 = 1.f / (s3 + 1e-6f);
    float w0 = fw[hop * 3], w1 = fw[hop * 3 + 1], w2 = fw[hop * 3 + 2], b0 = fbv[hop];
    float sig[16];
    float ssum = 0.f;
    #pragma unroll
    for (int c = 0; c < 16; c++) {
        float p1 = fminf(fmaxf(m1[c] * i1, 1e-6f), 1.0f - 1e-6f);
        float p2 = fminf(fmaxf(m2[c] * i2, 1e-6f), 1.0f - 1e-6f);
        float p3 = fminf(fmaxf(m3[c] * i3, 1e-6f), 1.0f - 1e-6f);
        float l1 = __logf(p1 / (1.0f - p1 + 1e-6f));
        float l2 = __logf(p2 / (1.0f - p2 + 1e-6f));
        float l3 = __logf(p3 / (1.0f - p3 + 1e-6f));
        float lg = b0 + w0 * l1 + w1 * l2 + w2 * l3;
        float sg = 1.0f / (1.0f + __expf(-lg));
        sig[c] = sg; ssum += sg;
    }
    #pragma unroll
    for (int o = 1; o < 64; o <<= 1) ssum += __shfl_xor(ssum, o);
    float inv = 1.0f / (ssum + 1e-6f);
    #pragma unroll
    for (int c = 0; c < 16; c++) F[row * 1024 + c * 64 + lane] = f2bf(sig[c] * inv);
}

// ---------------------------------------------------------------------------
// K7: gate-combine hop outputs -> combined bf16 [8192][64]
// ---------------------------------------------------------------------------
__global__ __launch_bounds__(256) void k_combine(
    const float* __restrict__ h0, const float* __restrict__ h1,
    const float* __restrict__ gate, u16* __restrict__ comb)
{
    long idx = (long)blockIdx.x * 256 + threadIdx.x;   // 8192*64
    long row = idx >> 6;
    float g0 = gate[row * 2], g1 = gate[row * 2 + 1];
    comb[idx] = f2bf(h0[idx] * g0 + h1[idx] * g1);
}

// ---------------------------------------------------------------------------
extern "C" void kernel_launch(void* const* d_in, const int* in_sizes, int n_in,
                              void* d_out, int out_size, void* d_ws, size_t ws_size,
                              hipStream_t stream) {
    const float* x    = (const float*)d_in[0];
    const float* Wq   = (const float*)d_in[1];
    const float* Wk   = (const float*)d_in[2];
    const float* Wv   = (const float*)d_in[3];
    const float* btab = (const float*)d_in[4];
    const float* fw   = (const float*)d_in[5];
    const float* fbv  = (const float*)d_in[6];
    const float* hopW = (const float*)d_in[7];
    const float* gW   = (const float*)d_in[8];
    const float* gb   = (const float*)d_in[9];
    const float* outW = (const float*)d_in[10];
    const float* temp = (const float*)d_in[11];
    float* out = (float*)d_out;

    // workspace carve-up (~158 MB)
    char* wsb = (char*)d_ws;
    size_t off = 0;
    auto take = [&](size_t n) { char* p = wsb + off; off += (n + 255) & ~(size_t)255; return p; };
    u16* Qb      = (u16*)take(8192L * 64 * 2);
    u16* Kb      = (u16*)take(8192L * 64 * 2);
    u16* Vb      = (u16*)take(8192L * 64 * 2);
    float* gate  = (float*)take(8192L * 2 * 4);
    u16* wpack   = (u16*)take(256L * 512 * 2);
    u16* hopWb   = (u16*)take(2L * 64 * 64 * 2);
    u16* outWb   = (u16*)take(512L * 64 * 2);
    u16* hopvC   = (u16*)take(8192L * 128 * 2);      // [s][hop*64+e]
    u16* hopVT   = (u16*)take(2L * 8 * 64 * 1024 * 2);
    float* houts = (float*)take(2L * 8 * 1024 * 64 * 4);
    u16* comb    = (u16*)take(8192L * 64 * 2);
    float* scoresF = (float*)take(8L * 1024 * 1024 * 4);
    float* QKVG  = (float*)scoresF;                   // alias: dead before scores written
    u16* F       = (u16*)scoresF;                     // alias: scores dead before F written
    u16* A       = (u16*)take(8L * 1024 * 1024 * 2);
    u16* xb      = (u16*)A;                           // alias: xb dead before A written
    u16* AT      = (u16*)take(8L * 1024 * 1024 * 2);
    u16* AAt     = (u16*)take(8L * 1024 * 1024 * 2);
    u16* AtA     = (u16*)take(8L * 1024 * 1024 * 2);
    u16* A2      = (u16*)take(8L * 1024 * 1024 * 2);
    u16* AAt2    = (u16*)take(8L * 1024 * 1024 * 2);
    u16* AtA2    = (u16*)take(8L * 1024 * 1024 * 2);
    (void)ws_size; (void)in_sizes; (void)n_in; (void)out_size;

    const long SD = (long)SS * DD;        // 65536
    const long SSq = (long)SS * SS;       // 1048576

    // 1. pack x + weights to bf16
    k_packx<<<4096, 256, 0, stream>>>(x, xb);
    k_packw<<<672, 256, 0, stream>>>(Wq, Wk, Wv, gW, hopW, outW, wpack, hopWb, outWb);
    // 2. fused projection: QKVG[8192][256] = xb @ wpack^T  (fp32 out)
    gemm_nt<<<dim3(64, 2, 1), 256, 0, stream>>>(xb, 0, wpack, 0, QKVG, 0, 8192, 256, 512, 1);
    // 3. rope + gate + Vb
    k_rope<<<2048, 256, 0, stream>>>(QKVG, gb, Qb, Kb, Vb, gate);
    // 4. hop_v: hopvC[8192][128] = Vb @ hopWb^T ; then transpose to hopVT [hop][b][e][s]
    gemm_nt<<<dim3(64, 1, 1), 256, 0, stream>>>(Vb, 0, hopWb, 0, hopvC, 0, 8192, 128, 64, 0);
    k_transpose<<<dim3(16, 1, 8), 256, 0, stream>>>(hopvC, hopVT, 128, 1024, 1024L * 128, 65536L);
    k_transpose<<<dim3(16, 1, 8), 256, 0, stream>>>(hopvC + 64, hopVT + 8L * 65536, 128, 1024, 1024L * 128, 65536L);
    // 5. scores = Q K^T  (fp32 out)
    gemm_nt<<<dim3(8, 8, 8), 256, 0, stream>>>(Qb, SD, Kb, SD, scoresF, SSq, 1024, 1024, 64, 1);
    // 6. softmax -> A (bf16)
    k_softmax<<<2048, 256, 0, stream>>>(scoresF, btab, temp, A);
    // 7. AT
    k_transpose<<<dim3(16, 16, 8), 256, 0, stream>>>(A, AT, 1024, 1024, SSq, SSq);
    // 8. AAt = A A^T ; AtA = (AT)(AT)^T
    gemm_nt<<<dim3(8, 8, 8), 256, 0, stream>>>(A, SSq, A, SSq, AAt, SSq, 1024, 1024, 1024, 0);
    gemm_nt<<<dim3(8, 8, 8), 256, 0, stream>>>(AT, SSq, AT, SSq, AtA, SSq, 1024, 1024, 1024, 0);
    // 9. hop 0 fused -> F ; hop_out0 = F @ hopV0
    k_fused<<<2048, 256, 0, stream>>>(A, AAt, AtA, fw, fbv, 0, F);
    gemm_nt<<<dim3(8, 1, 8), 256, 0, stream>>>(F, SSq, hopVT, SD, houts, SD, 1024, 64, 1024, 1);
    // 10. squares for hop 1
    gemm_nt<<<dim3(8, 8, 8), 256, 0, stream>>>(A, SSq, AT, SSq, A2, SSq, 1024, 1024, 1024, 0);
    gemm_nt<<<dim3(8, 8, 8), 256, 0, stream>>>(AAt, SSq, AAt, SSq, AAt2, SSq, 1024, 1024, 1024, 0);
    gemm_nt<<<dim3(8, 8, 8), 256, 0, stream>>>(AtA, SSq, AtA, SSq, AtA2, SSq, 1024, 1024, 1024, 0);
    // 11. hop 1 fused -> F ; hop_out1
    k_fused<<<2048, 256, 0, stream>>>(A2, AAt2, AtA2, fw, fbv, 1, F);
    gemm_nt<<<dim3(8, 1, 8), 256, 0, stream>>>(F, SSq, hopVT + 8L * 65536, SD,
                                               houts + (long)BB * SS * DD, SD, 1024, 64, 1024, 1);
    // 12. combine + output projection
    k_combine<<<2048, 256, 0, stream>>>(houts, houts + (long)BB * SS * DD, gate, comb);
    gemm_nt<<<dim3(64, 4, 1), 256, 0, stream>>>(comb, 0, outWb, 0, out, 0, 8192, 512, 64, 1);
}

// Round 3
// 448.217 us; speedup vs baseline: 1.1622x; 1.0639x over previous
//
#include <hip/hip_runtime.h>
#include <hip/hip_bf16.h>

// Problem constants
#define BB 8
#define SS 1024
#define HH 512
#define DD 64

typedef unsigned short u16;
typedef short v8s __attribute__((ext_vector_type(8)));   // 8 x bf16 (bit pattern)
typedef float v4f __attribute__((ext_vector_type(4)));

__device__ __forceinline__ float bf2f(u16 u) {
    union { unsigned int i; float f; } v; v.i = ((unsigned int)u) << 16; return v.f;
}
__device__ __forceinline__ u16 f2bf(float f) {
    union { float f; unsigned int i; } v; v.f = f;
    unsigned int u = v.i;
    unsigned int r = u + 0x7fffu + ((u >> 16) & 1u);   // RNE
    return (u16)(r >> 16);
}

// async 16B global->LDS DMA: lane L's data lands at ldsbase + L*16
__device__ __forceinline__ void gload16(const u16* g, u16* l) {
    __builtin_amdgcn_global_load_lds(
        (const __attribute__((address_space(1))) void*)g,
        (__attribute__((address_space(3))) void*)l,
        16, 0, 0);
}

// ---------------------------------------------------------------------------
// K0a: x (fp32, 8192x512) -> bf16, vectorized
// ---------------------------------------------------------------------------
__global__ __launch_bounds__(256) void k_packx(const float* __restrict__ src,
                                               u16* __restrict__ dst)
{
    long i = (long)blockIdx.x * 256 + threadIdx.x;  // over float4 units (1M total)
    float4 v = ((const float4*)src)[i];
    ushort4 o;
    o.x = f2bf(v.x); o.y = f2bf(v.y); o.z = f2bf(v.z); o.w = f2bf(v.w);
    ((ushort4*)dst)[i] = o;
}

// ---------------------------------------------------------------------------
// K0b: pack weights to bf16.
//  wpack [256][512]: rows 0-63 Wq, 64-127 Wk, 128-191 Wv, 192-193 gate_W, rest 0
//  hopWb [2*64][64] (= hopW layout), outWb [512][64]
// ---------------------------------------------------------------------------
__global__ __launch_bounds__(256) void k_packw(
    const float* __restrict__ Wq, const float* __restrict__ Wk,
    const float* __restrict__ Wv, const float* __restrict__ gW,
    const float* __restrict__ hopW, const float* __restrict__ outW,
    u16* __restrict__ wpack, u16* __restrict__ hopWb, u16* __restrict__ outWb)
{
    int idx = blockIdx.x * 256 + threadIdx.x;
    if (idx < 131072) {
        int r = idx >> 9, c = idx & 511;
        float v = 0.f;
        if (r < 64)       v = Wq[r * 512 + c];
        else if (r < 128) v = Wk[(r - 64) * 512 + c];
        else if (r < 192) v = Wv[(r - 128) * 512 + c];
        else if (r < 194) v = gW[(r - 192) * 512 + c];
        wpack[idx] = f2bf(v);
    } else if (idx < 131072 + 8192) {
        int i = idx - 131072;
        hopWb[i] = f2bf(hopW[i]);
    } else if (idx < 131072 + 8192 + 32768) {
        int i = idx - 131072 - 8192;
        outWb[i] = f2bf(outW[i]);
    }
}

// ---------------------------------------------------------------------------
// K2: RoPE (QKVG fp32 -> bf16 Qb/Kb), Vb bf16, gate softmax
// one wave per row, 4 rows per block
// ---------------------------------------------------------------------------
__global__ __launch_bounds__(256) void k_rope(
    const float* __restrict__ QKVG, const float* __restrict__ gateb,
    u16* __restrict__ Qb, u16* __restrict__ Kb, u16* __restrict__ Vb,
    float* __restrict__ gate)
{
    int t = threadIdx.x, l = t & 63, w = t >> 6;
    long row = (long)blockIdx.x * 4 + w;       // 0..8191
    int spos = (int)(row & (SS - 1));
    const float* base = QKVG + row * 256;
    float q = base[l], k = base[64 + l], v = base[128 + l];
    float qp = __shfl_xor(q, 32), kp = __shfl_xor(k, 32);
    float sgn = (l < 32) ? -1.f : 1.f;
    int f = l & 31;
    float ang = (float)spos * exp2f(-(float)f * (13.287712379549449f / 32.0f));
    float cs = cosf(ang), sn = sinf(ang);
    Qb[row * 64 + l] = f2bf(q * cs + sgn * qp * sn);
    Kb[row * 64 + l] = f2bf(k * cs + sgn * kp * sn);
    Vb[row * 64 + l] = f2bf(v);
    if (l < 2) {
        float g0 = base[192] + gateb[0], g1 = base[193] + gateb[1];
        float m = fmaxf(g0, g1);
        float e0 = __expf(g0 - m), e1 = __expf(g1 - m);
        gate[row * 2 + l] = ((l == 0) ? e0 : e1) / (e0 + e1);
    }
}

// ---------------------------------------------------------------------------
// Batched NT GEMM:  C[b] = X[b] (MxK) * Y[b]^T (NxK), bf16 in, fp32 acc
// 128x128 tile, 4 waves of 64x64, mfma_f32_16x16x32_bf16.
// Staging via global_load_lds (16B/lane DMA). LDS rows are 32 shorts (64B),
// unpadded; bank conflicts broken by XOR chunk swizzle: logical 16B chunk c
// of local row r is stored at physical chunk c ^ ((r>>1)&3). This makes each
// fixed-q fragment read hit all 8 chunk-slots exactly 2x -> 2-way = free.
// C written bf16 (cf32=0) or fp32 (cf32=1). K multiple of 32; staging rows
// clamped, stores guarded.
// ---------------------------------------------------------------------------
__global__ __launch_bounds__(256) void gemm_nt(
    const u16* __restrict__ X, long sx,
    const u16* __restrict__ Y, long sy,
    void* __restrict__ Cv, long sc,
    int M, int N, int K, int cf32)
{
    __shared__ u16 Xs[128 * 32];   // 8 KB
    __shared__ u16 Ys[128 * 32];   // 8 KB
    const u16* Xb = X + (long)blockIdx.z * sx;
    const u16* Yb = Y + (long)blockIdx.z * sy;
    int tm = blockIdx.x * 128, tn = blockIdx.y * 128;
    int t = threadIdx.x, lane = t & 63, w = t >> 6;
    int wm = (w & 1) << 6, wn = (w >> 1) << 6;
    int fr = lane & 15, q = lane >> 4;

    // staging geometry: wave w stages local rows [32w, 32w+32) of X and Y.
    // lane L covers local row srow0 + L/4 (first instr) / +16 (second),
    // physical chunk p = L%3... p = L&3; global column = (p ^ ((r>>1)&3))*8.
    int srow0 = w << 5;
    int r1 = srow0 + (lane >> 2);
    int r2 = r1 + 16;
    int p = lane & 3;
    int kc1 = ((p ^ ((r1 >> 1) & 3)) << 3);
    int kc2 = ((p ^ ((r2 >> 1) & 3)) << 3);
    int xr1 = tm + r1; if (xr1 >= M) xr1 = M - 1;
    int xr2 = tm + r2; if (xr2 >= M) xr2 = M - 1;
    int yr1 = tn + r1; if (yr1 >= N) yr1 = N - 1;
    int yr2 = tn + r2; if (yr2 >= N) yr2 = N - 1;
    const u16* xg1 = Xb + (long)xr1 * K + kc1;
    const u16* xg2 = Xb + (long)xr2 * K + kc2;
    const u16* yg1 = Yb + (long)yr1 * K + kc1;
    const u16* yg2 = Yb + (long)yr2 * K + kc2;
    u16* xl1 = Xs + srow0 * 32;
    u16* xl2 = Xs + (srow0 + 16) * 32;
    u16* yl1 = Ys + srow0 * 32;
    u16* yl2 = Ys + (srow0 + 16) * 32;

    v4f acc[4][4];
    #pragma unroll
    for (int i = 0; i < 4; i++)
        #pragma unroll
        for (int j = 0; j < 4; j++) {
            acc[i][j][0] = 0.f; acc[i][j][1] = 0.f; acc[i][j][2] = 0.f; acc[i][j][3] = 0.f;
        }

    for (int k0 = 0; k0 < K; k0 += 32) {
        __syncthreads();
        gload16(xg1 + k0, xl1);
        gload16(xg2 + k0, xl2);
        gload16(yg1 + k0, yl1);
        gload16(yg2 + k0, yl2);
        __syncthreads();
        v8s af[4], bfr[4];
        #pragma unroll
        for (int s = 0; s < 4; s++) {
            int Ra = wm + s * 16 + fr;
            int Rb = wn + s * 16 + fr;
            af[s]  = *(const v8s*)(Xs + Ra * 32 + ((q ^ ((Ra >> 1) & 3)) << 3));
            bfr[s] = *(const v8s*)(Ys + Rb * 32 + ((q ^ ((Rb >> 1) & 3)) << 3));
        }
        #pragma unroll
        for (int i = 0; i < 4; i++)
            #pragma unroll
            for (int j = 0; j < 4; j++)
                acc[i][j] = __builtin_amdgcn_mfma_f32_16x16x32_bf16(af[i], bfr[j], acc[i][j], 0, 0, 0);
    }
    long cb = (long)blockIdx.z * sc;
    #pragma unroll
    for (int i = 0; i < 4; i++) {
        int rowb = tm + wm + i * 16 + q * 4;
        #pragma unroll
        for (int j = 0; j < 4; j++) {
            int col = tn + wn + j * 16 + fr;
            if (col < N) {
                #pragma unroll
                for (int r = 0; r < 4; r++) {
                    int row = rowb + r;
                    if (row < M) {
                        if (cf32) ((float*)Cv)[cb + (long)row * N + col] = acc[i][j][r];
                        else      ((u16*)Cv)[cb + (long)row * N + col] = f2bf(acc[i][j][r]);
                    }
                }
            }
        }
    }
}

// ---------------------------------------------------------------------------
// K4: softmax over scores rows (+ bias from table, /sqrt(d), /temp) -> A bf16
// one wave per row
// ---------------------------------------------------------------------------
__global__ __launch_bounds__(256) void k_softmax(
    const float* __restrict__ scores, const float* __restrict__ btab,
    const float* __restrict__ temp, u16* __restrict__ A)
{
    __shared__ float bt[63 * 63];
    int t = threadIdx.x;
    for (int i = t; i < 3969; i += 256) bt[i] = btab[i];
    __syncthreads();
    int lane = t & 63, w = t >> 6;
    long row = (long)blockIdx.x * 4 + w;
    int i = (int)(row & 1023);
    int ih = i >> 5, iw = i & 31;
    float inv_t = 1.0f / fmaxf(temp[0], 0.1f);
    const float* srow = scores + row * 1024;
    float sc[16];
    float m = -1e30f;
    #pragma unroll
    for (int c = 0; c < 16; c++) {
        int j = c * 64 + lane;
        int jh = j >> 5, jw = j & 31;
        float pb = bt[(ih - jh + 31) * 63 + (iw - jw + 31)];
        float s = (srow[j] * 0.125f + pb) * inv_t;
        sc[c] = s; m = fmaxf(m, s);
    }
    #pragma unroll
    for (int o = 1; o < 64; o <<= 1) m = fmaxf(m, __shfl_xor(m, o));
    float sum = 0.f;
    #pragma unroll
    for (int c = 0; c < 16; c++) { sc[c] = __expf(sc[c] - m); sum += sc[c]; }
    #pragma unroll
    for (int o = 1; o < 64; o <<= 1) sum += __shfl_xor(sum, o);
    float inv = 1.0f / sum;
    #pragma unroll
    for (int c = 0; c < 16; c++) A[row * 1024 + c * 64 + lane] = f2bf(sc[c] * inv);
}

// ---------------------------------------------------------------------------
// K5: bf16 transpose, 64x64 tiles. src row stride srs, dst row stride drs,
// per-batch strides sbs/dbs. dst[j][i] = src[i][j].
// grid: (rows/64, cols/64, nbatch)
// ---------------------------------------------------------------------------
__global__ __launch_bounds__(256) void k_transpose(
    const u16* __restrict__ src, u16* __restrict__ dst,
    int srs, int drs, long sbs, long dbs)
{
    __shared__ u16 tile[64 * 72];
    const u16* s = src + (long)blockIdx.z * sbs;
    u16* d = dst + (long)blockIdx.z * dbs;
    int i0 = blockIdx.x * 64, j0 = blockIdx.y * 64;
    int t = threadIdx.x;
    int r = t >> 2, c0 = (t & 3) << 4;
    #pragma unroll
    for (int p = 0; p < 2; p++) {
        int c = c0 + p * 8;
        uint4 v = *(const uint4*)(s + (long)(i0 + r) * srs + j0 + c);
        *(uint4*)(&tile[r * 72 + c]) = v;
    }
    __syncthreads();
    #pragma unroll
    for (int p = 0; p < 2; p++) {
        uint4 ov;
        u16* po = (u16*)&ov;
        #pragma unroll
        for (int e = 0; e < 8; e++) po[e] = tile[(c0 + p * 8 + e) * 72 + r];
        *(uint4*)(d + (long)(j0 + r) * drs + i0 + c0 + p * 8) = ov;
    }
}

// ---------------------------------------------------------------------------
// K6: fused prob_log/sigmoid/row-norm -> F bf16
// one wave per row; M1/M2/M3 are [8192][1024] bf16
// ---------------------------------------------------------------------------
__global__ __launch_bounds__(256) void k_fused(
    const u16* __restrict__ M1, const u16* __restrict__ M2,
    const u16* __restrict__ M3, const float* __restrict__ fw,
    const float* __restrict__ fbv, int hop, u16* __restrict__ F)
{
    int t = threadIdx.x, lane = t & 63, w = t >> 6;
    long row = (long)blockIdx.x * 4 + w;
    const u16* r1 = M1 + row * 1024;
    const u16* r2 = M2 + row * 1024;
    const u16* r3 = M3 + row * 1024;
    float m1[16], m2[16], m3[16];
    float s1 = 0.f, s2 = 0.f, s3 = 0.f;
    #pragma unroll
    for (int c = 0; c < 16; c++) {
        int j = c * 64 + lane;
        m1[c] = bf2f(r1[j]); m2[c] = bf2f(r2[j]); m3[c] = bf2f(r3[j]);
        s1 += m1[c]; s2 += m2[c]; s3 += m3[c];
    }
    #pragma unroll
    for (int o = 1; o < 64; o <<= 1) {
        s1 += __shfl_xor(s1, o); s2 += __shfl_xor(s2, o); s3 += __shfl_xor(s3, o);
    }
    float i1 = 1.f / (s1 + 1e-6f), i2 = 1.f / (s2 + 1e-6f), i3 = 1.f / (s3 + 1e-6f);
    float w0 = fw[hop * 3], w1 = fw[hop * 3 + 1], w2 = fw[hop * 3 + 2], b0 = fbv[hop];
    float sig[16];
    float ssum = 0.f;
    #pragma unroll
    for (int c = 0; c < 16; c++) {
        float p1 = fminf(fmaxf(m1[c] * i1, 1e-6f), 1.0f - 1e-6f);
        float p2 = fminf(fmaxf(m2[c] * i2, 1e-6f), 1.0f - 1e-6f);
        float p3 = fminf(fmaxf(m3[c] * i3, 1e-6f), 1.0f - 1e-6f);
        float l1 = __logf(p1 / (1.0f - p1 + 1e-6f));
        float l2 = __logf(p2 / (1.0f - p2 + 1e-6f));
        float l3 = __logf(p3 / (1.0f - p3 + 1e-6f));
        float lg = b0 + w0 * l1 + w1 * l2 + w2 * l3;
        float sg = 1.0f / (1.0f + __expf(-lg));
        sig[c] = sg; ssum += sg;
    }
    #pragma unroll
    for (int o = 1; o < 64; o <<= 1) ssum += __shfl_xor(ssum, o);
    float inv = 1.0f / (ssum + 1e-6f);
    #pragma unroll
    for (int c = 0; c < 16; c++) F[row * 1024 + c * 64 + lane] = f2bf(sig[c] * inv);
}

// ---------------------------------------------------------------------------
// K7: gate-combine hop outputs -> combined bf16 [8192][64]
// ---------------------------------------------------------------------------
__global__ __launch_bounds__(256) void k_combine(
    const float* __restrict__ h0, const float* __restrict__ h1,
    const float* __restrict__ gate, u16* __restrict__ comb)
{
    long idx = (long)blockIdx.x * 256 + threadIdx.x;   // 8192*64
    long row = idx >> 6;
    float g0 = gate[row * 2], g1 = gate[row * 2 + 1];
    comb[idx] = f2bf(h0[idx] * g0 + h1[idx] * g1);
}

// ---------------------------------------------------------------------------
extern "C" void kernel_launch(void* const* d_in, const int* in_sizes, int n_in,
                              void* d_out, int out_size, void* d_ws, size_t ws_size,
                              hipStream_t stream) {
    const float* x    = (const float*)d_in[0];
    const float* Wq   = (const float*)d_in[1];
    const float* Wk   = (const float*)d_in[2];
    const float* Wv   = (const float*)d_in[3];
    const float* btab = (const float*)d_in[4];
    const float* fw   = (const float*)d_in[5];
    const float* fbv  = (const float*)d_in[6];
    const float* hopW = (const float*)d_in[7];
    const float* gW   = (const float*)d_in[8];
    const float* gb   = (const float*)d_in[9];
    const float* outW = (const float*)d_in[10];
    const float* temp = (const float*)d_in[11];
    float* out = (float*)d_out;

    // workspace carve-up (~158 MB)
    char* wsb = (char*)d_ws;
    size_t off = 0;
    auto take = [&](size_t n) { char* p = wsb + off; off += (n + 255) & ~(size_t)255; return p; };
    u16* Qb      = (u16*)take(8192L * 64 * 2);
    u16* Kb      = (u16*)take(8192L * 64 * 2);
    u16* Vb      = (u16*)take(8192L * 64 * 2);
    float* gate  = (float*)take(8192L * 2 * 4);
    u16* wpack   = (u16*)take(256L * 512 * 2);
    u16* hopWb   = (u16*)take(2L * 64 * 64 * 2);
    u16* outWb   = (u16*)take(512L * 64 * 2);
    u16* hopvC   = (u16*)take(8192L * 128 * 2);      // [s][hop*64+e]
    u16* hopVT   = (u16*)take(2L * 8 * 64 * 1024 * 2);
    float* houts = (float*)take(2L * 8 * 1024 * 64 * 4);
    u16* comb    = (u16*)take(8192L * 64 * 2);
    float* scoresF = (float*)take(8L * 1024 * 1024 * 4);
    float* QKVG  = (float*)scoresF;                   // alias: dead before scores written
    u16* F       = (u16*)scoresF;                     // alias: scores dead before F written
    u16* A       = (u16*)take(8L * 1024 * 1024 * 2);
    u16* xb      = (u16*)A;                           // alias: xb dead before A written
    u16* AT      = (u16*)take(8L * 1024 * 1024 * 2);
    u16* AAt     = (u16*)take(8L * 1024 * 1024 * 2);
    u16* AtA     = (u16*)take(8L * 1024 * 1024 * 2);
    u16* A2      = (u16*)take(8L * 1024 * 1024 * 2);
    u16* AAt2    = (u16*)take(8L * 1024 * 1024 * 2);
    u16* AtA2    = (u16*)take(8L * 1024 * 1024 * 2);
    (void)ws_size; (void)in_sizes; (void)n_in; (void)out_size;

    const long SD = (long)SS * DD;        // 65536
    const long SSq = (long)SS * SS;       // 1048576

    // 1. pack x + weights to bf16
    k_packx<<<4096, 256, 0, stream>>>(x, xb);
    k_packw<<<672, 256, 0, stream>>>(Wq, Wk, Wv, gW, hopW, outW, wpack, hopWb, outWb);
    // 2. fused projection: QKVG[8192][256] = xb @ wpack^T  (fp32 out)
    gemm_nt<<<dim3(64, 2, 1), 256, 0, stream>>>(xb, 0, wpack, 0, QKVG, 0, 8192, 256, 512, 1);
    // 3. rope + gate + Vb
    k_rope<<<2048, 256, 0, stream>>>(QKVG, gb, Qb, Kb, Vb, gate);
    // 4. hop_v: hopvC[8192][128] = Vb @ hopWb^T ; then transpose to hopVT [hop][b][e][s]
    gemm_nt<<<dim3(64, 1, 1), 256, 0, stream>>>(Vb, 0, hopWb, 0, hopvC, 0, 8192, 128, 64, 0);
    k_transpose<<<dim3(16, 1, 8), 256, 0, stream>>>(hopvC, hopVT, 128, 1024, 1024L * 128, 65536L);
    k_transpose<<<dim3(16, 1, 8), 256, 0, stream>>>(hopvC + 64, hopVT + 8L * 65536, 128, 1024, 1024L * 128, 65536L);
    // 5. scores = Q K^T  (fp32 out)
    gemm_nt<<<dim3(8, 8, 8), 256, 0, stream>>>(Qb, SD, Kb, SD, scoresF, SSq, 1024, 1024, 64, 1);
    // 6. softmax -> A (bf16)
    k_softmax<<<2048, 256, 0, stream>>>(scoresF, btab, temp, A);
    // 7. AT
    k_transpose<<<dim3(16, 16, 8), 256, 0, stream>>>(A, AT, 1024, 1024, SSq, SSq);
    // 8. AAt = A A^T ; AtA = (AT)(AT)^T
    gemm_nt<<<dim3(8, 8, 8), 256, 0, stream>>>(A, SSq, A, SSq, AAt, SSq, 1024, 1024, 1024, 0);
    gemm_nt<<<dim3(8, 8, 8), 256, 0, stream>>>(AT, SSq, AT, SSq, AtA, SSq, 1024, 1024, 1024, 0);
    // 9. hop 0 fused -> F ; hop_out0 = F @ hopV0
    k_fused<<<2048, 256, 0, stream>>>(A, AAt, AtA, fw, fbv, 0, F);
    gemm_nt<<<dim3(8, 1, 8), 256, 0, stream>>>(F, SSq, hopVT, SD, houts, SD, 1024, 64, 1024, 1);
    // 10. squares for hop 1
    gemm_nt<<<dim3(8, 8, 8), 256, 0, stream>>>(A, SSq, AT, SSq, A2, SSq, 1024, 1024, 1024, 0);
    gemm_nt<<<dim3(8, 8, 8), 256, 0, stream>>>(AAt, SSq, AAt, SSq, AAt2, SSq, 1024, 1024, 1024, 0);
    gemm_nt<<<dim3(8, 8, 8), 256, 0, stream>>>(AtA, SSq, AtA, SSq, AtA2, SSq, 1024, 1024, 1024, 0);
    // 11. hop 1 fused -> F ; hop_out1
    k_fused<<<2048, 256, 0, stream>>>(A2, AAt2, AtA2, fw, fbv, 1, F);
    gemm_nt<<<dim3(8, 1, 8), 256, 0, stream>>>(F, SSq, hopVT + 8L * 65536, SD,
                                               houts + (long)BB * SS * DD, SD, 1024, 64, 1024, 1);
    // 12. combine + output projection
    k_combine<<<2048, 256, 0, stream>>>(houts, houts + (long)BB * SS * DD, gate, comb);
    gemm_nt<<<dim3(64, 4, 1), 256, 0, stream>>>(comb, 0, outWb, 0, out, 0, 8192, 512, 64, 1);
}

// Round 4
// 364.942 us; speedup vs baseline: 1.4274x; 1.2282x over previous
//
#include <hip/hip_runtime.h>
#include <hip/hip_bf16.h>

// Problem constants
#define BB 8
#define SS 1024
#define HH 512
#define DD 64

typedef unsigned short u16;
typedef short v8s __attribute__((ext_vector_type(8)));   // 8 x bf16 (bit pattern)
typedef float v4f __attribute__((ext_vector_type(4)));

__device__ __forceinline__ float bf2f(u16 u) {
    union { unsigned int i; float f; } v; v.i = ((unsigned int)u) << 16; return v.f;
}
__device__ __forceinline__ u16 f2bf(float f) {
    union { float f; unsigned int i; } v; v.f = f;
    unsigned int u = v.i;
    unsigned int r = u + 0x7fffu + ((u >> 16) & 1u);   // RNE
    return (u16)(r >> 16);
}

// async 16B global->LDS DMA: lane L's data lands at ldsbase + L*16
__device__ __forceinline__ void gload16(const u16* g, u16* l) {
    __builtin_amdgcn_global_load_lds(
        (const __attribute__((address_space(1))) void*)g,
        (__attribute__((address_space(3))) void*)l,
        16, 0, 0);
}

// ---------------------------------------------------------------------------
// Shared GEMM geometry (BK=64):
// LDS tile rows of 64 bf16 = 8 chunks of 16B. Physical chunk p of row r holds
// logical chunk p ^ (r&7)  (XOR swizzle -> conflict-free b128 reads).
// Staging: thread t=64w+lane, instr i: row = i*32 + w*8 + (lane>>3),
//          phys chunk = lane&7, so global col chunk = (lane&7) ^ (lane>>3).
// ---------------------------------------------------------------------------

// ---------------------------------------------------------------------------
// Generic batched NT GEMM: C[z] = X[z] (MxK) * Y[z]^T (NxK), bf16 in, fp32 acc
// 128x128 tile, 4 waves 64x64, BK=64. M,N multiples of 128; K multiple of 64.
// ---------------------------------------------------------------------------
__global__ __launch_bounds__(256) void gemm_nt(
    const u16* __restrict__ X, long sx,
    const u16* __restrict__ Y, long sy,
    void* __restrict__ Cv, long sc,
    int M, int N, int K, int cf32)
{
    __shared__ u16 Xs[128 * 64];   // 16 KB
    __shared__ u16 Ys[128 * 64];   // 16 KB
    const u16* Xb = X + (long)blockIdx.z * sx;
    const u16* Yb = Y + (long)blockIdx.z * sy;
    int tm = blockIdx.x * 128, tn = blockIdx.y * 128;
    int t = threadIdx.x, lane = t & 63, w = t >> 6;
    int wm = (w & 1) << 6, wn = (w >> 1) << 6;
    int fr = lane & 15, q = lane >> 4, m7 = fr & 7;
    int subrow = lane >> 3, cch = (lane & 7) ^ subrow;

    const u16* xg[4]; const u16* yg[4]; u16* xl[4]; u16* yl[4];
    #pragma unroll
    for (int i = 0; i < 4; i++) {
        int r = i * 32 + w * 8 + subrow;
        xg[i] = Xb + (long)(tm + r) * K + cch * 8;
        yg[i] = Yb + (long)(tn + r) * K + cch * 8;
        xl[i] = Xs + (i * 32 + w * 8) * 64;
        yl[i] = Ys + (i * 32 + w * 8) * 64;
    }

    v4f acc[4][4];
    #pragma unroll
    for (int i = 0; i < 4; i++)
        #pragma unroll
        for (int j = 0; j < 4; j++) {
            acc[i][j][0] = 0.f; acc[i][j][1] = 0.f; acc[i][j][2] = 0.f; acc[i][j][3] = 0.f;
        }

    for (int k0 = 0; k0 < K; k0 += 64) {
        __syncthreads();
        #pragma unroll
        for (int i = 0; i < 4; i++) { gload16(xg[i] + k0, xl[i]); gload16(yg[i] + k0, yl[i]); }
        __syncthreads();
        v8s af[2][4], bfr[2][4];
        #pragma unroll
        for (int h = 0; h < 2; h++) {
            int ca = (((h << 2) + q) ^ m7) << 3;
            #pragma unroll
            for (int s = 0; s < 4; s++) {
                af[h][s]  = *(const v8s*)(Xs + (wm + s * 16 + fr) * 64 + ca);
                bfr[h][s] = *(const v8s*)(Ys + (wn + s * 16 + fr) * 64 + ca);
            }
        }
        #pragma unroll
        for (int h = 0; h < 2; h++)
            #pragma unroll
            for (int i = 0; i < 4; i++)
                #pragma unroll
                for (int j = 0; j < 4; j++)
                    acc[i][j] = __builtin_amdgcn_mfma_f32_16x16x32_bf16(af[h][i], bfr[h][j], acc[i][j], 0, 0, 0);
    }
    long cb = (long)blockIdx.z * sc;
    #pragma unroll
    for (int i = 0; i < 4; i++) {
        int rowb = tm + wm + i * 16 + q * 4;
        #pragma unroll
        for (int j = 0; j < 4; j++) {
            int col = tn + wn + j * 16 + fr;
            #pragma unroll
            for (int r = 0; r < 4; r++) {
                long o = cb + (long)(rowb + r) * N + col;
                if (cf32) ((float*)Cv)[o] = acc[i][j][r];
                else      ((u16*)Cv)[o] = f2bf(acc[i][j][r]);
            }
        }
    }
}

// ---------------------------------------------------------------------------
// Symmetric batched GEMM pair: C = X * X^T (1024x1024, K=1024), upper triangle
// tiles only. z<8 -> (X0,C0) batch z ; z>=8 -> (X1,C1) batch z-8.
// blockIdx.x in [0,36) unranked to tile (i<=j).
// ---------------------------------------------------------------------------
__global__ __launch_bounds__(256) void gemm_sym(
    const u16* __restrict__ X0, const u16* __restrict__ X1,
    u16* __restrict__ C0, u16* __restrict__ C1)
{
    __shared__ u16 Xs[128 * 64];
    __shared__ u16 Ys[128 * 64];
    const long SSq = (long)SS * SS;
    int z = blockIdx.z;
    const u16* Xb = (z < 8 ? X0 : X1) + (long)(z & 7) * SSq;
    u16* Cd = (z < 8 ? C0 : C1) + (long)(z & 7) * SSq;
    int tt = blockIdx.x, ti = 0;
    while (tt >= 8 - ti) { tt -= 8 - ti; ti++; }
    int tj = ti + tt;
    int tm = ti * 128, tn = tj * 128;

    int t = threadIdx.x, lane = t & 63, w = t >> 6;
    int wm = (w & 1) << 6, wn = (w >> 1) << 6;
    int fr = lane & 15, q = lane >> 4, m7 = fr & 7;
    int subrow = lane >> 3, cch = (lane & 7) ^ subrow;

    const u16* xg[4]; const u16* yg[4]; u16* xl[4]; u16* yl[4];
    #pragma unroll
    for (int i = 0; i < 4; i++) {
        int r = i * 32 + w * 8 + subrow;
        xg[i] = Xb + (long)(tm + r) * 1024 + cch * 8;
        yg[i] = Xb + (long)(tn + r) * 1024 + cch * 8;
        xl[i] = Xs + (i * 32 + w * 8) * 64;
        yl[i] = Ys + (i * 32 + w * 8) * 64;
    }

    v4f acc[4][4];
    #pragma unroll
    for (int i = 0; i < 4; i++)
        #pragma unroll
        for (int j = 0; j < 4; j++) {
            acc[i][j][0] = 0.f; acc[i][j][1] = 0.f; acc[i][j][2] = 0.f; acc[i][j][3] = 0.f;
        }

    for (int k0 = 0; k0 < 1024; k0 += 64) {
        __syncthreads();
        #pragma unroll
        for (int i = 0; i < 4; i++) { gload16(xg[i] + k0, xl[i]); gload16(yg[i] + k0, yl[i]); }
        __syncthreads();
        v8s af[2][4], bfr[2][4];
        #pragma unroll
        for (int h = 0; h < 2; h++) {
            int ca = (((h << 2) + q) ^ m7) << 3;
            #pragma unroll
            for (int s = 0; s < 4; s++) {
                af[h][s]  = *(const v8s*)(Xs + (wm + s * 16 + fr) * 64 + ca);
                bfr[h][s] = *(const v8s*)(Ys + (wn + s * 16 + fr) * 64 + ca);
            }
        }
        #pragma unroll
        for (int h = 0; h < 2; h++)
            #pragma unroll
            for (int i = 0; i < 4; i++)
                #pragma unroll
                for (int j = 0; j < 4; j++)
                    acc[i][j] = __builtin_amdgcn_mfma_f32_16x16x32_bf16(af[h][i], bfr[h][j], acc[i][j], 0, 0, 0);
    }
    #pragma unroll
    for (int i = 0; i < 4; i++) {
        int rowb = tm + wm + i * 16 + q * 4;
        #pragma unroll
        for (int j = 0; j < 4; j++) {
            int col = tn + wn + j * 16 + fr;
            #pragma unroll
            for (int r = 0; r < 4; r++)
                Cd[(long)(rowb + r) * 1024 + col] = f2bf(acc[i][j][r]);
        }
    }
}

// ---------------------------------------------------------------------------
// Mirror lower triangle from upper: C[j-tile][i-tile] = C[i][j]^T, 28 off-diag
// tiles, z selects matrix (as gemm_sym).
// ---------------------------------------------------------------------------
__global__ __launch_bounds__(256) void k_mirror(u16* __restrict__ C0, u16* __restrict__ C1)
{
    __shared__ u16 tile[128 * 136];
    const long SSq = (long)SS * SS;
    int z = blockIdx.z;
    u16* C = (z < 8 ? C0 : C1) + (long)(z & 7) * SSq;
    int tt = blockIdx.x, ti = 0;
    while (tt >= 7 - ti) { tt -= 7 - ti; ti++; }
    int tj = ti + 1 + tt;
    int t = threadIdx.x;
    int r = t >> 1, ch = (t & 1) << 6;   // row r, 64-col half
    const u16* src = C + (long)(ti * 128 + r) * 1024 + tj * 128 + ch;
    #pragma unroll
    for (int p = 0; p < 8; p++) {
        uint4 v = *(const uint4*)(src + p * 8);
        *(uint4*)(&tile[r * 136 + ch + p * 8]) = v;
    }
    __syncthreads();
    u16* dst = C + (long)(tj * 128 + r) * 1024 + ti * 128 + ch;
    #pragma unroll
    for (int p = 0; p < 8; p++) {
        uint4 ov; u16* po = (u16*)&ov;
        #pragma unroll
        for (int e = 0; e < 8; e++) po[e] = tile[(ch + p * 8 + e) * 136 + r];
        *(uint4*)(dst + p * 8) = ov;
    }
}

// ---------------------------------------------------------------------------
// Hop-output GEMM: P[y*16+z] (1024x64 fp32 partial) = F[z] (1024x1024) *
// H[z]^T (64x1024), K-range [y*512,(y+1)*512). z = hop*8+b. Tile 128x64,
// wave w -> rows [32w,32w+32).
// ---------------------------------------------------------------------------
__global__ __launch_bounds__(256) void gemm_hop(
    const u16* __restrict__ F0, const u16* __restrict__ F1,
    const u16* __restrict__ H, float* __restrict__ P)
{
    __shared__ u16 Fs[128 * 64];   // 16 KB
    __shared__ u16 Hs[64 * 64];    // 8 KB
    const long SSq = (long)SS * SS;
    int z = blockIdx.z;
    const u16* Fb = (z < 8 ? F0 : F1) + (long)(z & 7) * SSq;
    const u16* Hb = H + (long)z * 65536;
    int tm = blockIdx.x * 128;
    int kb = blockIdx.y * 512;
    int t = threadIdx.x, lane = t & 63, w = t >> 6;
    int fr = lane & 15, q = lane >> 4, m7 = fr & 7;
    int subrow = lane >> 3, cch = (lane & 7) ^ subrow;

    const u16* fg[4]; u16* fl[4]; const u16* hg[2]; u16* hl[2];
    #pragma unroll
    for (int i = 0; i < 4; i++) {
        int r = i * 32 + w * 8 + subrow;
        fg[i] = Fb + (long)(tm + r) * 1024 + cch * 8;
        fl[i] = Fs + (i * 32 + w * 8) * 64;
    }
    #pragma unroll
    for (int i = 0; i < 2; i++) {
        int r = i * 32 + w * 8 + subrow;
        hg[i] = Hb + (long)r * 1024 + cch * 8;
        hl[i] = Hs + (i * 32 + w * 8) * 64;
    }

    v4f acc[2][4];
    #pragma unroll
    for (int i = 0; i < 2; i++)
        #pragma unroll
        for (int j = 0; j < 4; j++) {
            acc[i][j][0] = 0.f; acc[i][j][1] = 0.f; acc[i][j][2] = 0.f; acc[i][j][3] = 0.f;
        }

    for (int k0 = kb; k0 < kb + 512; k0 += 64) {
        __syncthreads();
        #pragma unroll
        for (int i = 0; i < 4; i++) gload16(fg[i] + k0, fl[i]);
        #pragma unroll
        for (int i = 0; i < 2; i++) gload16(hg[i] + k0, hl[i]);
        __syncthreads();
        v8s af[2][2], bfr[2][4];
        #pragma unroll
        for (int h = 0; h < 2; h++) {
            int ca = (((h << 2) + q) ^ m7) << 3;
            #pragma unroll
            for (int s = 0; s < 2; s++)
                af[h][s] = *(const v8s*)(Fs + (w * 32 + s * 16 + fr) * 64 + ca);
            #pragma unroll
            for (int s = 0; s < 4; s++)
                bfr[h][s] = *(const v8s*)(Hs + (s * 16 + fr) * 64 + ca);
        }
        #pragma unroll
        for (int h = 0; h < 2; h++)
            #pragma unroll
            for (int i = 0; i < 2; i++)
                #pragma unroll
                for (int j = 0; j < 4; j++)
                    acc[i][j] = __builtin_amdgcn_mfma_f32_16x16x32_bf16(af[h][i], bfr[h][j], acc[i][j], 0, 0, 0);
    }
    float* Pd = P + (long)(blockIdx.y * 16 + z) * 65536;
    #pragma unroll
    for (int i = 0; i < 2; i++) {
        int rowb = tm + w * 32 + i * 16 + q * 4;
        #pragma unroll
        for (int j = 0; j < 4; j++) {
            int col = j * 16 + fr;
            #pragma unroll
            for (int r = 0; r < 4; r++)
                Pd[(long)(rowb + r) * 64 + col] = acc[i][j][r];
        }
    }
}

// ---------------------------------------------------------------------------
// K0a: x (fp32, 8192x512) -> bf16, vectorized
// ---------------------------------------------------------------------------
__global__ __launch_bounds__(256) void k_packx(const float* __restrict__ src,
                                               u16* __restrict__ dst)
{
    long i = (long)blockIdx.x * 256 + threadIdx.x;
    float4 v = ((const float4*)src)[i];
    ushort4 o;
    o.x = f2bf(v.x); o.y = f2bf(v.y); o.z = f2bf(v.z); o.w = f2bf(v.w);
    ((ushort4*)dst)[i] = o;
}

// ---------------------------------------------------------------------------
// K0b: pack weights to bf16.
// ---------------------------------------------------------------------------
__global__ __launch_bounds__(256) void k_packw(
    const float* __restrict__ Wq, const float* __restrict__ Wk,
    const float* __restrict__ Wv, const float* __restrict__ gW,
    const float* __restrict__ hopW, const float* __restrict__ outW,
    u16* __restrict__ wpack, u16* __restrict__ hopWb, u16* __restrict__ outWb)
{
    int idx = blockIdx.x * 256 + threadIdx.x;
    if (idx < 131072) {
        int r = idx >> 9, c = idx & 511;
        float v = 0.f;
        if (r < 64)       v = Wq[r * 512 + c];
        else if (r < 128) v = Wk[(r - 64) * 512 + c];
        else if (r < 192) v = Wv[(r - 128) * 512 + c];
        else if (r < 194) v = gW[(r - 192) * 512 + c];
        wpack[idx] = f2bf(v);
    } else if (idx < 131072 + 8192) {
        int i = idx - 131072;
        hopWb[i] = f2bf(hopW[i]);
    } else if (idx < 131072 + 8192 + 32768) {
        int i = idx - 131072 - 8192;
        outWb[i] = f2bf(outW[i]);
    }
}

// ---------------------------------------------------------------------------
// K2: RoPE + gate softmax + Vb
// ---------------------------------------------------------------------------
__global__ __launch_bounds__(256) void k_rope(
    const float* __restrict__ QKVG, const float* __restrict__ gateb,
    u16* __restrict__ Qb, u16* __restrict__ Kb, u16* __restrict__ Vb,
    float* __restrict__ gate)
{
    int t = threadIdx.x, l = t & 63, w = t >> 6;
    long row = (long)blockIdx.x * 4 + w;
    int spos = (int)(row & (SS - 1));
    const float* base = QKVG + row * 256;
    float q = base[l], k = base[64 + l], v = base[128 + l];
    float qp = __shfl_xor(q, 32), kp = __shfl_xor(k, 32);
    float sgn = (l < 32) ? -1.f : 1.f;
    int f = l & 31;
    float ang = (float)spos * exp2f(-(float)f * (13.287712379549449f / 32.0f));
    float cs = cosf(ang), sn = sinf(ang);
    Qb[row * 64 + l] = f2bf(q * cs + sgn * qp * sn);
    Kb[row * 64 + l] = f2bf(k * cs + sgn * kp * sn);
    Vb[row * 64 + l] = f2bf(v);
    if (l < 2) {
        float g0 = base[192] + gateb[0], g1 = base[193] + gateb[1];
        float m = fmaxf(g0, g1);
        float e0 = __expf(g0 - m), e1 = __expf(g1 - m);
        gate[row * 2 + l] = ((l == 0) ? e0 : e1) / (e0 + e1);
    }
}

// ---------------------------------------------------------------------------
// K4: softmax (+ rel-pos bias, /sqrt(d), /temp) -> A bf16; one wave per row
// ---------------------------------------------------------------------------
__global__ __launch_bounds__(256) void k_softmax(
    const float* __restrict__ scores, const float* __restrict__ btab,
    const float* __restrict__ temp, u16* __restrict__ A)
{
    __shared__ float bt[63 * 63];
    int t = threadIdx.x;
    for (int i = t; i < 3969; i += 256) bt[i] = btab[i];
    __syncthreads();
    int lane = t & 63, w = t >> 6;
    long row = (long)blockIdx.x * 4 + w;
    int i = (int)(row & 1023);
    int ih = i >> 5, iw = i & 31;
    float inv_t = 1.0f / fmaxf(temp[0], 0.1f);
    const float* srow = scores + row * 1024;
    float sc[16];
    float m = -1e30f;
    #pragma unroll
    for (int c = 0; c < 16; c++) {
        int j = c * 64 + lane;
        int jh = j >> 5, jw = j & 31;
        float pb = bt[(ih - jh + 31) * 63 + (iw - jw + 31)];
        float s = (srow[j] * 0.125f + pb) * inv_t;
        sc[c] = s; m = fmaxf(m, s);
    }
    #pragma unroll
    for (int o = 1; o < 64; o <<= 1) m = fmaxf(m, __shfl_xor(m, o));
    float sum = 0.f;
    #pragma unroll
    for (int c = 0; c < 16; c++) { sc[c] = __expf(sc[c] - m); sum += sc[c]; }
    #pragma unroll
    for (int o = 1; o < 64; o <<= 1) sum += __shfl_xor(sum, o);
    float inv = 1.0f / sum;
    #pragma unroll
    for (int c = 0; c < 16; c++) A[row * 1024 + c * 64 + lane] = f2bf(sc[c] * inv);
}

// ---------------------------------------------------------------------------
// K5: bf16 transpose, 64x64 tiles, parameterized strides.
// ---------------------------------------------------------------------------
__global__ __launch_bounds__(256) void k_transpose(
    const u16* __restrict__ src, u16* __restrict__ dst,
    int srs, int drs, long sbs, long dbs)
{
    __shared__ u16 tile[64 * 72];
    const u16* s = src + (long)blockIdx.z * sbs;
    u16* d = dst + (long)blockIdx.z * dbs;
    int i0 = blockIdx.x * 64, j0 = blockIdx.y * 64;
    int t = threadIdx.x;
    int r = t >> 2, c0 = (t & 3) << 4;
    #pragma unroll
    for (int p = 0; p < 2; p++) {
        int c = c0 + p * 8;
        uint4 v = *(const uint4*)(s + (long)(i0 + r) * srs + j0 + c);
        *(uint4*)(&tile[r * 72 + c]) = v;
    }
    __syncthreads();
    #pragma unroll
    for (int p = 0; p < 2; p++) {
        uint4 ov;
        u16* po = (u16*)&ov;
        #pragma unroll
        for (int e = 0; e < 8; e++) po[e] = tile[(c0 + p * 8 + e) * 72 + r];
        *(uint4*)(d + (long)(j0 + r) * drs + i0 + c0 + p * 8) = ov;
    }
}

// ---------------------------------------------------------------------------
// K6: fused prob_log/sigmoid/row-norm -> F bf16; one wave per row
// ---------------------------------------------------------------------------
__global__ __launch_bounds__(256) void k_fused(
    const u16* __restrict__ M1, const u16* __restrict__ M2,
    const u16* __restrict__ M3, const float* __restrict__ fw,
    const float* __restrict__ fbv, int hop, u16* __restrict__ F)
{
    int t = threadIdx.x, lane = t & 63, w = t >> 6;
    long row = (long)blockIdx.x * 4 + w;
    const u16* r1 = M1 + row * 1024;
    const u16* r2 = M2 + row * 1024;
    const u16* r3 = M3 + row * 1024;
    float m1[16], m2[16], m3[16];
    float s1 = 0.f, s2 = 0.f, s3 = 0.f;
    #pragma unroll
    for (int c = 0; c < 16; c++) {
        int j = c * 64 + lane;
        m1[c] = bf2f(r1[j]); m2[c] = bf2f(r2[j]); m3[c] = bf2f(r3[j]);
        s1 += m1[c]; s2 += m2[c]; s3 += m3[c];
    }
    #pragma unroll
    for (int o = 1; o < 64; o <<= 1) {
        s1 += __shfl_xor(s1, o); s2 += __shfl_xor(s2, o); s3 += __shfl_xor(s3, o);
    }
    float i1 = 1.f / (s1 + 1e-6f), i2 = 1.f / (s2 + 1e-6f), i3 = 1.f / (s3 + 1e-6f);
    float w0 = fw[hop * 3], w1 = fw[hop * 3 + 1], w2 = fw[hop * 3 + 2], b0 = fbv[hop];
    float sig[16];
    float ssum = 0.f;
    #pragma unroll
    for (int c = 0; c < 16; c++) {
        float p1 = fminf(fmaxf(m1[c] * i1, 1e-6f), 1.0f - 1e-6f);
        float p2 = fminf(fmaxf(m2[c] * i2, 1e-6f), 1.0f - 1e-6f);
        float p3 = fminf(fmaxf(m3[c] * i3, 1e-6f), 1.0f - 1e-6f);
        float l1 = __logf(p1 / (1.0f - p1 + 1e-6f));
        float l2 = __logf(p2 / (1.0f - p2 + 1e-6f));
        float l3 = __logf(p3 / (1.0f - p3 + 1e-6f));
        float lg = b0 + w0 * l1 + w1 * l2 + w2 * l3;
        float sg = 1.0f / (1.0f + __expf(-lg));
        sig[c] = sg; ssum += sg;
    }
    #pragma unroll
    for (int o = 1; o < 64; o <<= 1) ssum += __shfl_xor(ssum, o);
    float inv = 1.0f / (ssum + 1e-6f);
    #pragma unroll
    for (int c = 0; c < 16; c++) F[row * 1024 + c * 64 + lane] = f2bf(sig[c] * inv);
}

// ---------------------------------------------------------------------------
// K7: sum split-K partials, gate-combine -> comb bf16 [8192][64]
// P layout: [y(2)][hop(2)][b(8)][s(1024)][e(64)] fp32
// ---------------------------------------------------------------------------
__global__ __launch_bounds__(256) void k_combine(
    const float* __restrict__ P, const float* __restrict__ gate,
    u16* __restrict__ comb)
{
    long idx = (long)blockIdx.x * 256 + threadIdx.x;   // 8192*64
    long srow = idx >> 6;
    int b = (int)(srow >> 10);
    long o = (long)(srow & 1023) * 64 + (idx & 63);
    float h0 = P[(long)(b) * 65536 + o]        + P[(long)(16 + b) * 65536 + o];
    float h1 = P[(long)(8 + b) * 65536 + o]    + P[(long)(24 + b) * 65536 + o];
    float g0 = gate[srow * 2], g1 = gate[srow * 2 + 1];
    comb[idx] = f2bf(h0 * g0 + h1 * g1);
}

// ---------------------------------------------------------------------------
extern "C" void kernel_launch(void* const* d_in, const int* in_sizes, int n_in,
                              void* d_out, int out_size, void* d_ws, size_t ws_size,
                              hipStream_t stream) {
    const float* x    = (const float*)d_in[0];
    const float* Wq   = (const float*)d_in[1];
    const float* Wk   = (const float*)d_in[2];
    const float* Wv   = (const float*)d_in[3];
    const float* btab = (const float*)d_in[4];
    const float* fw   = (const float*)d_in[5];
    const float* fbv  = (const float*)d_in[6];
    const float* hopW = (const float*)d_in[7];
    const float* gW   = (const float*)d_in[8];
    const float* gb   = (const float*)d_in[9];
    const float* outW = (const float*)d_in[10];
    const float* temp = (const float*)d_in[11];
    float* out = (float*)d_out;

    char* wsb = (char*)d_ws;
    size_t off = 0;
    auto take = [&](size_t n) { char* p = wsb + off; off += (n + 255) & ~(size_t)255; return p; };
    u16* Qb      = (u16*)take(8192L * 64 * 2);
    u16* Kb      = (u16*)take(8192L * 64 * 2);
    u16* Vb      = (u16*)take(8192L * 64 * 2);
    float* gate  = (float*)take(8192L * 2 * 4);
    u16* wpack   = (u16*)take(256L * 512 * 2);
    u16* hopWb   = (u16*)take(2L * 64 * 64 * 2);
    u16* outWb   = (u16*)take(512L * 64 * 2);
    u16* hopvC   = (u16*)take(8192L * 128 * 2);      // [s][hop*64+e]
    u16* hopVT   = (u16*)take(2L * 8 * 64 * 1024 * 2);
    float* P     = (float*)take(2L * 2 * 8 * 1024 * 64 * 4);   // split-K partials
    u16* comb    = (u16*)take(8192L * 64 * 2);
    float* scoresF = (float*)take(8L * 1024 * 1024 * 4);  // 32 MB region
    float* QKVG  = (float*)scoresF;                   // alias: dead before scores
    u16* F0      = (u16*)scoresF;                     // alias: scores dead before F0
    u16* F1      = (u16*)scoresF + 8L * 1024 * 1024;  // second 16 MB of region
    u16* A       = (u16*)take(8L * 1024 * 1024 * 2);
    u16* xb      = (u16*)A;                           // alias: dead before A
    u16* AT      = (u16*)take(8L * 1024 * 1024 * 2);
    u16* AAt     = (u16*)take(8L * 1024 * 1024 * 2);
    u16* AtA     = (u16*)take(8L * 1024 * 1024 * 2);
    u16* A2      = (u16*)take(8L * 1024 * 1024 * 2);
    u16* AAt2    = (u16*)take(8L * 1024 * 1024 * 2);
    u16* AtA2    = (u16*)take(8L * 1024 * 1024 * 2);
    (void)ws_size; (void)in_sizes; (void)n_in; (void)out_size;

    const long SD = (long)SS * DD;        // 65536
    const long SSq = (long)SS * SS;       // 1048576

    // 1. pack inputs
    k_packx<<<4096, 256, 0, stream>>>(x, xb);
    k_packw<<<672, 256, 0, stream>>>(Wq, Wk, Wv, gW, hopW, outW, wpack, hopWb, outWb);
    // 2. fused projection: QKVG[8192][256] = xb @ wpack^T (fp32)
    gemm_nt<<<dim3(64, 2, 1), 256, 0, stream>>>(xb, 0, wpack, 0, QKVG, 0, 8192, 256, 512, 1);
    // 3. rope + gate + Vb
    k_rope<<<2048, 256, 0, stream>>>(QKVG, gb, Qb, Kb, Vb, gate);
    // 4. hop_v -> hopvC, transpose to hopVT [hop][b][e][s]
    gemm_nt<<<dim3(64, 1, 1), 256, 0, stream>>>(Vb, 0, hopWb, 0, hopvC, 0, 8192, 128, 64, 0);
    k_transpose<<<dim3(16, 1, 8), 256, 0, stream>>>(hopvC, hopVT, 128, 1024, 1024L * 128, 65536L);
    k_transpose<<<dim3(16, 1, 8), 256, 0, stream>>>(hopvC + 64, hopVT + 8L * 65536, 128, 1024, 1024L * 128, 65536L);
    // 5. scores = Q K^T (fp32)
    gemm_nt<<<dim3(8, 8, 8), 256, 0, stream>>>(Qb, SD, Kb, SD, scoresF, SSq, 1024, 1024, 64, 1);
    // 6. softmax -> A
    k_softmax<<<2048, 256, 0, stream>>>(scoresF, btab, temp, A);
    // 7. AT
    k_transpose<<<dim3(16, 16, 8), 256, 0, stream>>>(A, AT, 1024, 1024, SSq, SSq);
    // 8. AAt = A A^T, AtA = AT AT^T (symmetric, merged pair) + mirror
    gemm_sym<<<dim3(36, 1, 16), 256, 0, stream>>>(A, AT, AAt, AtA);
    k_mirror<<<dim3(28, 1, 16), 256, 0, stream>>>(AAt, AtA);
    // 9. hop 0 fused -> F0
    k_fused<<<2048, 256, 0, stream>>>(A, AAt, AtA, fw, fbv, 0, F0);
    // 10. A2 = A A (full) ; AAt2, AtA2 (symmetric pair) + mirror
    gemm_nt<<<dim3(8, 8, 8), 256, 0, stream>>>(A, SSq, AT, SSq, A2, SSq, 1024, 1024, 1024, 0);
    gemm_sym<<<dim3(36, 1, 16), 256, 0, stream>>>(AAt, AtA, AAt2, AtA2);
    k_mirror<<<dim3(28, 1, 16), 256, 0, stream>>>(AAt2, AtA2);
    // 11. hop 1 fused -> F1
    k_fused<<<2048, 256, 0, stream>>>(A2, AAt2, AtA2, fw, fbv, 1, F1);
    // 12. hop outputs (both hops, split-K=2) -> partials
    gemm_hop<<<dim3(8, 2, 16), 256, 0, stream>>>(F0, F1, hopVT, P);
    // 13. combine + output projection
    k_combine<<<2048, 256, 0, stream>>>(P, gate, comb);
    gemm_nt<<<dim3(64, 4, 1), 256, 0, stream>>>(comb, 0, outWb, 0, out, 0, 8192, 512, 64, 1);
}

// Round 5
// 335.692 us; speedup vs baseline: 1.5518x; 1.0871x over previous
//
#include <hip/hip_runtime.h>
#include <hip/hip_bf16.h>

// Problem constants
#define BB 8
#define SS 1024
#define HH 512
#define DD 64

typedef unsigned short u16;
typedef short v8s __attribute__((ext_vector_type(8)));   // 8 x bf16 (bit pattern)
typedef float v4f __attribute__((ext_vector_type(4)));

__device__ __forceinline__ float bf2f(u16 u) {
    union { unsigned int i; float f; } v; v.i = ((unsigned int)u) << 16; return v.f;
}
__device__ __forceinline__ u16 f2bf(float f) {
    union { float f; unsigned int i; } v; v.f = f;
    unsigned int u = v.i;
    unsigned int r = u + 0x7fffu + ((u >> 16) & 1u);   // RNE
    return (u16)(r >> 16);
}

// async 16B global->LDS DMA: lane L's data lands at ldsbase + L*16
__device__ __forceinline__ void gload16(const u16* g, u16* l) {
    __builtin_amdgcn_global_load_lds(
        (const __attribute__((address_space(1))) void*)g,
        (__attribute__((address_space(3))) void*)l,
        16, 0, 0);
}

// ---------------------------------------------------------------------------
// Shared GEMM geometry (BK=64):
// LDS tile rows of 64 bf16 = 8 chunks of 16B. Physical chunk p of row r holds
// logical chunk p ^ (r&7)  (XOR swizzle -> conflict-free b128 reads).
// Staging: thread t=64w+lane, instr i: row = i*32 + w*8 + (lane>>3),
//          phys chunk = lane&7, so global col chunk = (lane&7) ^ (lane>>3).
// ---------------------------------------------------------------------------

// Core 128x128 tile x K=1024 NT product, bf16 out. Xb/Yb are batch bases
// (row stride 1024); writes C[tm..tm+128)[tn..tn+128).
__device__ __forceinline__ void tile_1024(
    const u16* __restrict__ Xb, const u16* __restrict__ Yb,
    u16* __restrict__ Cd, int tm, int tn, u16* Xs, u16* Ys)
{
    int t = threadIdx.x, lane = t & 63, w = t >> 6;
    int wm = (w & 1) << 6, wn = (w >> 1) << 6;
    int fr = lane & 15, q = lane >> 4, m7 = fr & 7;
    int subrow = lane >> 3, cch = (lane & 7) ^ subrow;

    const u16* xg[4]; const u16* yg[4]; u16* xl[4]; u16* yl[4];
    #pragma unroll
    for (int i = 0; i < 4; i++) {
        int r = i * 32 + w * 8 + subrow;
        xg[i] = Xb + (long)(tm + r) * 1024 + cch * 8;
        yg[i] = Yb + (long)(tn + r) * 1024 + cch * 8;
        xl[i] = Xs + (i * 32 + w * 8) * 64;
        yl[i] = Ys + (i * 32 + w * 8) * 64;
    }

    v4f acc[4][4];
    #pragma unroll
    for (int i = 0; i < 4; i++)
        #pragma unroll
        for (int j = 0; j < 4; j++) {
            acc[i][j][0] = 0.f; acc[i][j][1] = 0.f; acc[i][j][2] = 0.f; acc[i][j][3] = 0.f;
        }

    for (int k0 = 0; k0 < 1024; k0 += 64) {
        __syncthreads();
        #pragma unroll
        for (int i = 0; i < 4; i++) { gload16(xg[i] + k0, xl[i]); gload16(yg[i] + k0, yl[i]); }
        __syncthreads();
        v8s af[2][4], bfr[2][4];
        #pragma unroll
        for (int h = 0; h < 2; h++) {
            int ca = (((h << 2) + q) ^ m7) << 3;
            #pragma unroll
            for (int s = 0; s < 4; s++) {
                af[h][s]  = *(const v8s*)(Xs + (wm + s * 16 + fr) * 64 + ca);
                bfr[h][s] = *(const v8s*)(Ys + (wn + s * 16 + fr) * 64 + ca);
            }
        }
        #pragma unroll
        for (int h = 0; h < 2; h++)
            #pragma unroll
            for (int i = 0; i < 4; i++)
                #pragma unroll
                for (int j = 0; j < 4; j++)
                    acc[i][j] = __builtin_amdgcn_mfma_f32_16x16x32_bf16(af[h][i], bfr[h][j], acc[i][j], 0, 0, 0);
    }
    #pragma unroll
    for (int i = 0; i < 4; i++) {
        int rowb = tm + wm + i * 16 + q * 4;
        #pragma unroll
        for (int j = 0; j < 4; j++) {
            int col = tn + wn + j * 16 + fr;
            #pragma unroll
            for (int r = 0; r < 4; r++)
                Cd[(long)(rowb + r) * 1024 + col] = f2bf(acc[i][j][r]);
        }
    }
}

// ---------------------------------------------------------------------------
// Generation-1 products, one dispatch: AAt = A A^T (upper tiles), AtA = AT AT^T
// (upper tiles), A2 = A A (full). 1D grid 1088 = 8 batches x 136 jobs,
// batch = blockIdx.x & 7 (keeps each batch's blocks on one XCD for L2 reuse).
// ---------------------------------------------------------------------------
__global__ __launch_bounds__(256) void gemm_link1(
    const u16* __restrict__ A, const u16* __restrict__ AT,
    u16* __restrict__ AAt, u16* __restrict__ AtA, u16* __restrict__ A2)
{
    __shared__ u16 Xs[128 * 64];
    __shared__ u16 Ys[128 * 64];
    const long SSq = (long)SS * SS;
    int b = blockIdx.x & 7;
    int job = blockIdx.x >> 3;
    const u16* Xb; const u16* Yb; u16* Cd;
    int ti, tj;
    if (job < 72) {
        int tt = job < 36 ? job : job - 36;
        ti = 0;
        while (tt >= 8 - ti) { tt -= 8 - ti; ti++; }
        tj = ti + tt;
        if (job < 36) { Xb = A  + b * SSq; Yb = Xb; Cd = AAt + b * SSq; }
        else          { Xb = AT + b * SSq; Yb = Xb; Cd = AtA + b * SSq; }
    } else {
        int jj = job - 72;
        ti = jj >> 3; tj = jj & 7;
        Xb = A + b * SSq; Yb = AT + b * SSq; Cd = A2 + b * SSq;   // A2 = A*(AT)^T = A*A
    }
    tile_1024(Xb, Yb, Cd, ti * 128, tj * 128, Xs, Ys);
}

// ---------------------------------------------------------------------------
// Generation-2 symmetric pair: AAt2 = AAt AAt^T, AtA2 = AtA AtA^T, upper tiles.
// 1D grid 576 = 16 z x 36 tiles, z = blockIdx.x & 15 (z,z+8 share an XCD).
// ---------------------------------------------------------------------------
__global__ __launch_bounds__(256) void gemm_link2(
    const u16* __restrict__ X0, const u16* __restrict__ X1,
    u16* __restrict__ C0, u16* __restrict__ C1)
{
    __shared__ u16 Xs[128 * 64];
    __shared__ u16 Ys[128 * 64];
    const long SSq = (long)SS * SS;
    int z = blockIdx.x & 15;
    int tt = blockIdx.x >> 4, ti = 0;
    while (tt >= 8 - ti) { tt -= 8 - ti; ti++; }
    int tj = ti + tt;
    const u16* Xb = (z < 8 ? X0 : X1) + (long)(z & 7) * SSq;
    u16* Cd = (z < 8 ? C0 : C1) + (long)(z & 7) * SSq;
    tile_1024(Xb, Xb, Cd, ti * 128, tj * 128, Xs, Ys);
}

// ---------------------------------------------------------------------------
// Generic batched NT GEMM: C[z] = X[z] (MxK) * Y[z]^T (NxK), bf16 in, fp32 acc
// 128x128 tile, 4 waves 64x64, BK=64. M,N multiples of 128; K multiple of 64.
// ---------------------------------------------------------------------------
__global__ __launch_bounds__(256) void gemm_nt(
    const u16* __restrict__ X, long sx,
    const u16* __restrict__ Y, long sy,
    void* __restrict__ Cv, long sc,
    int M, int N, int K, int cf32)
{
    __shared__ u16 Xs[128 * 64];   // 16 KB
    __shared__ u16 Ys[128 * 64];   // 16 KB
    const u16* Xb = X + (long)blockIdx.z * sx;
    const u16* Yb = Y + (long)blockIdx.z * sy;
    int tm = blockIdx.x * 128, tn = blockIdx.y * 128;
    int t = threadIdx.x, lane = t & 63, w = t >> 6;
    int wm = (w & 1) << 6, wn = (w >> 1) << 6;
    int fr = lane & 15, q = lane >> 4, m7 = fr & 7;
    int subrow = lane >> 3, cch = (lane & 7) ^ subrow;

    const u16* xg[4]; const u16* yg[4]; u16* xl[4]; u16* yl[4];
    #pragma unroll
    for (int i = 0; i < 4; i++) {
        int r = i * 32 + w * 8 + subrow;
        xg[i] = Xb + (long)(tm + r) * K + cch * 8;
        yg[i] = Yb + (long)(tn + r) * K + cch * 8;
        xl[i] = Xs + (i * 32 + w * 8) * 64;
        yl[i] = Ys + (i * 32 + w * 8) * 64;
    }

    v4f acc[4][4];
    #pragma unroll
    for (int i = 0; i < 4; i++)
        #pragma unroll
        for (int j = 0; j < 4; j++) {
            acc[i][j][0] = 0.f; acc[i][j][1] = 0.f; acc[i][j][2] = 0.f; acc[i][j][3] = 0.f;
        }

    for (int k0 = 0; k0 < K; k0 += 64) {
        __syncthreads();
        #pragma unroll
        for (int i = 0; i < 4; i++) { gload16(xg[i] + k0, xl[i]); gload16(yg[i] + k0, yl[i]); }
        __syncthreads();
        v8s af[2][4], bfr[2][4];
        #pragma unroll
        for (int h = 0; h < 2; h++) {
            int ca = (((h << 2) + q) ^ m7) << 3;
            #pragma unroll
            for (int s = 0; s < 4; s++) {
                af[h][s]  = *(const v8s*)(Xs + (wm + s * 16 + fr) * 64 + ca);
                bfr[h][s] = *(const v8s*)(Ys + (wn + s * 16 + fr) * 64 + ca);
            }
        }
        #pragma unroll
        for (int h = 0; h < 2; h++)
            #pragma unroll
            for (int i = 0; i < 4; i++)
                #pragma unroll
                for (int j = 0; j < 4; j++)
                    acc[i][j] = __builtin_amdgcn_mfma_f32_16x16x32_bf16(af[h][i], bfr[h][j], acc[i][j], 0, 0, 0);
    }
    long cb = (long)blockIdx.z * sc;
    #pragma unroll
    for (int i = 0; i < 4; i++) {
        int rowb = tm + wm + i * 16 + q * 4;
        #pragma unroll
        for (int j = 0; j < 4; j++) {
            int col = tn + wn + j * 16 + fr;
            #pragma unroll
            for (int r = 0; r < 4; r++) {
                long o = cb + (long)(rowb + r) * N + col;
                if (cf32) ((float*)Cv)[o] = acc[i][j][r];
                else      ((u16*)Cv)[o] = f2bf(acc[i][j][r]);
            }
        }
    }
}

// ---------------------------------------------------------------------------
// Mirror lower triangle from upper: C[j-tile][i-tile] = C[i][j]^T, 28 off-diag
// tiles, z selects matrix.
// ---------------------------------------------------------------------------
__global__ __launch_bounds__(256) void k_mirror(u16* __restrict__ C0, u16* __restrict__ C1)
{
    __shared__ u16 tile[128 * 136];
    const long SSq = (long)SS * SS;
    int z = blockIdx.z;
    u16* C = (z < 8 ? C0 : C1) + (long)(z & 7) * SSq;
    int tt = blockIdx.x, ti = 0;
    while (tt >= 7 - ti) { tt -= 7 - ti; ti++; }
    int tj = ti + 1 + tt;
    int t = threadIdx.x;
    int r = t >> 1, ch = (t & 1) << 6;   // row r, 64-col half
    const u16* src = C + (long)(ti * 128 + r) * 1024 + tj * 128 + ch;
    #pragma unroll
    for (int p = 0; p < 8; p++) {
        uint4 v = *(const uint4*)(src + p * 8);
        *(uint4*)(&tile[r * 136 + ch + p * 8]) = v;
    }
    __syncthreads();
    u16* dst = C + (long)(tj * 128 + r) * 1024 + ti * 128 + ch;
    #pragma unroll
    for (int p = 0; p < 8; p++) {
        uint4 ov; u16* po = (u16*)&ov;
        #pragma unroll
        for (int e = 0; e < 8; e++) po[e] = tile[(ch + p * 8 + e) * 136 + r];
        *(uint4*)(dst + p * 8) = ov;
    }
}

// ---------------------------------------------------------------------------
// Hop-output GEMM: P[y*16+z] (1024x64 fp32 partial) = F[z] (1024x1024) *
// H[z]^T (64x1024), K-range [y*512,(y+1)*512). z = hop*8+b. Tile 128x64.
// ---------------------------------------------------------------------------
__global__ __launch_bounds__(256) void gemm_hop(
    const u16* __restrict__ F0, const u16* __restrict__ F1,
    const u16* __restrict__ H, float* __restrict__ P)
{
    __shared__ u16 Fs[128 * 64];   // 16 KB
    __shared__ u16 Hs[64 * 64];    // 8 KB
    const long SSq = (long)SS * SS;
    int z = blockIdx.z;
    const u16* Fb = (z < 8 ? F0 : F1) + (long)(z & 7) * SSq;
    const u16* Hb = H + (long)z * 65536;
    int tm = blockIdx.x * 128;
    int kb = blockIdx.y * 512;
    int t = threadIdx.x, lane = t & 63, w = t >> 6;
    int fr = lane & 15, q = lane >> 4, m7 = fr & 7;
    int subrow = lane >> 3, cch = (lane & 7) ^ subrow;

    const u16* fg[4]; u16* fl[4]; const u16* hg[2]; u16* hl[2];
    #pragma unroll
    for (int i = 0; i < 4; i++) {
        int r = i * 32 + w * 8 + subrow;
        fg[i] = Fb + (long)(tm + r) * 1024 + cch * 8;
        fl[i] = Fs + (i * 32 + w * 8) * 64;
    }
    #pragma unroll
    for (int i = 0; i < 2; i++) {
        int r = i * 32 + w * 8 + subrow;
        hg[i] = Hb + (long)r * 1024 + cch * 8;
        hl[i] = Hs + (i * 32 + w * 8) * 64;
    }

    v4f acc[2][4];
    #pragma unroll
    for (int i = 0; i < 2; i++)
        #pragma unroll
        for (int j = 0; j < 4; j++) {
            acc[i][j][0] = 0.f; acc[i][j][1] = 0.f; acc[i][j][2] = 0.f; acc[i][j][3] = 0.f;
        }

    for (int k0 = kb; k0 < kb + 512; k0 += 64) {
        __syncthreads();
        #pragma unroll
        for (int i = 0; i < 4; i++) gload16(fg[i] + k0, fl[i]);
        #pragma unroll
        for (int i = 0; i < 2; i++) gload16(hg[i] + k0, hl[i]);
        __syncthreads();
        v8s af[2][2], bfr[2][4];
        #pragma unroll
        for (int h = 0; h < 2; h++) {
            int ca = (((h << 2) + q) ^ m7) << 3;
            #pragma unroll
            for (int s = 0; s < 2; s++)
                af[h][s] = *(const v8s*)(Fs + (w * 32 + s * 16 + fr) * 64 + ca);
            #pragma unroll
            for (int s = 0; s < 4; s++)
                bfr[h][s] = *(const v8s*)(Hs + (s * 16 + fr) * 64 + ca);
        }
        #pragma unroll
        for (int h = 0; h < 2; h++)
            #pragma unroll
            for (int i = 0; i < 2; i++)
                #pragma unroll
                for (int j = 0; j < 4; j++)
                    acc[i][j] = __builtin_amdgcn_mfma_f32_16x16x32_bf16(af[h][i], bfr[h][j], acc[i][j], 0, 0, 0);
    }
    float* Pd = P + (long)(blockIdx.y * 16 + z) * 65536;
    #pragma unroll
    for (int i = 0; i < 2; i++) {
        int rowb = tm + w * 32 + i * 16 + q * 4;
        #pragma unroll
        for (int j = 0; j < 4; j++) {
            int col = j * 16 + fr;
            #pragma unroll
            for (int r = 0; r < 4; r++)
                Pd[(long)(rowb + r) * 64 + col] = acc[i][j][r];
        }
    }
}

// ---------------------------------------------------------------------------
// K0a: x (fp32, 8192x512) -> bf16, vectorized
// ---------------------------------------------------------------------------
__global__ __launch_bounds__(256) void k_packx(const float* __restrict__ src,
                                               u16* __restrict__ dst)
{
    long i = (long)blockIdx.x * 256 + threadIdx.x;
    float4 v = ((const float4*)src)[i];
    ushort4 o;
    o.x = f2bf(v.x); o.y = f2bf(v.y); o.z = f2bf(v.z); o.w = f2bf(v.w);
    ((ushort4*)dst)[i] = o;
}

// ---------------------------------------------------------------------------
// K0b: pack weights to bf16.
// ---------------------------------------------------------------------------
__global__ __launch_bounds__(256) void k_packw(
    const float* __restrict__ Wq, const float* __restrict__ Wk,
    const float* __restrict__ Wv, const float* __restrict__ gW,
    const float* __restrict__ hopW, const float* __restrict__ outW,
    u16* __restrict__ wpack, u16* __restrict__ hopWb, u16* __restrict__ outWb)
{
    int idx = blockIdx.x * 256 + threadIdx.x;
    if (idx < 131072) {
        int r = idx >> 9, c = idx & 511;
        float v = 0.f;
        if (r < 64)       v = Wq[r * 512 + c];
        else if (r < 128) v = Wk[(r - 64) * 512 + c];
        else if (r < 192) v = Wv[(r - 128) * 512 + c];
        else if (r < 194) v = gW[(r - 192) * 512 + c];
        wpack[idx] = f2bf(v);
    } else if (idx < 131072 + 8192) {
        int i = idx - 131072;
        hopWb[i] = f2bf(hopW[i]);
    } else if (idx < 131072 + 8192 + 32768) {
        int i = idx - 131072 - 8192;
        outWb[i] = f2bf(outW[i]);
    }
}

// ---------------------------------------------------------------------------
// K2: RoPE + gate softmax + Vb
// ---------------------------------------------------------------------------
__global__ __launch_bounds__(256) void k_rope(
    const float* __restrict__ QKVG, const float* __restrict__ gateb,
    u16* __restrict__ Qb, u16* __restrict__ Kb, u16* __restrict__ Vb,
    float* __restrict__ gate)
{
    int t = threadIdx.x, l = t & 63, w = t >> 6;
    long row = (long)blockIdx.x * 4 + w;
    int spos = (int)(row & (SS - 1));
    const float* base = QKVG + row * 256;
    float q = base[l], k = base[64 + l], v = base[128 + l];
    float qp = __shfl_xor(q, 32), kp = __shfl_xor(k, 32);
    float sgn = (l < 32) ? -1.f : 1.f;
    int f = l & 31;
    float ang = (float)spos * exp2f(-(float)f * (13.287712379549449f / 32.0f));
    float cs = cosf(ang), sn = sinf(ang);
    Qb[row * 64 + l] = f2bf(q * cs + sgn * qp * sn);
    Kb[row * 64 + l] = f2bf(k * cs + sgn * kp * sn);
    Vb[row * 64 + l] = f2bf(v);
    if (l < 2) {
        float g0 = base[192] + gateb[0], g1 = base[193] + gateb[1];
        float m = fmaxf(g0, g1);
        float e0 = __expf(g0 - m), e1 = __expf(g1 - m);
        gate[row * 2 + l] = ((l == 0) ? e0 : e1) / (e0 + e1);
    }
}

// ---------------------------------------------------------------------------
// K4: softmax (+ rel-pos bias, /sqrt(d), /temp) -> A bf16; one wave per row
// ---------------------------------------------------------------------------
__global__ __launch_bounds__(256) void k_softmax(
    const float* __restrict__ scores, const float* __restrict__ btab,
    const float* __restrict__ temp, u16* __restrict__ A)
{
    __shared__ float bt[63 * 63];
    int t = threadIdx.x;
    for (int i = t; i < 3969; i += 256) bt[i] = btab[i];
    __syncthreads();
    int lane = t & 63, w = t >> 6;
    long row = (long)blockIdx.x * 4 + w;
    int i = (int)(row & 1023);
    int ih = i >> 5, iw = i & 31;
    float inv_t = 1.0f / fmaxf(temp[0], 0.1f);
    const float* srow = scores + row * 1024;
    float sc[16];
    float m = -1e30f;
    #pragma unroll
    for (int c = 0; c < 16; c++) {
        int j = c * 64 + lane;
        int jh = j >> 5, jw = j & 31;
        float pb = bt[(ih - jh + 31) * 63 + (iw - jw + 31)];
        float s = (srow[j] * 0.125f + pb) * inv_t;
        sc[c] = s; m = fmaxf(m, s);
    }
    #pragma unroll
    for (int o = 1; o < 64; o <<= 1) m = fmaxf(m, __shfl_xor(m, o));
    float sum = 0.f;
    #pragma unroll
    for (int c = 0; c < 16; c++) { sc[c] = __expf(sc[c] - m); sum += sc[c]; }
    #pragma unroll
    for (int o = 1; o < 64; o <<= 1) sum += __shfl_xor(sum, o);
    float inv = 1.0f / sum;
    #pragma unroll
    for (int c = 0; c < 16; c++) A[row * 1024 + c * 64 + lane] = f2bf(sc[c] * inv);
}

// ---------------------------------------------------------------------------
// K5: bf16 transpose, 64x64 tiles, parameterized strides.
// ---------------------------------------------------------------------------
__global__ __launch_bounds__(256) void k_transpose(
    const u16* __restrict__ src, u16* __restrict__ dst,
    int srs, int drs, long sbs, long dbs)
{
    __shared__ u16 tile[64 * 72];
    const u16* s = src + (long)blockIdx.z * sbs;
    u16* d = dst + (long)blockIdx.z * dbs;
    int i0 = blockIdx.x * 64, j0 = blockIdx.y * 64;
    int t = threadIdx.x;
    int r = t >> 2, c0 = (t & 3) << 4;
    #pragma unroll
    for (int p = 0; p < 2; p++) {
        int c = c0 + p * 8;
        uint4 v = *(const uint4*)(s + (long)(i0 + r) * srs + j0 + c);
        *(uint4*)(&tile[r * 72 + c]) = v;
    }
    __syncthreads();
    #pragma unroll
    for (int p = 0; p < 2; p++) {
        uint4 ov;
        u16* po = (u16*)&ov;
        #pragma unroll
        for (int e = 0; e < 8; e++) po[e] = tile[(c0 + p * 8 + e) * 72 + r];
        *(uint4*)(d + (long)(j0 + r) * drs + i0 + c0 + p * 8) = ov;
    }
}

// ---------------------------------------------------------------------------
// K6: fused prob_log/sigmoid/row-norm -> F bf16; one wave per row
// ---------------------------------------------------------------------------
__global__ __launch_bounds__(256) void k_fused(
    const u16* __restrict__ M1, const u16* __restrict__ M2,
    const u16* __restrict__ M3, const float* __restrict__ fw,
    const float* __restrict__ fbv, int hop, u16* __restrict__ F)
{
    int t = threadIdx.x, lane = t & 63, w = t >> 6;
    long row = (long)blockIdx.x * 4 + w;
    const u16* r1 = M1 + row * 1024;
    const u16* r2 = M2 + row * 1024;
    const u16* r3 = M3 + row * 1024;
    float m1[16], m2[16], m3[16];
    float s1 = 0.f, s2 = 0.f, s3 = 0.f;
    #pragma unroll
    for (int c = 0; c < 16; c++) {
        int j = c * 64 + lane;
        m1[c] = bf2f(r1[j]); m2[c] = bf2f(r2[j]); m3[c] = bf2f(r3[j]);
        s1 += m1[c]; s2 += m2[c]; s3 += m3[c];
    }
    #pragma unroll
    for (int o = 1; o < 64; o <<= 1) {
        s1 += __shfl_xor(s1, o); s2 += __shfl_xor(s2, o); s3 += __shfl_xor(s3, o);
    }
    float i1 = 1.f / (s1 + 1e-6f), i2 = 1.f / (s2 + 1e-6f), i3 = 1.f / (s3 + 1e-6f);
    float w0 = fw[hop * 3], w1 = fw[hop * 3 + 1], w2 = fw[hop * 3 + 2], b0 = fbv[hop];
    float sig[16];
    float ssum = 0.f;
    #pragma unroll
    for (int c = 0; c < 16; c++) {
        float p1 = fminf(fmaxf(m1[c] * i1, 1e-6f), 1.0f - 1e-6f);
        float p2 = fminf(fmaxf(m2[c] * i2, 1e-6f), 1.0f - 1e-6f);
        float p3 = fminf(fmaxf(m3[c] * i3, 1e-6f), 1.0f - 1e-6f);
        float l1 = __logf(p1 / (1.0f - p1 + 1e-6f));
        float l2 = __logf(p2 / (1.0f - p2 + 1e-6f));
        float l3 = __logf(p3 / (1.0f - p3 + 1e-6f));
        float lg = b0 + w0 * l1 + w1 * l2 + w2 * l3;
        float sg = 1.0f / (1.0f + __expf(-lg));
        sig[c] = sg; ssum += sg;
    }
    #pragma unroll
    for (int o = 1; o < 64; o <<= 1) ssum += __shfl_xor(ssum, o);
    float inv = 1.0f / (ssum + 1e-6f);
    #pragma unroll
    for (int c = 0; c < 16; c++) F[row * 1024 + c * 64 + lane] = f2bf(sig[c] * inv);
}

// ---------------------------------------------------------------------------
// K7: sum split-K partials, gate-combine -> comb bf16 [8192][64]
// P layout: [y(2)][hop(2)][b(8)][s(1024)][e(64)] fp32
// ---------------------------------------------------------------------------
__global__ __launch_bounds__(256) void k_combine(
    const float* __restrict__ P, const float* __restrict__ gate,
    u16* __restrict__ comb)
{
    long idx = (long)blockIdx.x * 256 + threadIdx.x;   // 8192*64
    long srow = idx >> 6;
    int b = (int)(srow >> 10);
    long o = (long)(srow & 1023) * 64 + (idx & 63);
    float h0 = P[(long)(b) * 65536 + o]        + P[(long)(16 + b) * 65536 + o];
    float h1 = P[(long)(8 + b) * 65536 + o]    + P[(long)(24 + b) * 65536 + o];
    float g0 = gate[srow * 2], g1 = gate[srow * 2 + 1];
    comb[idx] = f2bf(h0 * g0 + h1 * g1);
}

// ---------------------------------------------------------------------------
extern "C" void kernel_launch(void* const* d_in, const int* in_sizes, int n_in,
                              void* d_out, int out_size, void* d_ws, size_t ws_size,
                              hipStream_t stream) {
    const float* x    = (const float*)d_in[0];
    const float* Wq   = (const float*)d_in[1];
    const float* Wk   = (const float*)d_in[2];
    const float* Wv   = (const float*)d_in[3];
    const float* btab = (const float*)d_in[4];
    const float* fw   = (const float*)d_in[5];
    const float* fbv  = (const float*)d_in[6];
    const float* hopW = (const float*)d_in[7];
    const float* gW   = (const float*)d_in[8];
    const float* gb   = (const float*)d_in[9];
    const float* outW = (const float*)d_in[10];
    const float* temp = (const float*)d_in[11];
    float* out = (float*)d_out;

    char* wsb = (char*)d_ws;
    size_t off = 0;
    auto take = [&](size_t n) { char* p = wsb + off; off += (n + 255) & ~(size_t)255; return p; };
    u16* Qb      = (u16*)take(8192L * 64 * 2);
    u16* Kb      = (u16*)take(8192L * 64 * 2);
    u16* Vb      = (u16*)take(8192L * 64 * 2);
    float* gate  = (float*)take(8192L * 2 * 4);
    u16* wpack   = (u16*)take(256L * 512 * 2);
    u16* hopWb   = (u16*)take(2L * 64 * 64 * 2);
    u16* outWb   = (u16*)take(512L * 64 * 2);
    u16* hopvC   = (u16*)take(8192L * 128 * 2);      // [s][hop*64+e]
    u16* hopVT   = (u16*)take(2L * 8 * 64 * 1024 * 2);
    float* P     = (float*)take(2L * 2 * 8 * 1024 * 64 * 4);   // split-K partials
    u16* comb    = (u16*)take(8192L * 64 * 2);
    float* scoresF = (float*)take(8L * 1024 * 1024 * 4);  // 32 MB region
    float* QKVG  = (float*)scoresF;                   // alias: dead before scores
    u16* F0      = (u16*)scoresF;                     // alias: scores dead before F0
    u16* F1      = (u16*)scoresF + 8L * 1024 * 1024;  // second 16 MB of region
    u16* A       = (u16*)take(8L * 1024 * 1024 * 2);
    u16* xb      = (u16*)A;                           // alias: dead before A
    u16* AT      = (u16*)take(8L * 1024 * 1024 * 2);
    u16* AAt     = (u16*)take(8L * 1024 * 1024 * 2);
    u16* AtA     = (u16*)take(8L * 1024 * 1024 * 2);
    u16* A2      = (u16*)take(8L * 1024 * 1024 * 2);
    u16* AAt2    = (u16*)take(8L * 1024 * 1024 * 2);
    u16* AtA2    = (u16*)take(8L * 1024 * 1024 * 2);
    (void)ws_size; (void)in_sizes; (void)n_in; (void)out_size;

    const long SD = (long)SS * DD;        // 65536
    const long SSq = (long)SS * SS;       // 1048576

    // 1. pack inputs
    k_packx<<<4096, 256, 0, stream>>>(x, xb);
    k_packw<<<672, 256, 0, stream>>>(Wq, Wk, Wv, gW, hopW, outW, wpack, hopWb, outWb);
    // 2. fused projection: QKVG[8192][256] = xb @ wpack^T (fp32)
    gemm_nt<<<dim3(64, 2, 1), 256, 0, stream>>>(xb, 0, wpack, 0, QKVG, 0, 8192, 256, 512, 1);
    // 3. rope + gate + Vb
    k_rope<<<2048, 256, 0, stream>>>(QKVG, gb, Qb, Kb, Vb, gate);
    // 4. hop_v -> hopvC, transpose to hopVT [hop][b][e][s]
    gemm_nt<<<dim3(64, 1, 1), 256, 0, stream>>>(Vb, 0, hopWb, 0, hopvC, 0, 8192, 128, 64, 0);
    k_transpose<<<dim3(16, 1, 8), 256, 0, stream>>>(hopvC, hopVT, 128, 1024, 1024L * 128, 65536L);
    k_transpose<<<dim3(16, 1, 8), 256, 0, stream>>>(hopvC + 64, hopVT + 8L * 65536, 128, 1024, 1024L * 128, 65536L);
    // 5. scores = Q K^T (fp32)
    gemm_nt<<<dim3(8, 8, 8), 256, 0, stream>>>(Qb, SD, Kb, SD, scoresF, SSq, 1024, 1024, 64, 1);
    // 6. softmax -> A
    k_softmax<<<2048, 256, 0, stream>>>(scoresF, btab, temp, A);
    // 7. AT
    k_transpose<<<dim3(16, 16, 8), 256, 0, stream>>>(A, AT, 1024, 1024, SSq, SSq);
    // 8. generation-1: AAt, AtA (upper) + A2 (full) in one dispatch, then mirror
    gemm_link1<<<1088, 256, 0, stream>>>(A, AT, AAt, AtA, A2);
    k_mirror<<<dim3(28, 1, 16), 256, 0, stream>>>(AAt, AtA);
    // 9. hop 0 fused -> F0
    k_fused<<<2048, 256, 0, stream>>>(A, AAt, AtA, fw, fbv, 0, F0);
    // 10. generation-2: AAt2, AtA2 (upper) + mirror
    gemm_link2<<<576, 256, 0, stream>>>(AAt, AtA, AAt2, AtA2);
    k_mirror<<<dim3(28, 1, 16), 256, 0, stream>>>(AAt2, AtA2);
    // 11. hop 1 fused -> F1
    k_fused<<<2048, 256, 0, stream>>>(A2, AAt2, AtA2, fw, fbv, 1, F1);
    // 12. hop outputs (both hops, split-K=2) -> partials
    gemm_hop<<<dim3(8, 2, 16), 256, 0, stream>>>(F0, F1, hopVT, P);
    // 13. combine + output projection
    k_combine<<<2048, 256, 0, stream>>>(P, gate, comb);
    gemm_nt<<<dim3(64, 4, 1), 256, 0, stream>>>(comb, 0, outWb, 0, out, 0, 8192, 512, 64, 1);
}

// Round 6
// 321.905 us; speedup vs baseline: 1.6182x; 1.0428x over previous
//
#include <hip/hip_runtime.h>
#include <hip/hip_bf16.h>

// Problem constants
#define BB 8
#define SS 1024
#define HH 512
#define DD 64

typedef unsigned short u16;
typedef short v8s __attribute__((ext_vector_type(8)));   // 8 x bf16 (bit pattern)
typedef float v4f __attribute__((ext_vector_type(4)));

__device__ __forceinline__ float bf2f(u16 u) {
    union { unsigned int i; float f; } v; v.i = ((unsigned int)u) << 16; return v.f;
}
__device__ __forceinline__ u16 f2bf(float f) {
    union { float f; unsigned int i; } v; v.f = f;
    unsigned int u = v.i;
    unsigned int r = u + 0x7fffu + ((u >> 16) & 1u);   // RNE
    return (u16)(r >> 16);
}

// async 16B global->LDS DMA: lane L's data lands at ldsbase + L*16
__device__ __forceinline__ void gload16(const u16* g, u16* l) {
    __builtin_amdgcn_global_load_lds(
        (const __attribute__((address_space(1))) void*)g,
        (__attribute__((address_space(3))) void*)l,
        16, 0, 0);
}

// ---------------------------------------------------------------------------
// Shared GEMM geometry (BK=64): LDS rows of 64 bf16 = 8 chunks of 16B.
// Physical chunk p of row r holds logical chunk p ^ (r&7) (conflict-free b128).
// Staging: thread t=64w+lane, instr i: row = i*32 + w*8 + (lane>>3),
//          phys chunk = lane&7, global col chunk = (lane&7) ^ (lane>>3).
// ---------------------------------------------------------------------------

// Core 128x128 tile x K=1024 NT product, bf16 out.
__device__ __forceinline__ void tile_1024(
    const u16* __restrict__ Xb, const u16* __restrict__ Yb,
    u16* __restrict__ Cd, int tm, int tn, u16* Xs, u16* Ys)
{
    int t = threadIdx.x, lane = t & 63, w = t >> 6;
    int wm = (w & 1) << 6, wn = (w >> 1) << 6;
    int fr = lane & 15, q = lane >> 4, m7 = fr & 7;
    int subrow = lane >> 3, cch = (lane & 7) ^ subrow;

    const u16* xg[4]; const u16* yg[4]; u16* xl[4]; u16* yl[4];
    #pragma unroll
    for (int i = 0; i < 4; i++) {
        int r = i * 32 + w * 8 + subrow;
        xg[i] = Xb + (long)(tm + r) * 1024 + cch * 8;
        yg[i] = Yb + (long)(tn + r) * 1024 + cch * 8;
        xl[i] = Xs + (i * 32 + w * 8) * 64;
        yl[i] = Ys + (i * 32 + w * 8) * 64;
    }

    v4f acc[4][4];
    #pragma unroll
    for (int i = 0; i < 4; i++)
        #pragma unroll
        for (int j = 0; j < 4; j++) {
            acc[i][j][0] = 0.f; acc[i][j][1] = 0.f; acc[i][j][2] = 0.f; acc[i][j][3] = 0.f;
        }

    for (int k0 = 0; k0 < 1024; k0 += 64) {
        __syncthreads();
        #pragma unroll
        for (int i = 0; i < 4; i++) { gload16(xg[i] + k0, xl[i]); gload16(yg[i] + k0, yl[i]); }
        __syncthreads();
        v8s af[2][4], bfr[2][4];
        #pragma unroll
        for (int h = 0; h < 2; h++) {
            int ca = (((h << 2) + q) ^ m7) << 3;
            #pragma unroll
            for (int s = 0; s < 4; s++) {
                af[h][s]  = *(const v8s*)(Xs + (wm + s * 16 + fr) * 64 + ca);
                bfr[h][s] = *(const v8s*)(Ys + (wn + s * 16 + fr) * 64 + ca);
            }
        }
        #pragma unroll
        for (int h = 0; h < 2; h++)
            #pragma unroll
            for (int i = 0; i < 4; i++)
                #pragma unroll
                for (int j = 0; j < 4; j++)
                    acc[i][j] = __builtin_amdgcn_mfma_f32_16x16x32_bf16(af[h][i], bfr[h][j], acc[i][j], 0, 0, 0);
    }
    #pragma unroll
    for (int i = 0; i < 4; i++) {
        int rowb = tm + wm + i * 16 + q * 4;
        #pragma unroll
        for (int j = 0; j < 4; j++) {
            int col = tn + wn + j * 16 + fr;
            #pragma unroll
            for (int r = 0; r < 4; r++)
                Cd[(long)(rowb + r) * 1024 + col] = f2bf(acc[i][j][r]);
        }
    }
}

// Single-K-iteration 128x128 tile (K=64, row stride 64). cf32 selects C dtype.
__device__ __forceinline__ void tile_k64(
    const u16* __restrict__ Xrows, const u16* __restrict__ Yrows,
    void* __restrict__ Cd, int crs, int cf32, u16* Xs, u16* Ys)
{
    int t = threadIdx.x, lane = t & 63, w = t >> 6;
    int wm = (w & 1) << 6, wn = (w >> 1) << 6;
    int fr = lane & 15, q = lane >> 4, m7 = fr & 7;
    int subrow = lane >> 3, cch = (lane & 7) ^ subrow;

    #pragma unroll
    for (int i = 0; i < 4; i++) {
        int r = i * 32 + w * 8 + subrow;
        gload16(Xrows + (long)r * 64 + cch * 8, Xs + (i * 32 + w * 8) * 64);
        gload16(Yrows + (long)r * 64 + cch * 8, Ys + (i * 32 + w * 8) * 64);
    }
    __syncthreads();

    v4f acc[4][4];
    #pragma unroll
    for (int i = 0; i < 4; i++)
        #pragma unroll
        for (int j = 0; j < 4; j++) {
            acc[i][j][0] = 0.f; acc[i][j][1] = 0.f; acc[i][j][2] = 0.f; acc[i][j][3] = 0.f;
        }
    v8s af[2][4], bfr[2][4];
    #pragma unroll
    for (int h = 0; h < 2; h++) {
        int ca = (((h << 2) + q) ^ m7) << 3;
        #pragma unroll
        for (int s = 0; s < 4; s++) {
            af[h][s]  = *(const v8s*)(Xs + (wm + s * 16 + fr) * 64 + ca);
            bfr[h][s] = *(const v8s*)(Ys + (wn + s * 16 + fr) * 64 + ca);
        }
    }
    #pragma unroll
    for (int h = 0; h < 2; h++)
        #pragma unroll
        for (int i = 0; i < 4; i++)
            #pragma unroll
            for (int j = 0; j < 4; j++)
                acc[i][j] = __builtin_amdgcn_mfma_f32_16x16x32_bf16(af[h][i], bfr[h][j], acc[i][j], 0, 0, 0);
    #pragma unroll
    for (int i = 0; i < 4; i++) {
        int rowb = wm + i * 16 + q * 4;
        #pragma unroll
        for (int j = 0; j < 4; j++) {
            int col = wn + j * 16 + fr;
            #pragma unroll
            for (int r = 0; r < 4; r++) {
                long o = (long)(rowb + r) * crs + col;
                if (cf32) ((float*)Cd)[o] = acc[i][j][r];
                else      ((u16*)Cd)[o] = f2bf(acc[i][j][r]);
            }
        }
    }
}

// 128x64 F@H^T tile over K-range [y*256,(y+1)*256). Fs:128x64, Hs:64x64 LDS.
__device__ __forceinline__ void hop_tile(
    const u16* __restrict__ Fb, const u16* __restrict__ Hb,
    int y, int tmt, float* __restrict__ Pd, u16* Fs, u16* Hs)
{
    int tm = tmt * 128, kb = y * 256;
    int t = threadIdx.x, lane = t & 63, w = t >> 6;
    int fr = lane & 15, q = lane >> 4, m7 = fr & 7;
    int subrow = lane >> 3, cch = (lane & 7) ^ subrow;

    const u16* fg[4]; u16* fl[4]; const u16* hg[2]; u16* hl[2];
    #pragma unroll
    for (int i = 0; i < 4; i++) {
        int r = i * 32 + w * 8 + subrow;
        fg[i] = Fb + (long)(tm + r) * 1024 + cch * 8;
        fl[i] = Fs + (i * 32 + w * 8) * 64;
    }
    #pragma unroll
    for (int i = 0; i < 2; i++) {
        int r = i * 32 + w * 8 + subrow;
        hg[i] = Hb + (long)r * 1024 + cch * 8;
        hl[i] = Hs + (i * 32 + w * 8) * 64;
    }

    v4f acc[2][4];
    #pragma unroll
    for (int i = 0; i < 2; i++)
        #pragma unroll
        for (int j = 0; j < 4; j++) {
            acc[i][j][0] = 0.f; acc[i][j][1] = 0.f; acc[i][j][2] = 0.f; acc[i][j][3] = 0.f;
        }

    for (int k0 = kb; k0 < kb + 256; k0 += 64) {
        __syncthreads();
        #pragma unroll
        for (int i = 0; i < 4; i++) gload16(fg[i] + k0, fl[i]);
        #pragma unroll
        for (int i = 0; i < 2; i++) gload16(hg[i] + k0, hl[i]);
        __syncthreads();
        v8s af[2][2], bfr[2][4];
        #pragma unroll
        for (int h = 0; h < 2; h++) {
            int ca = (((h << 2) + q) ^ m7) << 3;
            #pragma unroll
            for (int s = 0; s < 2; s++)
                af[h][s] = *(const v8s*)(Fs + (w * 32 + s * 16 + fr) * 64 + ca);
            #pragma unroll
            for (int s = 0; s < 4; s++)
                bfr[h][s] = *(const v8s*)(Hs + (s * 16 + fr) * 64 + ca);
        }
        #pragma unroll
        for (int h = 0; h < 2; h++)
            #pragma unroll
            for (int i = 0; i < 2; i++)
                #pragma unroll
                for (int j = 0; j < 4; j++)
                    acc[i][j] = __builtin_amdgcn_mfma_f32_16x16x32_bf16(af[h][i], bfr[h][j], acc[i][j], 0, 0, 0);
    }
    #pragma unroll
    for (int i = 0; i < 2; i++) {
        int rowb = tm + w * 32 + i * 16 + q * 4;
        #pragma unroll
        for (int j = 0; j < 4; j++) {
            int col = j * 16 + fr;
            #pragma unroll
            for (int r = 0; r < 4; r++)
                Pd[(long)(rowb + r) * 64 + col] = acc[i][j][r];
        }
    }
}

// mirror one off-diagonal 128x128 tile: C[tj][ti] = C[ti][tj]^T. sm: 128*136 u16.
__device__ __forceinline__ void mirror_tile(u16* __restrict__ C, int ti, int tj, u16* sm)
{
    int t = threadIdx.x;
    int r = t >> 1, ch = (t & 1) << 6;
    const u16* src = C + (long)(ti * 128 + r) * 1024 + tj * 128 + ch;
    #pragma unroll
    for (int p = 0; p < 8; p++) {
        uint4 v = *(const uint4*)(src + p * 8);
        *(uint4*)(&sm[r * 136 + ch + p * 8]) = v;
    }
    __syncthreads();
    u16* dst = C + (long)(tj * 128 + r) * 1024 + ti * 128 + ch;
    #pragma unroll
    for (int p = 0; p < 8; p++) {
        uint4 ov; u16* po = (u16*)&ov;
        #pragma unroll
        for (int e = 0; e < 8; e++) po[e] = sm[(ch + p * 8 + e) * 136 + r];
        *(uint4*)(dst + p * 8) = ov;
    }
}

// fused prob_log/sigmoid/row-norm for one row (wave-collective, 64 lanes)
__device__ __forceinline__ void fused_row(
    const u16* __restrict__ r1, const u16* __restrict__ r2, const u16* __restrict__ r3,
    float w0, float w1, float w2, float b0, u16* __restrict__ Frow, int lane)
{
    float m1[16], m2[16], m3[16];
    float s1 = 0.f, s2 = 0.f, s3 = 0.f;
    #pragma unroll
    for (int c = 0; c < 16; c++) {
        int j = c * 64 + lane;
        m1[c] = bf2f(r1[j]); m2[c] = bf2f(r2[j]); m3[c] = bf2f(r3[j]);
        s1 += m1[c]; s2 += m2[c]; s3 += m3[c];
    }
    #pragma unroll
    for (int o = 1; o < 64; o <<= 1) {
        s1 += __shfl_xor(s1, o); s2 += __shfl_xor(s2, o); s3 += __shfl_xor(s3, o);
    }
    float i1 = 1.f / (s1 + 1e-6f), i2 = 1.f / (s2 + 1e-6f), i3 = 1.f / (s3 + 1e-6f);
    float sig[16];
    float ssum = 0.f;
    #pragma unroll
    for (int c = 0; c < 16; c++) {
        float p1 = fminf(fmaxf(m1[c] * i1, 1e-6f), 1.0f - 1e-6f);
        float p2 = fminf(fmaxf(m2[c] * i2, 1e-6f), 1.0f - 1e-6f);
        float p3 = fminf(fmaxf(m3[c] * i3, 1e-6f), 1.0f - 1e-6f);
        float l1 = __logf(p1 / (1.0f - p1 + 1e-6f));
        float l2 = __logf(p2 / (1.0f - p2 + 1e-6f));
        float l3 = __logf(p3 / (1.0f - p3 + 1e-6f));
        float lg = b0 + w0 * l1 + w1 * l2 + w2 * l3;
        float sg = 1.0f / (1.0f + __expf(-lg));
        sig[c] = sg; ssum += sg;
    }
    #pragma unroll
    for (int o = 1; o < 64; o <<= 1) ssum += __shfl_xor(ssum, o);
    float inv = 1.0f / (ssum + 1e-6f);
    #pragma unroll
    for (int c = 0; c < 16; c++) Frow[c * 64 + lane] = f2bf(sig[c] * inv);
}

// ---------------------------------------------------------------------------
// Generation-1: AAt (upper 36), AtA (upper 36), A2 = A*A (full 64).
// 1D grid 1088 = 8 batches x 136 jobs, batch = blockIdx.x & 7 (XCD locality).
// ---------------------------------------------------------------------------
__global__ __launch_bounds__(256) void gemm_link1(
    const u16* __restrict__ A, const u16* __restrict__ AT,
    u16* __restrict__ AAt, u16* __restrict__ AtA, u16* __restrict__ A2)
{
    __shared__ u16 Xs[128 * 64];
    __shared__ u16 Ys[128 * 64];
    const long SSq = (long)SS * SS;
    int b = blockIdx.x & 7;
    int job = blockIdx.x >> 3;
    const u16* Xb; const u16* Yb; u16* Cd;
    int ti, tj;
    if (job < 72) {
        int tt = job < 36 ? job : job - 36;
        ti = 0;
        while (tt >= 8 - ti) { tt -= 8 - ti; ti++; }
        tj = ti + tt;
        if (job < 36) { Xb = A  + b * SSq; Yb = Xb; Cd = AAt + b * SSq; }
        else          { Xb = AT + b * SSq; Yb = Xb; Cd = AtA + b * SSq; }
    } else {
        int jj = job - 72;
        ti = jj >> 3; tj = jj & 7;
        Xb = A + b * SSq; Yb = AT + b * SSq; Cd = A2 + b * SSq;   // A2 = A*(AT)^T = A*A
    }
    tile_1024(Xb, Yb, Cd, ti * 128, tj * 128, Xs, Ys);
}

// ---------------------------------------------------------------------------
// Merged: gen-2 symmetric pair (576 blocks) + fused hop-0 (512 blocks).
// ---------------------------------------------------------------------------
__global__ __launch_bounds__(256) void k_g2f0(
    const u16* __restrict__ AAt, const u16* __restrict__ AtA,
    u16* __restrict__ AAt2, u16* __restrict__ AtA2,
    const u16* __restrict__ A, const float* __restrict__ fw,
    const float* __restrict__ fbv, u16* __restrict__ F0)
{
    __shared__ u16 Xs[128 * 64];
    __shared__ u16 Ys[128 * 64];
    const long SSq = (long)SS * SS;
    int bx = blockIdx.x;
    if (bx < 576) {
        int z = bx & 15;
        int tt = bx >> 4, ti = 0;
        while (tt >= 8 - ti) { tt -= 8 - ti; ti++; }
        int tj = ti + tt;
        const u16* Xb = (z < 8 ? AAt : AtA) + (long)(z & 7) * SSq;
        u16* Cd = (z < 8 ? AAt2 : AtA2) + (long)(z & 7) * SSq;
        tile_1024(Xb, Xb, Cd, ti * 128, tj * 128, Xs, Ys);
    } else {
        int f = bx - 576;                  // 0..511 -> 16 rows each
        int lane = threadIdx.x & 63, w = threadIdx.x >> 6;
        float w0 = fw[0], w1 = fw[1], w2 = fw[2], b0 = fbv[0];
        #pragma unroll
        for (int r = 0; r < 4; r++) {
            long row = (long)f * 16 + w * 4 + r;
            fused_row(A + row * 1024, AAt + row * 1024, AtA + row * 1024,
                      w0, w1, w2, b0, F0 + row * 1024, lane);
        }
    }
}

// ---------------------------------------------------------------------------
// Merged: mirror gen-2 (448 blocks) + hop-0 GEMM split-K=4 (256 blocks).
// ---------------------------------------------------------------------------
__global__ __launch_bounds__(256) void k_m2h0(
    u16* __restrict__ AAt2, u16* __restrict__ AtA2,
    const u16* __restrict__ F0, const u16* __restrict__ hopVT,
    float* __restrict__ Pa, float* __restrict__ Pb)
{
    __shared__ __align__(16) u16 sm[128 * 136];   // 34816 B
    const long SSq = (long)SS * SS;
    int bx = blockIdx.x;
    if (bx < 448) {
        int z = bx & 15;
        int tt = bx >> 4, ti = 0;
        while (tt >= 7 - ti) { tt -= 7 - ti; ti++; }
        int tj = ti + 1 + tt;
        u16* C = (z < 8 ? AAt2 : AtA2) + (long)(z & 7) * SSq;
        mirror_tile(C, ti, tj, sm);
    } else {
        int j = bx - 448;                  // 0..255
        int y = j >> 6, rest = j & 63;
        int tmt = rest >> 3, b = rest & 7;
        float* Pd = (y < 2 ? Pa + (long)y * 16 * 65536 : Pb + (long)(y - 2) * 16 * 65536)
                    + (long)b * 65536;                    // hop=0
        hop_tile(F0 + (long)b * SSq, hopVT + (long)b * 65536, y, tmt, Pd,
                 sm, sm + 128 * 64);
    }
}

// hop-1 GEMM standalone, split-K=4: grid 256.
__global__ __launch_bounds__(256) void gemm_hop1(
    const u16* __restrict__ F1, const u16* __restrict__ hopVT,
    float* __restrict__ Pa, float* __restrict__ Pb)
{
    __shared__ u16 Fs[128 * 64];
    __shared__ u16 Hs[64 * 64];
    const long SSq = (long)SS * SS;
    int j = blockIdx.x;
    int y = j >> 6, rest = j & 63;
    int tmt = rest >> 3, b = rest & 7;
    float* Pd = (y < 2 ? Pa + (long)y * 16 * 65536 : Pb + (long)(y - 2) * 16 * 65536)
                + (long)(8 + b) * 65536;                  // hop=1
    hop_tile(F1 + (long)b * SSq, hopVT + (long)(8 + b) * 65536, y, tmt, Pd, Fs, Hs);
}

// ---------------------------------------------------------------------------
// Generic batched NT GEMM (projection + final): C[z] = X[z](MxK) * Y[z]^T(NxK)
// ---------------------------------------------------------------------------
__global__ __launch_bounds__(256) void gemm_nt(
    const u16* __restrict__ X, long sx,
    const u16* __restrict__ Y, long sy,
    void* __restrict__ Cv, long sc,
    int M, int N, int K, int cf32)
{
    __shared__ u16 Xs[128 * 64];
    __shared__ u16 Ys[128 * 64];
    const u16* Xb = X + (long)blockIdx.z * sx;
    const u16* Yb = Y + (long)blockIdx.z * sy;
    int tm = blockIdx.x * 128, tn = blockIdx.y * 128;
    int t = threadIdx.x, lane = t & 63, w = t >> 6;
    int wm = (w & 1) << 6, wn = (w >> 1) << 6;
    int fr = lane & 15, q = lane >> 4, m7 = fr & 7;
    int subrow = lane >> 3, cch = (lane & 7) ^ subrow;

    const u16* xg[4]; const u16* yg[4]; u16* xl[4]; u16* yl[4];
    #pragma unroll
    for (int i = 0; i < 4; i++) {
        int r = i * 32 + w * 8 + subrow;
        xg[i] = Xb + (long)(tm + r) * K + cch * 8;
        yg[i] = Yb + (long)(tn + r) * K + cch * 8;
        xl[i] = Xs + (i * 32 + w * 8) * 64;
        yl[i] = Ys + (i * 32 + w * 8) * 64;
    }

    v4f acc[4][4];
    #pragma unroll
    for (int i = 0; i < 4; i++)
        #pragma unroll
        for (int j = 0; j < 4; j++) {
            acc[i][j][0] = 0.f; acc[i][j][1] = 0.f; acc[i][j][2] = 0.f; acc[i][j][3] = 0.f;
        }

    for (int k0 = 0; k0 < K; k0 += 64) {
        __syncthreads();
        #pragma unroll
        for (int i = 0; i < 4; i++) { gload16(xg[i] + k0, xl[i]); gload16(yg[i] + k0, yl[i]); }
        __syncthreads();
        v8s af[2][4], bfr[2][4];
        #pragma unroll
        for (int h = 0; h < 2; h++) {
            int ca = (((h << 2) + q) ^ m7) << 3;
            #pragma unroll
            for (int s = 0; s < 4; s++) {
                af[h][s]  = *(const v8s*)(Xs + (wm + s * 16 + fr) * 64 + ca);
                bfr[h][s] = *(const v8s*)(Ys + (wn + s * 16 + fr) * 64 + ca);
            }
        }
        #pragma unroll
        for (int h = 0; h < 2; h++)
            #pragma unroll
            for (int i = 0; i < 4; i++)
                #pragma unroll
                for (int j = 0; j < 4; j++)
                    acc[i][j] = __builtin_amdgcn_mfma_f32_16x16x32_bf16(af[h][i], bfr[h][j], acc[i][j], 0, 0, 0);
    }
    long cb = (long)blockIdx.z * sc;
    #pragma unroll
    for (int i = 0; i < 4; i++) {
        int rowb = tm + wm + i * 16 + q * 4;
        #pragma unroll
        for (int j = 0; j < 4; j++) {
            int col = tn + wn + j * 16 + fr;
            #pragma unroll
            for (int r = 0; r < 4; r++) {
                long o = cb + (long)(rowb + r) * N + col;
                if (cf32) ((float*)Cv)[o] = acc[i][j][r];
                else      ((u16*)Cv)[o] = f2bf(acc[i][j][r]);
            }
        }
    }
}

// ---------------------------------------------------------------------------
// Merged: QK^T scores (512 blocks, fp32) + hopV projection (64 blocks, bf16)
// ---------------------------------------------------------------------------
__global__ __launch_bounds__(256) void k_qk_hopv(
    const u16* __restrict__ Qb, const u16* __restrict__ Kb,
    const u16* __restrict__ Vb, const u16* __restrict__ hopWb,
    float* __restrict__ scores, u16* __restrict__ hopvC)
{
    __shared__ u16 Xs[128 * 64];
    __shared__ u16 Ys[128 * 64];
    const long SSq = (long)SS * SS;
    const long SD = (long)SS * DD;
    int bx = blockIdx.x;
    if (bx < 512) {
        int z = bx & 7;
        int tt = bx >> 3;
        int tm = (tt >> 3) * 128, tn = (tt & 7) * 128;
        tile_k64(Qb + z * SD + (long)tm * 64, Kb + z * SD + (long)tn * 64,
                 scores + z * SSq + (long)tm * 1024 + tn, 1024, 1, Xs, Ys);
    } else {
        int tm = (bx - 512) * 128;
        tile_k64(Vb + (long)tm * 64, hopWb,
                 hopvC + (long)tm * 128, 128, 0, Xs, Ys);
    }
}

// ---------------------------------------------------------------------------
// Merged: softmax (2048 blocks) + hopVT transposes (256 blocks)
// ---------------------------------------------------------------------------
__global__ __launch_bounds__(256) void k_sm_hvt(
    const float* __restrict__ scores, const float* __restrict__ btab,
    const float* __restrict__ temp, u16* __restrict__ A,
    const u16* __restrict__ hopvC, u16* __restrict__ hopVT)
{
    __shared__ __align__(16) float smf[3969];   // 15876 B
    int bx = blockIdx.x;
    int t = threadIdx.x;
    if (bx < 2048) {
        for (int i = t; i < 3969; i += 256) smf[i] = btab[i];
        __syncthreads();
        int lane = t & 63, w = t >> 6;
        long row = (long)bx * 4 + w;
        int i = (int)(row & 1023);
        int ih = i >> 5, iw = i & 31;
        float inv_t = 1.0f / fmaxf(temp[0], 0.1f);
        const float* srow = scores + row * 1024;
        float sc[16];
        float m = -1e30f;
        #pragma unroll
        for (int c = 0; c < 16; c++) {
            int j = c * 64 + lane;
            int jh = j >> 5, jw = j & 31;
            float pb = smf[(ih - jh + 31) * 63 + (iw - jw + 31)];
            float s = (srow[j] * 0.125f + pb) * inv_t;
            sc[c] = s; m = fmaxf(m, s);
        }
        #pragma unroll
        for (int o = 1; o < 64; o <<= 1) m = fmaxf(m, __shfl_xor(m, o));
        float sum = 0.f;
        #pragma unroll
        for (int c = 0; c < 16; c++) { sc[c] = __expf(sc[c] - m); sum += sc[c]; }
        #pragma unroll
        for (int o = 1; o < 64; o <<= 1) sum += __shfl_xor(sum, o);
        float inv = 1.0f / sum;
        #pragma unroll
        for (int c = 0; c < 16; c++) A[row * 1024 + c * 64 + lane] = f2bf(sc[c] * inv);
    } else {
        u16* tile = (u16*)smf;                 // 64*72 u16 = 9216 B
        int ex = bx - 2048;                    // 0..255
        int hop = ex >> 7, rem = ex & 127;
        int z = rem & 7, i0 = (rem >> 3) * 64;
        const u16* s = hopvC + (long)z * (1024 * 128) + hop * 64;
        u16* d = hopVT + (long)(hop * 8 + z) * 65536;
        int r = t >> 2, c0 = (t & 3) << 4;
        #pragma unroll
        for (int p = 0; p < 2; p++) {
            int c = c0 + p * 8;
            uint4 v = *(const uint4*)(s + (long)(i0 + r) * 128 + c);
            *(uint4*)(&tile[r * 72 + c]) = v;
        }
        __syncthreads();
        #pragma unroll
        for (int p = 0; p < 2; p++) {
            uint4 ov; u16* po = (u16*)&ov;
            #pragma unroll
            for (int e = 0; e < 8; e++) po[e] = tile[(c0 + p * 8 + e) * 72 + r];
            *(uint4*)(d + (long)r * 1024 + i0 + c0 + p * 8) = ov;
        }
    }
}

// mirror gen-1: 28 off-diag tiles x 16 matrices
__global__ __launch_bounds__(256) void k_mirror(u16* __restrict__ C0, u16* __restrict__ C1)
{
    __shared__ __align__(16) u16 sm[128 * 136];
    const long SSq = (long)SS * SS;
    int z = blockIdx.z;
    u16* C = (z < 8 ? C0 : C1) + (long)(z & 7) * SSq;
    int tt = blockIdx.x, ti = 0;
    while (tt >= 7 - ti) { tt -= 7 - ti; ti++; }
    int tj = ti + 1 + tt;
    mirror_tile(C, ti, tj, sm);
}

// fused hop-1: 512 blocks x 16 rows
__global__ __launch_bounds__(256) void k_fused1(
    const u16* __restrict__ A2, const u16* __restrict__ AAt2,
    const u16* __restrict__ AtA2, const float* __restrict__ fw,
    const float* __restrict__ fbv, u16* __restrict__ F1)
{
    int lane = threadIdx.x & 63, w = threadIdx.x >> 6;
    float w0 = fw[3], w1 = fw[4], w2 = fw[5], b0 = fbv[1];
    #pragma unroll
    for (int r = 0; r < 4; r++) {
        long row = (long)blockIdx.x * 16 + w * 4 + r;
        fused_row(A2 + row * 1024, AAt2 + row * 1024, AtA2 + row * 1024,
                  w0, w1, w2, b0, F1 + row * 1024, lane);
    }
}

// pack x + weights to bf16 (merged)
__global__ __launch_bounds__(256) void k_pack(
    const float* __restrict__ x, const float* __restrict__ Wq,
    const float* __restrict__ Wk, const float* __restrict__ Wv,
    const float* __restrict__ gW, const float* __restrict__ hopW,
    const float* __restrict__ outW, u16* __restrict__ xb,
    u16* __restrict__ wpack, u16* __restrict__ hopWb, u16* __restrict__ outWb)
{
    int bx = blockIdx.x;
    if (bx < 4096) {
        long i = (long)bx * 256 + threadIdx.x;
        float4 v = ((const float4*)x)[i];
        ushort4 o;
        o.x = f2bf(v.x); o.y = f2bf(v.y); o.z = f2bf(v.z); o.w = f2bf(v.w);
        ((ushort4*)xb)[i] = o;
    } else {
        int idx = (bx - 4096) * 256 + threadIdx.x;
        if (idx < 131072) {
            int r = idx >> 9, c = idx & 511;
            float v = 0.f;
            if (r < 64)       v = Wq[r * 512 + c];
            else if (r < 128) v = Wk[(r - 64) * 512 + c];
            else if (r < 192) v = Wv[(r - 128) * 512 + c];
            else if (r < 194) v = gW[(r - 192) * 512 + c];
            wpack[idx] = f2bf(v);
        } else if (idx < 131072 + 8192) {
            int i = idx - 131072;
            hopWb[i] = f2bf(hopW[i]);
        } else if (idx < 131072 + 8192 + 32768) {
            int i = idx - 131072 - 8192;
            outWb[i] = f2bf(outW[i]);
        }
    }
}

// RoPE + gate softmax + Vb
__global__ __launch_bounds__(256) void k_rope(
    const float* __restrict__ QKVG, const float* __restrict__ gateb,
    u16* __restrict__ Qb, u16* __restrict__ Kb, u16* __restrict__ Vb,
    float* __restrict__ gate)
{
    int t = threadIdx.x, l = t & 63, w = t >> 6;
    long row = (long)blockIdx.x * 4 + w;
    int spos = (int)(row & (SS - 1));
    const float* base = QKVG + row * 256;
    float q = base[l], k = base[64 + l], v = base[128 + l];
    float qp = __shfl_xor(q, 32), kp = __shfl_xor(k, 32);
    float sgn = (l < 32) ? -1.f : 1.f;
    int f = l & 31;
    float ang = (float)spos * exp2f(-(float)f * (13.287712379549449f / 32.0f));
    float cs = cosf(ang), sn = sinf(ang);
    Qb[row * 64 + l] = f2bf(q * cs + sgn * qp * sn);
    Kb[row * 64 + l] = f2bf(k * cs + sgn * kp * sn);
    Vb[row * 64 + l] = f2bf(v);
    if (l < 2) {
        float g0 = base[192] + gateb[0], g1 = base[193] + gateb[1];
        float m = fmaxf(g0, g1);
        float e0 = __expf(g0 - m), e1 = __expf(g1 - m);
        gate[row * 2 + l] = ((l == 0) ? e0 : e1) / (e0 + e1);
    }
}

// generic bf16 transpose (A -> AT)
__global__ __launch_bounds__(256) void k_transpose(
    const u16* __restrict__ src, u16* __restrict__ dst,
    int srs, int drs, long sbs, long dbs)
{
    __shared__ u16 tile[64 * 72];
    const u16* s = src + (long)blockIdx.z * sbs;
    u16* d = dst + (long)blockIdx.z * dbs;
    int i0 = blockIdx.x * 64, j0 = blockIdx.y * 64;
    int t = threadIdx.x;
    int r = t >> 2, c0 = (t & 3) << 4;
    #pragma unroll
    for (int p = 0; p < 2; p++) {
        int c = c0 + p * 8;
        uint4 v = *(const uint4*)(s + (long)(i0 + r) * srs + j0 + c);
        *(uint4*)(&tile[r * 72 + c]) = v;
    }
    __syncthreads();
    #pragma unroll
    for (int p = 0; p < 2; p++) {
        uint4 ov;
        u16* po = (u16*)&ov;
        #pragma unroll
        for (int e = 0; e < 8; e++) po[e] = tile[(c0 + p * 8 + e) * 72 + r];
        *(uint4*)(d + (long)(j0 + r) * drs + i0 + c0 + p * 8) = ov;
    }
}

// sum split-K=4 partials, gate-combine -> comb bf16 [8192][64]
__global__ __launch_bounds__(256) void k_combine(
    const float* __restrict__ Pa, const float* __restrict__ Pb,
    const float* __restrict__ gate, u16* __restrict__ comb)
{
    long idx = (long)blockIdx.x * 256 + threadIdx.x;   // 8192*64
    long srow = idx >> 6;
    int b = (int)(srow >> 10);
    long o = (long)(srow & 1023) * 64 + (idx & 63);
    float h0 = Pa[(long)b * 65536 + o] + Pa[(long)(16 + b) * 65536 + o]
             + Pb[(long)b * 65536 + o] + Pb[(long)(16 + b) * 65536 + o];
    float h1 = Pa[(long)(8 + b) * 65536 + o] + Pa[(long)(24 + b) * 65536 + o]
             + Pb[(long)(8 + b) * 65536 + o] + Pb[(long)(24 + b) * 65536 + o];
    float g0 = gate[srow * 2], g1 = gate[srow * 2 + 1];
    comb[idx] = f2bf(h0 * g0 + h1 * g1);
}

// ---------------------------------------------------------------------------
extern "C" void kernel_launch(void* const* d_in, const int* in_sizes, int n_in,
                              void* d_out, int out_size, void* d_ws, size_t ws_size,
                              hipStream_t stream) {
    const float* x    = (const float*)d_in[0];
    const float* Wq   = (const float*)d_in[1];
    const float* Wk   = (const float*)d_in[2];
    const float* Wv   = (const float*)d_in[3];
    const float* btab = (const float*)d_in[4];
    const float* fw   = (const float*)d_in[5];
    const float* fbv  = (const float*)d_in[6];
    const float* hopW = (const float*)d_in[7];
    const float* gW   = (const float*)d_in[8];
    const float* gb   = (const float*)d_in[9];
    const float* outW = (const float*)d_in[10];
    const float* temp = (const float*)d_in[11];
    float* out = (float*)d_out;

    char* wsb = (char*)d_ws;
    size_t off = 0;
    auto take = [&](size_t n) { char* p = wsb + off; off += (n + 255) & ~(size_t)255; return p; };
    u16* Qb      = (u16*)take(8192L * 64 * 2);
    u16* Kb      = (u16*)take(8192L * 64 * 2);
    u16* Vb      = (u16*)take(8192L * 64 * 2);
    float* gate  = (float*)take(8192L * 2 * 4);
    u16* wpack   = (u16*)take(256L * 512 * 2);
    u16* hopWb   = (u16*)take(2L * 64 * 64 * 2);
    u16* outWb   = (u16*)take(512L * 64 * 2);
    u16* hopvC   = (u16*)take(8192L * 128 * 2);      // [s][hop*64+e]
    u16* hopVT   = (u16*)take(2L * 8 * 64 * 1024 * 2);
    float* Pa    = (float*)take(2L * 16 * 65536 * 4);     // split-K partials y=0,1
    u16* comb    = (u16*)take(8192L * 64 * 2);
    float* scoresF = (float*)take(8L * 1024 * 1024 * 4);  // 32 MB region
    float* QKVG  = (float*)scoresF;                   // alias: dead before scores
    u16* F0      = (u16*)scoresF;                     // alias: scores dead before F0
    u16* F1      = (u16*)scoresF + 8L * 1024 * 1024;  // second 16 MB of region
    u16* A       = (u16*)take(8L * 1024 * 1024 * 2);
    u16* xb      = (u16*)A;                           // alias: dead before A
    u16* AT      = (u16*)take(8L * 1024 * 1024 * 2);
    float* Pb    = (float*)AT;                        // alias: AT dead after link1
    u16* AAt     = (u16*)take(8L * 1024 * 1024 * 2);
    u16* AtA     = (u16*)take(8L * 1024 * 1024 * 2);
    u16* A2      = (u16*)take(8L * 1024 * 1024 * 2);
    u16* AAt2    = (u16*)take(8L * 1024 * 1024 * 2);
    u16* AtA2    = (u16*)take(8L * 1024 * 1024 * 2);
    (void)ws_size; (void)in_sizes; (void)n_in; (void)out_size;

    const long SSq = (long)SS * SS;

    // 1. pack inputs (merged)
    k_pack<<<4768, 256, 0, stream>>>(x, Wq, Wk, Wv, gW, hopW, outW, xb, wpack, hopWb, outWb);
    // 2. fused projection: QKVG[8192][256] = xb @ wpack^T (fp32)
    gemm_nt<<<dim3(64, 2, 1), 256, 0, stream>>>(xb, 0, wpack, 0, QKVG, 0, 8192, 256, 512, 1);
    // 3. rope + gate + Vb
    k_rope<<<2048, 256, 0, stream>>>(QKVG, gb, Qb, Kb, Vb, gate);
    // 4. scores = Q K^T (fp32) + hopvC = Vb @ hopWb^T (merged)
    k_qk_hopv<<<576, 256, 0, stream>>>(Qb, Kb, Vb, hopWb, scoresF, hopvC);
    // 5. softmax -> A + hopVT transposes (merged)
    k_sm_hvt<<<2304, 256, 0, stream>>>(scoresF, btab, temp, A, hopvC, hopVT);
    // 6. AT
    k_transpose<<<dim3(16, 16, 8), 256, 0, stream>>>(A, AT, 1024, 1024, SSq, SSq);
    // 7. generation-1: AAt, AtA (upper) + A2 (full)
    gemm_link1<<<1088, 256, 0, stream>>>(A, AT, AAt, AtA, A2);
    // 8. mirror gen-1
    k_mirror<<<dim3(28, 1, 16), 256, 0, stream>>>(AAt, AtA);
    // 9. gen-2 sym pair + fused hop-0 (merged; F0 rides free on VALU pipe)
    k_g2f0<<<1088, 256, 0, stream>>>(AAt, AtA, AAt2, AtA2, A, fw, fbv, F0);
    // 10. mirror gen-2 + hop-0 GEMM (merged)
    k_m2h0<<<704, 256, 0, stream>>>(AAt2, AtA2, F0, hopVT, Pa, Pb);
    // 11. fused hop-1 -> F1
    k_fused1<<<512, 256, 0, stream>>>(A2, AAt2, AtA2, fw, fbv, F1);
    // 12. hop-1 GEMM
    gemm_hop1<<<256, 256, 0, stream>>>(F1, hopVT, Pa, Pb);
    // 13. combine + output projection
    k_combine<<<2048, 256, 0, stream>>>(Pa, Pb, gate, comb);
    gemm_nt<<<dim3(64, 4, 1), 256, 0, stream>>>(comb, 0, outWb, 0, out, 0, 8192, 512, 64, 1);
}

// Round 7
// 321.006 us; speedup vs baseline: 1.6228x; 1.0028x over previous
//
#include <hip/hip_runtime.h>
#include <hip/hip_bf16.h>

// Problem constants
#define BB 8
#define SS 1024
#define HH 512
#define DD 64

typedef unsigned short u16;
typedef short v8s __attribute__((ext_vector_type(8)));   // 8 x bf16 (bit pattern)
typedef float v4f __attribute__((ext_vector_type(4)));

__device__ __forceinline__ float bf2f(u16 u) {
    union { unsigned int i; float f; } v; v.i = ((unsigned int)u) << 16; return v.f;
}
__device__ __forceinline__ u16 f2bf(float f) {
    union { float f; unsigned int i; } v; v.f = f;
    unsigned int u = v.i;
    unsigned int r = u + 0x7fffu + ((u >> 16) & 1u);   // RNE
    return (u16)(r >> 16);
}

// async 16B global->LDS DMA: lane L's data lands at ldsbase + L*16
__device__ __forceinline__ void gload16(const u16* g, u16* l) {
    __builtin_amdgcn_global_load_lds(
        (const __attribute__((address_space(1))) void*)g,
        (__attribute__((address_space(3))) void*)l,
        16, 0, 0);
}

// ---------------------------------------------------------------------------
// Shared GEMM geometry (BK=64): LDS rows of 64 bf16 = 8 chunks of 16B.
// Physical chunk p of row r holds logical chunk p ^ (r&7) (conflict-free b128).
// Staging: thread t=64w+lane, instr i: row = i*32 + w*8 + (lane>>3),
//          phys chunk = lane&7, global col chunk = (lane&7) ^ (lane>>3).
// ---------------------------------------------------------------------------

// Core 128x128 tile x K=1024 NT product, bf16 out.
__device__ __forceinline__ void tile_1024(
    const u16* __restrict__ Xb, const u16* __restrict__ Yb,
    u16* __restrict__ Cd, int tm, int tn, u16* Xs, u16* Ys)
{
    int t = threadIdx.x, lane = t & 63, w = t >> 6;
    int wm = (w & 1) << 6, wn = (w >> 1) << 6;
    int fr = lane & 15, q = lane >> 4, m7 = fr & 7;
    int subrow = lane >> 3, cch = (lane & 7) ^ subrow;

    const u16* xg[4]; const u16* yg[4]; u16* xl[4]; u16* yl[4];
    #pragma unroll
    for (int i = 0; i < 4; i++) {
        int r = i * 32 + w * 8 + subrow;
        xg[i] = Xb + (long)(tm + r) * 1024 + cch * 8;
        yg[i] = Yb + (long)(tn + r) * 1024 + cch * 8;
        xl[i] = Xs + (i * 32 + w * 8) * 64;
        yl[i] = Ys + (i * 32 + w * 8) * 64;
    }

    v4f acc[4][4];
    #pragma unroll
    for (int i = 0; i < 4; i++)
        #pragma unroll
        for (int j = 0; j < 4; j++) {
            acc[i][j][0] = 0.f; acc[i][j][1] = 0.f; acc[i][j][2] = 0.f; acc[i][j][3] = 0.f;
        }

    for (int k0 = 0; k0 < 1024; k0 += 64) {
        __syncthreads();
        #pragma unroll
        for (int i = 0; i < 4; i++) { gload16(xg[i] + k0, xl[i]); gload16(yg[i] + k0, yl[i]); }
        __syncthreads();
        v8s af[2][4], bfr[2][4];
        #pragma unroll
        for (int h = 0; h < 2; h++) {
            int ca = (((h << 2) + q) ^ m7) << 3;
            #pragma unroll
            for (int s = 0; s < 4; s++) {
                af[h][s]  = *(const v8s*)(Xs + (wm + s * 16 + fr) * 64 + ca);
                bfr[h][s] = *(const v8s*)(Ys + (wn + s * 16 + fr) * 64 + ca);
            }
        }
        #pragma unroll
        for (int h = 0; h < 2; h++)
            #pragma unroll
            for (int i = 0; i < 4; i++)
                #pragma unroll
                for (int j = 0; j < 4; j++)
                    acc[i][j] = __builtin_amdgcn_mfma_f32_16x16x32_bf16(af[h][i], bfr[h][j], acc[i][j], 0, 0, 0);
    }
    #pragma unroll
    for (int i = 0; i < 4; i++) {
        int rowb = tm + wm + i * 16 + q * 4;
        #pragma unroll
        for (int j = 0; j < 4; j++) {
            int col = tn + wn + j * 16 + fr;
            #pragma unroll
            for (int r = 0; r < 4; r++)
                Cd[(long)(rowb + r) * 1024 + col] = f2bf(acc[i][j][r]);
        }
    }
}

// Single-K-iteration 128x128 tile (K=64, row stride 64). cf32 selects C dtype.
__device__ __forceinline__ void tile_k64(
    const u16* __restrict__ Xrows, const u16* __restrict__ Yrows,
    void* __restrict__ Cd, int crs, int cf32, u16* Xs, u16* Ys)
{
    int t = threadIdx.x, lane = t & 63, w = t >> 6;
    int wm = (w & 1) << 6, wn = (w >> 1) << 6;
    int fr = lane & 15, q = lane >> 4, m7 = fr & 7;
    int subrow = lane >> 3, cch = (lane & 7) ^ subrow;

    #pragma unroll
    for (int i = 0; i < 4; i++) {
        int r = i * 32 + w * 8 + subrow;
        gload16(Xrows + (long)r * 64 + cch * 8, Xs + (i * 32 + w * 8) * 64);
        gload16(Yrows + (long)r * 64 + cch * 8, Ys + (i * 32 + w * 8) * 64);
    }
    __syncthreads();

    v4f acc[4][4];
    #pragma unroll
    for (int i = 0; i < 4; i++)
        #pragma unroll
        for (int j = 0; j < 4; j++) {
            acc[i][j][0] = 0.f; acc[i][j][1] = 0.f; acc[i][j][2] = 0.f; acc[i][j][3] = 0.f;
        }
    v8s af[2][4], bfr[2][4];
    #pragma unroll
    for (int h = 0; h < 2; h++) {
        int ca = (((h << 2) + q) ^ m7) << 3;
        #pragma unroll
        for (int s = 0; s < 4; s++) {
            af[h][s]  = *(const v8s*)(Xs + (wm + s * 16 + fr) * 64 + ca);
            bfr[h][s] = *(const v8s*)(Ys + (wn + s * 16 + fr) * 64 + ca);
        }
    }
    #pragma unroll
    for (int h = 0; h < 2; h++)
        #pragma unroll
        for (int i = 0; i < 4; i++)
            #pragma unroll
            for (int j = 0; j < 4; j++)
                acc[i][j] = __builtin_amdgcn_mfma_f32_16x16x32_bf16(af[h][i], bfr[h][j], acc[i][j], 0, 0, 0);
    #pragma unroll
    for (int i = 0; i < 4; i++) {
        int rowb = wm + i * 16 + q * 4;
        #pragma unroll
        for (int j = 0; j < 4; j++) {
            int col = wn + j * 16 + fr;
            #pragma unroll
            for (int r = 0; r < 4; r++) {
                long o = (long)(rowb + r) * crs + col;
                if (cf32) ((float*)Cd)[o] = acc[i][j][r];
                else      ((u16*)Cd)[o] = f2bf(acc[i][j][r]);
            }
        }
    }
}

// 128x64 F@H^T tile over K-range [y*256,(y+1)*256). Fs:128x64, Hs:64x64 LDS.
__device__ __forceinline__ void hop_tile(
    const u16* __restrict__ Fb, const u16* __restrict__ Hb,
    int y, int tmt, float* __restrict__ Pd, u16* Fs, u16* Hs)
{
    int tm = tmt * 128, kb = y * 256;
    int t = threadIdx.x, lane = t & 63, w = t >> 6;
    int fr = lane & 15, q = lane >> 4, m7 = fr & 7;
    int subrow = lane >> 3, cch = (lane & 7) ^ subrow;

    const u16* fg[4]; u16* fl[4]; const u16* hg[2]; u16* hl[2];
    #pragma unroll
    for (int i = 0; i < 4; i++) {
        int r = i * 32 + w * 8 + subrow;
        fg[i] = Fb + (long)(tm + r) * 1024 + cch * 8;
        fl[i] = Fs + (i * 32 + w * 8) * 64;
    }
    #pragma unroll
    for (int i = 0; i < 2; i++) {
        int r = i * 32 + w * 8 + subrow;
        hg[i] = Hb + (long)r * 1024 + cch * 8;
        hl[i] = Hs + (i * 32 + w * 8) * 64;
    }

    v4f acc[2][4];
    #pragma unroll
    for (int i = 0; i < 2; i++)
        #pragma unroll
        for (int j = 0; j < 4; j++) {
            acc[i][j][0] = 0.f; acc[i][j][1] = 0.f; acc[i][j][2] = 0.f; acc[i][j][3] = 0.f;
        }

    for (int k0 = kb; k0 < kb + 256; k0 += 64) {
        __syncthreads();
        #pragma unroll
        for (int i = 0; i < 4; i++) gload16(fg[i] + k0, fl[i]);
        #pragma unroll
        for (int i = 0; i < 2; i++) gload16(hg[i] + k0, hl[i]);
        __syncthreads();
        v8s af[2][2], bfr[2][4];
        #pragma unroll
        for (int h = 0; h < 2; h++) {
            int ca = (((h << 2) + q) ^ m7) << 3;
            #pragma unroll
            for (int s = 0; s < 2; s++)
                af[h][s] = *(const v8s*)(Fs + (w * 32 + s * 16 + fr) * 64 + ca);
            #pragma unroll
            for (int s = 0; s < 4; s++)
                bfr[h][s] = *(const v8s*)(Hs + (s * 16 + fr) * 64 + ca);
        }
        #pragma unroll
        for (int h = 0; h < 2; h++)
            #pragma unroll
            for (int i = 0; i < 2; i++)
                #pragma unroll
                for (int j = 0; j < 4; j++)
                    acc[i][j] = __builtin_amdgcn_mfma_f32_16x16x32_bf16(af[h][i], bfr[h][j], acc[i][j], 0, 0, 0);
    }
    #pragma unroll
    for (int i = 0; i < 2; i++) {
        int rowb = tm + w * 32 + i * 16 + q * 4;
        #pragma unroll
        for (int j = 0; j < 4; j++) {
            int col = j * 16 + fr;
            #pragma unroll
            for (int r = 0; r < 4; r++)
                Pd[(long)(rowb + r) * 64 + col] = acc[i][j][r];
        }
    }
}

// mirror one off-diagonal 128x128 tile: C[tj][ti] = C[ti][tj]^T. sm: 128*136 u16.
__device__ __forceinline__ void mirror_tile(u16* __restrict__ C, int ti, int tj, u16* sm)
{
    int t = threadIdx.x;
    int r = t >> 1, ch = (t & 1) << 6;
    const u16* src = C + (long)(ti * 128 + r) * 1024 + tj * 128 + ch;
    #pragma unroll
    for (int p = 0; p < 8; p++) {
        uint4 v = *(const uint4*)(src + p * 8);
        *(uint4*)(&sm[r * 136 + ch + p * 8]) = v;
    }
    __syncthreads();
    u16* dst = C + (long)(tj * 128 + r) * 1024 + ti * 128 + ch;
    #pragma unroll
    for (int p = 0; p < 8; p++) {
        uint4 ov; u16* po = (u16*)&ov;
        #pragma unroll
        for (int e = 0; e < 8; e++) po[e] = sm[(ch + p * 8 + e) * 136 + r];
        *(uint4*)(dst + p * 8) = ov;
    }
}

// fused prob_log/sigmoid/row-norm for one row (wave-collective, 64 lanes)
__device__ __forceinline__ void fused_row(
    const u16* __restrict__ r1, const u16* __restrict__ r2, const u16* __restrict__ r3,
    float w0, float w1, float w2, float b0, u16* __restrict__ Frow, int lane)
{
    float m1[16], m2[16], m3[16];
    float s1 = 0.f, s2 = 0.f, s3 = 0.f;
    #pragma unroll
    for (int c = 0; c < 16; c++) {
        int j = c * 64 + lane;
        m1[c] = bf2f(r1[j]); m2[c] = bf2f(r2[j]); m3[c] = bf2f(r3[j]);
        s1 += m1[c]; s2 += m2[c]; s3 += m3[c];
    }
    #pragma unroll
    for (int o = 1; o < 64; o <<= 1) {
        s1 += __shfl_xor(s1, o); s2 += __shfl_xor(s2, o); s3 += __shfl_xor(s3, o);
    }
    float i1 = 1.f / (s1 + 1e-6f), i2 = 1.f / (s2 + 1e-6f), i3 = 1.f / (s3 + 1e-6f);
    float sig[16];
    float ssum = 0.f;
    #pragma unroll
    for (int c = 0; c < 16; c++) {
        float p1 = fminf(fmaxf(m1[c] * i1, 1e-6f), 1.0f - 1e-6f);
        float p2 = fminf(fmaxf(m2[c] * i2, 1e-6f), 1.0f - 1e-6f);
        float p3 = fminf(fmaxf(m3[c] * i3, 1e-6f), 1.0f - 1e-6f);
        float l1 = __logf(p1 / (1.0f - p1 + 1e-6f));
        float l2 = __logf(p2 / (1.0f - p2 + 1e-6f));
        float l3 = __logf(p3 / (1.0f - p3 + 1e-6f));
        float lg = b0 + w0 * l1 + w1 * l2 + w2 * l3;
        float sg = 1.0f / (1.0f + __expf(-lg));
        sig[c] = sg; ssum += sg;
    }
    #pragma unroll
    for (int o = 1; o < 64; o <<= 1) ssum += __shfl_xor(ssum, o);
    float inv = 1.0f / (ssum + 1e-6f);
    #pragma unroll
    for (int c = 0; c < 16; c++) Frow[c * 64 + lane] = f2bf(sig[c] * inv);
}

// ---------------------------------------------------------------------------
// Generation-1: AAt (upper 36), AtA (upper 36), A2 = A*A (full 64).
// 1D grid 1088 = 8 batches x 136 jobs, batch = blockIdx.x & 7 (XCD locality).
// ---------------------------------------------------------------------------
__global__ __launch_bounds__(256) void gemm_link1(
    const u16* __restrict__ A, const u16* __restrict__ AT,
    u16* __restrict__ AAt, u16* __restrict__ AtA, u16* __restrict__ A2)
{
    __shared__ u16 Xs[128 * 64];
    __shared__ u16 Ys[128 * 64];
    const long SSq = (long)SS * SS;
    int b = blockIdx.x & 7;
    int job = blockIdx.x >> 3;
    const u16* Xb; const u16* Yb; u16* Cd;
    int ti, tj;
    if (job < 72) {
        int tt = job < 36 ? job : job - 36;
        ti = 0;
        while (tt >= 8 - ti) { tt -= 8 - ti; ti++; }
        tj = ti + tt;
        if (job < 36) { Xb = A  + b * SSq; Yb = Xb; Cd = AAt + b * SSq; }
        else          { Xb = AT + b * SSq; Yb = Xb; Cd = AtA + b * SSq; }
    } else {
        int jj = job - 72;
        ti = jj >> 3; tj = jj & 7;
        Xb = A + b * SSq; Yb = AT + b * SSq; Cd = A2 + b * SSq;   // A2 = A*(AT)^T = A*A
    }
    tile_1024(Xb, Yb, Cd, ti * 128, tj * 128, Xs, Ys);
}

// ---------------------------------------------------------------------------
// Merged: gen-2 symmetric pair (576 blocks) + fused hop-0 (2048 blocks,
// 1 row/wave -> short blocks that fill in behind the GEMM blocks).
// ---------------------------------------------------------------------------
__global__ __launch_bounds__(256) void k_g2f0(
    const u16* __restrict__ AAt, const u16* __restrict__ AtA,
    u16* __restrict__ AAt2, u16* __restrict__ AtA2,
    const u16* __restrict__ A, const float* __restrict__ fw,
    const float* __restrict__ fbv, u16* __restrict__ F0)
{
    __shared__ u16 Xs[128 * 64];
    __shared__ u16 Ys[128 * 64];
    const long SSq = (long)SS * SS;
    int bx = blockIdx.x;
    if (bx < 576) {
        int z = bx & 15;
        int tt = bx >> 4, ti = 0;
        while (tt >= 8 - ti) { tt -= 8 - ti; ti++; }
        int tj = ti + tt;
        const u16* Xb = (z < 8 ? AAt : AtA) + (long)(z & 7) * SSq;
        u16* Cd = (z < 8 ? AAt2 : AtA2) + (long)(z & 7) * SSq;
        tile_1024(Xb, Xb, Cd, ti * 128, tj * 128, Xs, Ys);
    } else {
        int f = bx - 576;                  // 0..2047, 4 rows each (1 per wave)
        int lane = threadIdx.x & 63, w = threadIdx.x >> 6;
        float w0 = fw[0], w1 = fw[1], w2 = fw[2], b0 = fbv[0];
        long row = (long)f * 4 + w;
        fused_row(A + row * 1024, AAt + row * 1024, AtA + row * 1024,
                  w0, w1, w2, b0, F0 + row * 1024, lane);
    }
}

// ---------------------------------------------------------------------------
// Merged: mirror gen-2 (448 blocks) + hop-0 GEMM split-K=4 (256 blocks).
// ---------------------------------------------------------------------------
__global__ __launch_bounds__(256) void k_m2h0(
    u16* __restrict__ AAt2, u16* __restrict__ AtA2,
    const u16* __restrict__ F0, const u16* __restrict__ hopVT,
    float* __restrict__ Pa, float* __restrict__ Pb)
{
    __shared__ __align__(16) u16 sm[128 * 136];   // 34816 B
    const long SSq = (long)SS * SS;
    int bx = blockIdx.x;
    if (bx < 448) {
        int z = bx & 15;
        int tt = bx >> 4, ti = 0;
        while (tt >= 7 - ti) { tt -= 7 - ti; ti++; }
        int tj = ti + 1 + tt;
        u16* C = (z < 8 ? AAt2 : AtA2) + (long)(z & 7) * SSq;
        mirror_tile(C, ti, tj, sm);
    } else {
        int j = bx - 448;                  // 0..255
        int y = j >> 6, rest = j & 63;
        int tmt = rest >> 3, b = rest & 7;
        float* Pd = (y < 2 ? Pa + (long)y * 16 * 65536 : Pb + (long)(y - 2) * 16 * 65536)
                    + (long)b * 65536;                    // hop=0
        hop_tile(F0 + (long)b * SSq, hopVT + (long)b * 65536, y, tmt, Pd,
                 sm, sm + 128 * 64);
    }
}

// hop-1 GEMM standalone, split-K=4: grid 256.
__global__ __launch_bounds__(256) void gemm_hop1(
    const u16* __restrict__ F1, const u16* __restrict__ hopVT,
    float* __restrict__ Pa, float* __restrict__ Pb)
{
    __shared__ u16 Fs[128 * 64];
    __shared__ u16 Hs[64 * 64];
    const long SSq = (long)SS * SS;
    int j = blockIdx.x;
    int y = j >> 6, rest = j & 63;
    int tmt = rest >> 3, b = rest & 7;
    float* Pd = (y < 2 ? Pa + (long)y * 16 * 65536 : Pb + (long)(y - 2) * 16 * 65536)
                + (long)(8 + b) * 65536;                  // hop=1
    hop_tile(F1 + (long)b * SSq, hopVT + (long)(8 + b) * 65536, y, tmt, Pd, Fs, Hs);
}

// ---------------------------------------------------------------------------
// Generic batched NT GEMM (projection + final): C[z] = X[z](MxK) * Y[z]^T(NxK)
// ---------------------------------------------------------------------------
__global__ __launch_bounds__(256) void gemm_nt(
    const u16* __restrict__ X, long sx,
    const u16* __restrict__ Y, long sy,
    void* __restrict__ Cv, long sc,
    int M, int N, int K, int cf32)
{
    __shared__ u16 Xs[128 * 64];
    __shared__ u16 Ys[128 * 64];
    const u16* Xb = X + (long)blockIdx.z * sx;
    const u16* Yb = Y + (long)blockIdx.z * sy;
    int tm = blockIdx.x * 128, tn = blockIdx.y * 128;
    int t = threadIdx.x, lane = t & 63, w = t >> 6;
    int wm = (w & 1) << 6, wn = (w >> 1) << 6;
    int fr = lane & 15, q = lane >> 4, m7 = fr & 7;
    int subrow = lane >> 3, cch = (lane & 7) ^ subrow;

    const u16* xg[4]; const u16* yg[4]; u16* xl[4]; u16* yl[4];
    #pragma unroll
    for (int i = 0; i < 4; i++) {
        int r = i * 32 + w * 8 + subrow;
        xg[i] = Xb + (long)(tm + r) * K + cch * 8;
        yg[i] = Yb + (long)(tn + r) * K + cch * 8;
        xl[i] = Xs + (i * 32 + w * 8) * 64;
        yl[i] = Ys + (i * 32 + w * 8) * 64;
    }

    v4f acc[4][4];
    #pragma unroll
    for (int i = 0; i < 4; i++)
        #pragma unroll
        for (int j = 0; j < 4; j++) {
            acc[i][j][0] = 0.f; acc[i][j][1] = 0.f; acc[i][j][2] = 0.f; acc[i][j][3] = 0.f;
        }

    for (int k0 = 0; k0 < K; k0 += 64) {
        __syncthreads();
        #pragma unroll
        for (int i = 0; i < 4; i++) { gload16(xg[i] + k0, xl[i]); gload16(yg[i] + k0, yl[i]); }
        __syncthreads();
        v8s af[2][4], bfr[2][4];
        #pragma unroll
        for (int h = 0; h < 2; h++) {
            int ca = (((h << 2) + q) ^ m7) << 3;
            #pragma unroll
            for (int s = 0; s < 4; s++) {
                af[h][s]  = *(const v8s*)(Xs + (wm + s * 16 + fr) * 64 + ca);
                bfr[h][s] = *(const v8s*)(Ys + (wn + s * 16 + fr) * 64 + ca);
            }
        }
        #pragma unroll
        for (int h = 0; h < 2; h++)
            #pragma unroll
            for (int i = 0; i < 4; i++)
                #pragma unroll
                for (int j = 0; j < 4; j++)
                    acc[i][j] = __builtin_amdgcn_mfma_f32_16x16x32_bf16(af[h][i], bfr[h][j], acc[i][j], 0, 0, 0);
    }
    long cb = (long)blockIdx.z * sc;
    #pragma unroll
    for (int i = 0; i < 4; i++) {
        int rowb = tm + wm + i * 16 + q * 4;
        #pragma unroll
        for (int j = 0; j < 4; j++) {
            int col = tn + wn + j * 16 + fr;
            #pragma unroll
            for (int r = 0; r < 4; r++) {
                long o = cb + (long)(rowb + r) * N + col;
                if (cf32) ((float*)Cv)[o] = acc[i][j][r];
                else      ((u16*)Cv)[o] = f2bf(acc[i][j][r]);
            }
        }
    }
}

// ---------------------------------------------------------------------------
// Merged: QK^T scores (512 blocks, fp32) + hopV projection (64 blocks, bf16)
// ---------------------------------------------------------------------------
__global__ __launch_bounds__(256) void k_qk_hopv(
    const u16* __restrict__ Qb, const u16* __restrict__ Kb,
    const u16* __restrict__ Vb, const u16* __restrict__ hopWb,
    float* __restrict__ scores, u16* __restrict__ hopvC)
{
    __shared__ u16 Xs[128 * 64];
    __shared__ u16 Ys[128 * 64];
    const long SSq = (long)SS * SS;
    const long SD = (long)SS * DD;
    int bx = blockIdx.x;
    if (bx < 512) {
        int z = bx & 7;
        int tt = bx >> 3;
        int tm = (tt >> 3) * 128, tn = (tt & 7) * 128;
        tile_k64(Qb + z * SD + (long)tm * 64, Kb + z * SD + (long)tn * 64,
                 scores + z * SSq + (long)tm * 1024 + tn, 1024, 1, Xs, Ys);
    } else {
        int tm = (bx - 512) * 128;
        tile_k64(Vb + (long)tm * 64, hopWb,
                 hopvC + (long)tm * 128, 128, 0, Xs, Ys);
    }
}

// ---------------------------------------------------------------------------
// Merged: softmax (2048 blocks) + hopVT transposes (256 blocks)
// ---------------------------------------------------------------------------
__global__ __launch_bounds__(256) void k_sm_hvt(
    const float* __restrict__ scores, const float* __restrict__ btab,
    const float* __restrict__ temp, u16* __restrict__ A,
    const u16* __restrict__ hopvC, u16* __restrict__ hopVT)
{
    __shared__ __align__(16) float smf[3969];   // 15876 B
    int bx = blockIdx.x;
    int t = threadIdx.x;
    if (bx < 2048) {
        for (int i = t; i < 3969; i += 256) smf[i] = btab[i];
        __syncthreads();
        int lane = t & 63, w = t >> 6;
        long row = (long)bx * 4 + w;
        int i = (int)(row & 1023);
        int ih = i >> 5, iw = i & 31;
        float inv_t = 1.0f / fmaxf(temp[0], 0.1f);
        const float* srow = scores + row * 1024;
        float sc[16];
        float m = -1e30f;
        #pragma unroll
        for (int c = 0; c < 16; c++) {
            int j = c * 64 + lane;
            int jh = j >> 5, jw = j & 31;
            float pb = smf[(ih - jh + 31) * 63 + (iw - jw + 31)];
            float s = (srow[j] * 0.125f + pb) * inv_t;
            sc[c] = s; m = fmaxf(m, s);
        }
        #pragma unroll
        for (int o = 1; o < 64; o <<= 1) m = fmaxf(m, __shfl_xor(m, o));
        float sum = 0.f;
        #pragma unroll
        for (int c = 0; c < 16; c++) { sc[c] = __expf(sc[c] - m); sum += sc[c]; }
        #pragma unroll
        for (int o = 1; o < 64; o <<= 1) sum += __shfl_xor(sum, o);
        float inv = 1.0f / sum;
        #pragma unroll
        for (int c = 0; c < 16; c++) A[row * 1024 + c * 64 + lane] = f2bf(sc[c] * inv);
    } else {
        u16* tile = (u16*)smf;                 // 64*72 u16 = 9216 B
        int ex = bx - 2048;                    // 0..255
        int hop = ex >> 7, rem = ex & 127;
        int z = rem & 7, i0 = (rem >> 3) * 64;
        const u16* s = hopvC + (long)z * (1024 * 128) + hop * 64;
        u16* d = hopVT + (long)(hop * 8 + z) * 65536;
        int r = t >> 2, c0 = (t & 3) << 4;
        #pragma unroll
        for (int p = 0; p < 2; p++) {
            int c = c0 + p * 8;
            uint4 v = *(const uint4*)(s + (long)(i0 + r) * 128 + c);
            *(uint4*)(&tile[r * 72 + c]) = v;
        }
        __syncthreads();
        #pragma unroll
        for (int p = 0; p < 2; p++) {
            uint4 ov; u16* po = (u16*)&ov;
            #pragma unroll
            for (int e = 0; e < 8; e++) po[e] = tile[(c0 + p * 8 + e) * 72 + r];
            *(uint4*)(d + (long)r * 1024 + i0 + c0 + p * 8) = ov;
        }
    }
}

// mirror gen-1: 28 off-diag tiles x 16 matrices
__global__ __launch_bounds__(256) void k_mirror(u16* __restrict__ C0, u16* __restrict__ C1)
{
    __shared__ __align__(16) u16 sm[128 * 136];
    const long SSq = (long)SS * SS;
    int z = blockIdx.z;
    u16* C = (z < 8 ? C0 : C1) + (long)(z & 7) * SSq;
    int tt = blockIdx.x, ti = 0;
    while (tt >= 7 - ti) { tt -= 7 - ti; ti++; }
    int tj = ti + 1 + tt;
    mirror_tile(C, ti, tj, sm);
}

// fused hop-1: 2048 blocks, 1 row/wave
__global__ __launch_bounds__(256) void k_fused1(
    const u16* __restrict__ A2, const u16* __restrict__ AAt2,
    const u16* __restrict__ AtA2, const float* __restrict__ fw,
    const float* __restrict__ fbv, u16* __restrict__ F1)
{
    int lane = threadIdx.x & 63, w = threadIdx.x >> 6;
    float w0 = fw[3], w1 = fw[4], w2 = fw[5], b0 = fbv[1];
    long row = (long)blockIdx.x * 4 + w;
    fused_row(A2 + row * 1024, AAt2 + row * 1024, AtA2 + row * 1024,
              w0, w1, w2, b0, F1 + row * 1024, lane);
}

// pack x + weights to bf16 (merged)
__global__ __launch_bounds__(256) void k_pack(
    const float* __restrict__ x, const float* __restrict__ Wq,
    const float* __restrict__ Wk, const float* __restrict__ Wv,
    const float* __restrict__ gW, const float* __restrict__ hopW,
    const float* __restrict__ outW, u16* __restrict__ xb,
    u16* __restrict__ wpack, u16* __restrict__ hopWb, u16* __restrict__ outWb)
{
    int bx = blockIdx.x;
    if (bx < 4096) {
        long i = (long)bx * 256 + threadIdx.x;
        float4 v = ((const float4*)x)[i];
        ushort4 o;
        o.x = f2bf(v.x); o.y = f2bf(v.y); o.z = f2bf(v.z); o.w = f2bf(v.w);
        ((ushort4*)xb)[i] = o;
    } else {
        int idx = (bx - 4096) * 256 + threadIdx.x;
        if (idx < 131072) {
            int r = idx >> 9, c = idx & 511;
            float v = 0.f;
            if (r < 64)       v = Wq[r * 512 + c];
            else if (r < 128) v = Wk[(r - 64) * 512 + c];
            else if (r < 192) v = Wv[(r - 128) * 512 + c];
            else if (r < 194) v = gW[(r - 192) * 512 + c];
            wpack[idx] = f2bf(v);
        } else if (idx < 131072 + 8192) {
            int i = idx - 131072;
            hopWb[i] = f2bf(hopW[i]);
        } else if (idx < 131072 + 8192 + 32768) {
            int i = idx - 131072 - 8192;
            outWb[i] = f2bf(outW[i]);
        }
    }
}

// RoPE + gate softmax + Vb
__global__ __launch_bounds__(256) void k_rope(
    const float* __restrict__ QKVG, const float* __restrict__ gateb,
    u16* __restrict__ Qb, u16* __restrict__ Kb, u16* __restrict__ Vb,
    float* __restrict__ gate)
{
    int t = threadIdx.x, l = t & 63, w = t >> 6;
    long row = (long)blockIdx.x * 4 + w;
    int spos = (int)(row & (SS - 1));
    const float* base = QKVG + row * 256;
    float q = base[l], k = base[64 + l], v = base[128 + l];
    float qp = __shfl_xor(q, 32), kp = __shfl_xor(k, 32);
    float sgn = (l < 32) ? -1.f : 1.f;
    int f = l & 31;
    float ang = (float)spos * exp2f(-(float)f * (13.287712379549449f / 32.0f));
    float cs = cosf(ang), sn = sinf(ang);
    Qb[row * 64 + l] = f2bf(q * cs + sgn * qp * sn);
    Kb[row * 64 + l] = f2bf(k * cs + sgn * kp * sn);
    Vb[row * 64 + l] = f2bf(v);
    if (l < 2) {
        float g0 = base[192] + gateb[0], g1 = base[193] + gateb[1];
        float m = fmaxf(g0, g1);
        float e0 = __expf(g0 - m), e1 = __expf(g1 - m);
        gate[row * 2 + l] = ((l == 0) ? e0 : e1) / (e0 + e1);
    }
}

// generic bf16 transpose (A -> AT)
__global__ __launch_bounds__(256) void k_transpose(
    const u16* __restrict__ src, u16* __restrict__ dst,
    int srs, int drs, long sbs, long dbs)
{
    __shared__ u16 tile[64 * 72];
    const u16* s = src + (long)blockIdx.z * sbs;
    u16* d = dst + (long)blockIdx.z * dbs;
    int i0 = blockIdx.x * 64, j0 = blockIdx.y * 64;
    int t = threadIdx.x;
    int r = t >> 2, c0 = (t & 3) << 4;
    #pragma unroll
    for (int p = 0; p < 2; p++) {
        int c = c0 + p * 8;
        uint4 v = *(const uint4*)(s + (long)(i0 + r) * srs + j0 + c);
        *(uint4*)(&tile[r * 72 + c]) = v;
    }
    __syncthreads();
    #pragma unroll
    for (int p = 0; p < 2; p++) {
        uint4 ov;
        u16* po = (u16*)&ov;
        #pragma unroll
        for (int e = 0; e < 8; e++) po[e] = tile[(c0 + p * 8 + e) * 72 + r];
        *(uint4*)(d + (long)(j0 + r) * drs + i0 + c0 + p * 8) = ov;
    }
}

// sum split-K=4 partials, gate-combine -> comb bf16 [8192][64]
__global__ __launch_bounds__(256) void k_combine(
    const float* __restrict__ Pa, const float* __restrict__ Pb,
    const float* __restrict__ gate, u16* __restrict__ comb)
{
    long idx = (long)blockIdx.x * 256 + threadIdx.x;   // 8192*64
    long srow = idx >> 6;
    int b = (int)(srow >> 10);
    long o = (long)(srow & 1023) * 64 + (idx & 63);
    float h0 = Pa[(long)b * 65536 + o] + Pa[(long)(16 + b) * 65536 + o]
             + Pb[(long)b * 65536 + o] + Pb[(long)(16 + b) * 65536 + o];
    float h1 = Pa[(long)(8 + b) * 65536 + o] + Pa[(long)(24 + b) * 65536 + o]
             + Pb[(long)(8 + b) * 65536 + o] + Pb[(long)(24 + b) * 65536 + o];
    float g0 = gate[srow * 2], g1 = gate[srow * 2 + 1];
    comb[idx] = f2bf(h0 * g0 + h1 * g1);
}

// ---------------------------------------------------------------------------
extern "C" void kernel_launch(void* const* d_in, const int* in_sizes, int n_in,
                              void* d_out, int out_size, void* d_ws, size_t ws_size,
                              hipStream_t stream) {
    const float* x    = (const float*)d_in[0];
    const float* Wq   = (const float*)d_in[1];
    const float* Wk   = (const float*)d_in[2];
    const float* Wv   = (const float*)d_in[3];
    const float* btab = (const float*)d_in[4];
    const float* fw   = (const float*)d_in[5];
    const float* fbv  = (const float*)d_in[6];
    const float* hopW = (const float*)d_in[7];
    const float* gW   = (const float*)d_in[8];
    const float* gb   = (const float*)d_in[9];
    const float* outW = (const float*)d_in[10];
    const float* temp = (const float*)d_in[11];
    float* out = (float*)d_out;

    char* wsb = (char*)d_ws;
    size_t off = 0;
    auto take = [&](size_t n) { char* p = wsb + off; off += (n + 255) & ~(size_t)255; return p; };
    u16* Qb      = (u16*)take(8192L * 64 * 2);
    u16* Kb      = (u16*)take(8192L * 64 * 2);
    u16* Vb      = (u16*)take(8192L * 64 * 2);
    float* gate  = (float*)take(8192L * 2 * 4);
    u16* wpack   = (u16*)take(256L * 512 * 2);
    u16* hopWb   = (u16*)take(2L * 64 * 64 * 2);
    u16* outWb   = (u16*)take(512L * 64 * 2);
    u16* hopvC   = (u16*)take(8192L * 128 * 2);      // [s][hop*64+e]
    u16* hopVT   = (u16*)take(2L * 8 * 64 * 1024 * 2);
    float* Pa    = (float*)take(2L * 16 * 65536 * 4);     // split-K partials y=0,1
    u16* comb    = (u16*)take(8192L * 64 * 2);
    float* scoresF = (float*)take(8L * 1024 * 1024 * 4);  // 32 MB region
    float* QKVG  = (float*)scoresF;                   // alias: dead before scores
    u16* F0      = (u16*)scoresF;                     // alias: scores dead before F0
    u16* F1      = (u16*)scoresF + 8L * 1024 * 1024;  // second 16 MB of region
    u16* A       = (u16*)take(8L * 1024 * 1024 * 2);
    u16* xb      = (u16*)A;                           // alias: dead before A
    u16* AT      = (u16*)take(8L * 1024 * 1024 * 2);
    float* Pb    = (float*)AT;                        // alias: AT dead after link1
    u16* AAt     = (u16*)take(8L * 1024 * 1024 * 2);
    u16* AtA     = (u16*)take(8L * 1024 * 1024 * 2);
    u16* A2      = (u16*)take(8L * 1024 * 1024 * 2);
    u16* AAt2    = (u16*)take(8L * 1024 * 1024 * 2);
    u16* AtA2    = (u16*)take(8L * 1024 * 1024 * 2);
    (void)ws_size; (void)in_sizes; (void)n_in; (void)out_size;

    const long SSq = (long)SS * SS;

    // 1. pack inputs (merged)
    k_pack<<<4768, 256, 0, stream>>>(x, Wq, Wk, Wv, gW, hopW, outW, xb, wpack, hopWb, outWb);
    // 2. fused projection: QKVG[8192][256] = xb @ wpack^T (fp32)
    gemm_nt<<<dim3(64, 2, 1), 256, 0, stream>>>(xb, 0, wpack, 0, QKVG, 0, 8192, 256, 512, 1);
    // 3. rope + gate + Vb
    k_rope<<<2048, 256, 0, stream>>>(QKVG, gb, Qb, Kb, Vb, gate);
    // 4. scores = Q K^T (fp32) + hopvC = Vb @ hopWb^T (merged)
    k_qk_hopv<<<576, 256, 0, stream>>>(Qb, Kb, Vb, hopWb, scoresF, hopvC);
    // 5. softmax -> A + hopVT transposes (merged)
    k_sm_hvt<<<2304, 256, 0, stream>>>(scoresF, btab, temp, A, hopvC, hopVT);
    // 6. AT
    k_transpose<<<dim3(16, 16, 8), 256, 0, stream>>>(A, AT, 1024, 1024, SSq, SSq);
    // 7. generation-1: AAt, AtA (upper) + A2 (full)
    gemm_link1<<<1088, 256, 0, stream>>>(A, AT, AAt, AtA, A2);
    // 8. mirror gen-1
    k_mirror<<<dim3(28, 1, 16), 256, 0, stream>>>(AAt, AtA);
    // 9. gen-2 sym pair + fused hop-0 (merged; fine-grained fused blocks)
    k_g2f0<<<2624, 256, 0, stream>>>(AAt, AtA, AAt2, AtA2, A, fw, fbv, F0);
    // 10. mirror gen-2 + hop-0 GEMM (merged)
    k_m2h0<<<704, 256, 0, stream>>>(AAt2, AtA2, F0, hopVT, Pa, Pb);
    // 11. fused hop-1 -> F1 (fine-grained)
    k_fused1<<<2048, 256, 0, stream>>>(A2, AAt2, AtA2, fw, fbv, F1);
    // 12. hop-1 GEMM
    gemm_hop1<<<256, 256, 0, stream>>>(F1, hopVT, Pa, Pb);
    // 13. combine + output projection
    k_combine<<<2048, 256, 0, stream>>>(Pa, Pb, gate, comb);
    gemm_nt<<<dim3(64, 4, 1), 256, 0, stream>>>(comb, 0, outWb, 0, out, 0, 8192, 512, 64, 1);
}